// Round 6
// baseline (320.610 us; speedup 1.0000x reference)
//
#include <hip/hip_runtime.h>
#include <hip/hip_bf16.h>
#include <hip/hip_fp16.h>
#include <math.h>

#define D    1024
#define H    16
#define DH   64
#define S    1024
#define M    1024
#define B    2
#define J    2048          // M + S
#define SCALE 0.125f       // 1/sqrt(64)

typedef __attribute__((ext_vector_type(8))) short        bf16x8;
typedef __attribute__((ext_vector_type(4))) short        s16x4;
typedef __attribute__((ext_vector_type(8))) _Float16     h16x8;
typedef __attribute__((ext_vector_type(4))) _Float16     h16x4;
typedef __attribute__((ext_vector_type(8))) unsigned short us8;
typedef __attribute__((ext_vector_type(4))) float        f32x4;

__device__ __forceinline__ short f2bs(float f) {
    __hip_bfloat16 t = __float2bfloat16(f);
    short r; __builtin_memcpy(&r, &t, 2); return r;
}
// fast bf16 pack (round-half-up); inputs finite non-negative (probs)
__device__ __forceinline__ unsigned short f2bf_fast(float f) {
    unsigned int u; __builtin_memcpy(&u, &f, 4);
    return (unsigned short)((u + 0x8000u) >> 16);
}

// async global->LDS, 16 bytes per lane
__device__ __forceinline__ void g2l16(const short* g, short* l) {
    __builtin_amdgcn_global_load_lds(
        (const __attribute__((address_space(1))) unsigned int*)g,
        (__attribute__((address_space(3))) unsigned int*)l, 16, 0, 0);
}

// ---------------------------------------------------------------------------
// prep: blocks [0,6144)  fp32->bf16 flat convert (mem||x -> a_bf, pemb -> p_bf)
//       blocks [6144,7424) 64x64 weight transpose+convert W[k][n] -> Wt[n][k]
// ---------------------------------------------------------------------------
__global__ __launch_bounds__(256)
void prep(const float* __restrict__ mem, const float* __restrict__ x,
          const float* __restrict__ pemb,
          const float* __restrict__ Wkv, const float* __restrict__ Wq,
          const float* __restrict__ Wpos, const float* __restrict__ Wout,
          short* __restrict__ a_bf, short* __restrict__ p_bf,
          short* __restrict__ wkvt, short* __restrict__ wqt,
          short* __restrict__ wpt,  short* __restrict__ wot)
{
    __shared__ float t[64][65];
    int blk = blockIdx.x;
    const int tid = threadIdx.x;
    if (blk < 6144) {
        const int idx = (blk * 256 + tid) * 4;
        const int TWO_M = 2 * 1024 * 1024;
        float4 v; short* dst;
        if (idx < TWO_M)          { v = *(const float4*)(mem  + idx);           dst = a_bf + idx; }
        else if (idx < 2 * TWO_M) { v = *(const float4*)(x    + idx - TWO_M);   dst = a_bf + idx; }
        else                      { v = *(const float4*)(pemb + idx - 2*TWO_M); dst = p_bf + idx - 2*TWO_M; }
        s16x4 o = { f2bs(v.x), f2bs(v.y), f2bs(v.z), f2bs(v.w) };
        *(s16x4*)dst = o;
        return;
    }
    blk -= 6144;
    const float* src; short* dst; int N, t0;
    if (blk < 512)       { src = Wkv;  dst = wkvt; N = 2048; t0 = blk; }
    else if (blk < 768)  { src = Wq;   dst = wqt;  N = 1024; t0 = blk - 512; }
    else if (blk < 1024) { src = Wpos; dst = wpt;  N = 1024; t0 = blk - 768; }
    else                 { src = Wout; dst = wot;  N = 1024; t0 = blk - 1024; }
    const int ntn = N >> 6;
    const int k0 = (t0 / ntn) * 64, n0 = (t0 % ntn) * 64;
    #pragma unroll
    for (int e = tid; e < 4096; e += 256) {
        int r = e >> 6, c = e & 63;
        t[r][c] = src[(size_t)(k0 + r) * N + n0 + c];
    }
    __syncthreads();
    #pragma unroll
    for (int e = tid; e < 4096; e += 256) {
        int nr = e >> 6, kc = e & 63;
        dst[(size_t)(n0 + nr) * 1024 + k0 + kc] = f2bs(t[kc][nr]);
    }
}

// ---------------------------------------------------------------------------
// Shared MFMA GEMM core: BM=BN=128, BK=64, 256 thr, K=1024.
// ---------------------------------------------------------------------------
__device__ __forceinline__ void gemm_core(const short* __restrict__ A,
                                          const short* __restrict__ Bt,
                                          short* As, short* Bs,
                                          int bm0, int bn0, int tid,
                                          f32x4 acc[4][4])
{
    const int w    = tid >> 6;
    const int wy   = w >> 1, wx = w & 1;
    const int lane = tid & 63;
    const int lm   = lane & 15;
    const int lq   = lane >> 4;

    for (int k0 = 0; k0 < 1024; k0 += 64) {
        const short* Ab = A  + (size_t)bm0 * 1024 + k0;
        const short* Bb = Bt + (size_t)bn0 * 1024 + k0;
        #pragma unroll
        for (int t = 0; t < 4; ++t) {
            int s = t * 256 + tid;
            int r = s >> 3, c = s & 7;
            int cg = c ^ (r & 7);
            g2l16(Ab + r * 1024 + cg * 8, As + s * 8);
            g2l16(Bb + r * 1024 + cg * 8, Bs + s * 8);
        }
        __syncthreads();
        #pragma unroll
        for (int kk = 0; kk < 2; ++kk) {
            bf16x8 af[4], bg[4];
            #pragma unroll
            for (int r4 = 0; r4 < 4; ++r4) {
                int ar = wy * 64 + r4 * 16 + lm;
                int kc = kk * 4 + lq;
                af[r4] = *(const bf16x8*)(As + ((ar << 3) + (kc ^ (ar & 7))) * 8);
            }
            #pragma unroll
            for (int c4 = 0; c4 < 4; ++c4) {
                int br = wx * 64 + c4 * 16 + lm;
                int kc = kk * 4 + lq;
                bg[c4] = *(const bf16x8*)(Bs + ((br << 3) + (kc ^ (br & 7))) * 8);
            }
            #pragma unroll
            for (int r4 = 0; r4 < 4; ++r4)
                #pragma unroll
                for (int c4 = 0; c4 < 4; ++c4)
                    acc[r4][c4] = __builtin_amdgcn_mfma_f32_16x16x32_bf16(
                        af[r4], bg[c4], acc[r4][c4], 0, 0, 0);
        }
        __syncthreads();
    }
}

// ---------------------------------------------------------------------------
// Fused kv/q/r projections (unchanged).
// ---------------------------------------------------------------------------
__global__ __launch_bounds__(256)
void proj_fused(const short* __restrict__ a_bf, const short* __restrict__ p_bf,
                const short* __restrict__ wkvt, const short* __restrict__ wqt,
                const short* __restrict__ wpt,
                short* __restrict__ k_bf, short* __restrict__ vt_bf,
                short* __restrict__ qu_bf, short* __restrict__ qv_bf,
                short* __restrict__ r_bf,
                const float* __restrict__ uvec, const float* __restrict__ vvec)
{
    __shared__ __align__(16) short As[128 * 64];
    __shared__ __align__(16) short Bs[128 * 64];

    int blk = blockIdx.x;
    int mode, bx, by;
    const short *A, *Bt;
    if (blk < 512)      { bx = blk & 15; by = blk >> 4;
                          if (bx >= 8) { mode = 4; A = wkvt; Bt = a_bf; }   // swapped V
                          else         { mode = 0; A = a_bf; Bt = wkvt; } }
    else if (blk < 640) { int b2 = blk - 512; mode = 1; bx = b2 & 7; by = b2 >> 3;
                          A = a_bf + (size_t)2048 * 1024; Bt = wqt; }
    else                { int b3 = blk - 640; mode = 2; bx = b3 & 7; by = b3 >> 3;
                          A = p_bf; Bt = wpt; }
    const int bn0 = (mode == 4) ? by * 128 : bx * 128;
    const int bm0 = (mode == 4) ? bx * 128 : by * 128;
    const int tid = threadIdx.x;
    const int w = tid >> 6, wy = w >> 1, wx = w & 1;
    const int lane = tid & 63, lm = lane & 15, lq = lane >> 4;

    f32x4 acc[4][4];
    #pragma unroll
    for (int r = 0; r < 4; ++r)
        #pragma unroll
        for (int c = 0; c < 4; ++c) acc[r][c] = (f32x4){0.f, 0.f, 0.f, 0.f};

    gemm_core(A, Bt, As, Bs, bm0, bn0, tid, acc);

    #pragma unroll
    for (int r4 = 0; r4 < 4; ++r4) {
        #pragma unroll
        for (int c4 = 0; c4 < 4; ++c4) {
            const int n = bn0 + wx * 64 + c4 * 16 + lm;
            float ubias = 0.f, vbias = 0.f;
            if (mode == 1) { ubias = uvec[n]; vbias = vvec[n]; }
            #pragma unroll
            for (int reg = 0; reg < 4; ++reg) {
                const int m = bm0 + wy * 64 + r4 * 16 + lq * 4 + reg;
                const float val = acc[r4][c4][reg];
                if (mode == 0) {
                    int j = m >> 1, b = m & 1;
                    int h = n >> 6, d = n & 63;
                    k_bf[(((size_t)b * H + h) * J + j) * DH + d] = f2bs(val);
                } else if (mode == 4) {
                    int n2 = m - 1024, h = n2 >> 6, d = n2 & 63;
                    int j = n >> 1, b = n & 1;
                    vt_bf[(((size_t)b * H + h) * DH + d) * J + j] = f2bs(val);
                } else if (mode == 1) {
                    int i = m >> 1, b = m & 1;
                    int h = n >> 6, d = n & 63;
                    size_t o = (((size_t)b * H + h) * S + i) * DH + d;
                    qu_bf[o] = f2bs((val + ubias) * SCALE);
                    qv_bf[o] = f2bs((val + vbias) * SCALE);
                } else {
                    int h = n >> 6, d = n & 63;
                    r_bf[((size_t)h * J + m) * DH + d] = f2bs(val);
                }
            }
        }
    }
}

// ---------------------------------------------------------------------------
// Output projection: M=2048, N=1024, fp32 out.
// ---------------------------------------------------------------------------
__global__ __launch_bounds__(256)
void gemm_out(const short* __restrict__ A, const short* __restrict__ Bt,
              float* __restrict__ out)
{
    __shared__ __align__(16) short As[128 * 64];
    __shared__ __align__(16) short Bs[128 * 64];
    const int bn0 = blockIdx.x * 128, bm0 = blockIdx.y * 128;
    const int tid = threadIdx.x;
    const int w = tid >> 6, wy = w >> 1, wx = w & 1;
    const int lane = tid & 63, lm = lane & 15, lq = lane >> 4;

    f32x4 acc[4][4];
    #pragma unroll
    for (int r = 0; r < 4; ++r)
        #pragma unroll
        for (int c = 0; c < 4; ++c) acc[r][c] = (f32x4){0.f, 0.f, 0.f, 0.f};

    gemm_core(A, Bt, As, Bs, bm0, bn0, tid, acc);

    #pragma unroll
    for (int r4 = 0; r4 < 4; ++r4)
        #pragma unroll
        for (int c4 = 0; c4 < 4; ++c4) {
            const int n = bn0 + wx * 64 + c4 * 16 + lm;
            #pragma unroll
            for (int reg = 0; reg < 4; ++reg) {
                const int m = bm0 + wy * 64 + r4 * 16 + lq * 4 + reg;
                out[(size_t)m * 1024 + n] = acc[r4][c4][reg];
            }
        }
}

// ---------------------------------------------------------------------------
// MFMA attention. R15: block = 32 rows x (b,h) x jh-half, processed as TWO
// sequential 512-col chunks sharing a 32 KB score buffer + 16 KB LDS
// partial-O accumulator (48 KB total -> 3 blocks/CU, 24 waves = 75% occ cap,
// up from 43%). Key insight from R13's failure: pos-phase work scales with
// the COLUMN window (r-tiles ~ window/16), not rows — so splitting columns
// (not rows) halves per-block work along with LDS. PV accumulators are
// flushed to LDS per chunk so per-phase register live-sets stay at R14's
// measured ~52 VGPR (no forced launch bounds; R10's spill lesson). Softmax
// partial sums ride in a register across chunks; ml/opart/combine unchanged.
// Kernel is stall-bound (35% per-SIMD issue at 43% occ); inter-block
// overlap at 3 blocks/CU is the lever.
// ---------------------------------------------------------------------------
__device__ __forceinline__ int sidx(int m, int c) {   // m in [0,32), c in [0,512)
    return (m << 9) + (c ^ (m << 3));
}

__global__ __launch_bounds__(512)
void attn_mfma(const short* __restrict__ qu_bf, const short* __restrict__ qv_bf,
               const short* __restrict__ k_bf,  const short* __restrict__ vt_bf,
               const short* __restrict__ r_bf,
               float* __restrict__ opart, float* __restrict__ ml)
{
    __shared__ __align__(16) unsigned short sc[32 * 512];   // 32 KB scores
    __shared__ __align__(16) float oacc[4096];              // 16 KB partial O
    __half* sch = (__half*)sc;

    const int bh  = blockIdx.x;
    const int it  = blockIdx.y;
    const int jh  = blockIdx.z;
    const int i0  = it * 32;
    const int h   = bh & (H - 1);
    const int tid = threadIdx.x;
    const int w    = tid >> 6;       // 0..7
    const int lane = tid & 63;
    const int lm   = lane & 15;
    const int lq   = lane >> 4;
    const int slot = (it * 32 + bh) * 2 + jh;
    const int dslice = w & 3, jq = w >> 2;

    const short* rbase = r_bf + (size_t)h * J * DH;
    const short* kbase = k_bf + (size_t)bh * J * DH;

    float ssum = 0.f;

    #pragma unroll 1
    for (int ch = 0; ch < 2; ++ch) {
        const int cbeg = (jh << 10) + (ch << 9);
        const int cend = cbeg + 512;

        // ---- Qv / Qw fragments (reloaded per chunk: short live ranges) ----
        const short* qvp0 = qv_bf + ((size_t)(bh * S + i0 + lm)) * DH + lq * 8;
        const short* qvp1 = qvp0 + 16 * DH;
        bf16x8 av00 = *(const bf16x8*)qvp0, av01 = *(const bf16x8*)(qvp0 + 32);
        bf16x8 av10 = *(const bf16x8*)qvp1, av11 = *(const bf16x8*)(qvp1 + 32);
        int r1a = i0 + 1 + lm;  if (r1a > S - 1) r1a = S - 1;   // clamped rows masked
        int r1b = i0 + 17 + lm; if (r1b > S - 1) r1b = S - 1;
        const short* qwp0 = qv_bf + ((size_t)(bh * S + r1a)) * DH + lq * 8;
        const short* qwp1 = qv_bf + ((size_t)(bh * S + r1b)) * DH + lq * 8;
        bf16x8 aw00 = *(const bf16x8*)qwp0, aw01 = *(const bf16x8*)(qwp0 + 32);
        bf16x8 aw10 = *(const bf16x8*)qwp1, aw11 = *(const bf16x8*)(qwp1 + 32);

        // ---- zero the pos hole column: row m, col i0+m+1025 (if in window) ----
        if (tid < 32) {
            int hole = i0 + tid + 1025;
            if (hole >= cbeg && hole < cend) sc[sidx(tid, hole - cbeg)] = 0;
        }

        // ---- pos main: col = i0 + 16t + lm + m - 1023; interior/edge split ----
        {
            int tmp = cbeg + 977 - i0;
            int tlo = tmp > 0 ? ((tmp + 15) >> 4) : 0;
            int thi = (cend + 1022 - i0) >> 4; if (thi > 127) thi = 127;
            int t = tlo + w;
            if (t <= thi) {
                const short* rp = rbase + (size_t)(t * 16 + lm) * DH + lq * 8;
                bf16x8 b0 = *(const bf16x8*)rp, b1 = *(const bf16x8*)(rp + 32);
                for (; t <= thi; t += 8) {
                    bf16x8 n0, n1;
                    if (t + 8 <= thi) {
                        const short* rpn = rbase + (size_t)((t + 8) * 16 + lm) * DH + lq * 8;
                        n0 = *(const bf16x8*)rpn; n1 = *(const bf16x8*)(rpn + 32);
                    }
                    f32x4 c0 = {0.f,0.f,0.f,0.f}, c1 = {0.f,0.f,0.f,0.f};
                    c0 = __builtin_amdgcn_mfma_f32_16x16x32_bf16(av00, b0, c0, 0, 0, 0);
                    c1 = __builtin_amdgcn_mfma_f32_16x16x32_bf16(av10, b0, c1, 0, 0, 0);
                    c0 = __builtin_amdgcn_mfma_f32_16x16x32_bf16(av01, b1, c0, 0, 0, 0);
                    c1 = __builtin_amdgcn_mfma_f32_16x16x32_bf16(av11, b1, c1, 0, 0, 0);
                    int cb = i0 + t * 16 + lm - 1023 - cbeg;     // local col for m=0
                    int base = i0 + 16 * t - 1023;               // scalar col_min
                    if (base >= cbeg && base + 46 < cend) {
                        #pragma unroll
                        for (int r = 0; r < 4; ++r) {
                            int m0 = lq * 4 + r, m1 = m0 + 16;
                            sch[sidx(m0, cb + m0)] = __float2half(c0[r]);
                            sch[sidx(m1, cb + m1)] = __float2half(c1[r]);
                        }
                    } else {
                        #pragma unroll
                        for (int r = 0; r < 4; ++r) {
                            int m0 = lq * 4 + r, m1 = m0 + 16;
                            int cA = cb + m0, cB = cb + m1;
                            if (cA >= 0 && cA < 512) sch[sidx(m0, cA)] = __float2half(c0[r]);
                            if (cB >= 0 && cB < 512) sch[sidx(m1, cB)] = __float2half(c1[r]);
                        }
                    }
                    b0 = n0; b1 = n1;
                }
            }
        }

        // ---- pos wrap: col = i0 + 16t + lm + m + 1026, rows Qv[i+1] ----
        {
            int tmpw = cbeg - 1072 - i0;
            int tlw = tmpw > 0 ? ((tmpw + 15) >> 4) : 0;
            int thw = (cend - 1027 - i0) >> 4; if (thw > 127) thw = 127;
            int t = tlw + w;
            if (t <= thw) {
                const short* rp = rbase + (size_t)(t * 16 + lm) * DH + lq * 8;
                bf16x8 b0 = *(const bf16x8*)rp, b1 = *(const bf16x8*)(rp + 32);
                for (; t <= thw; t += 8) {
                    bf16x8 n0, n1;
                    if (t + 8 <= thw) {
                        const short* rpn = rbase + (size_t)((t + 8) * 16 + lm) * DH + lq * 8;
                        n0 = *(const bf16x8*)rpn; n1 = *(const bf16x8*)(rpn + 32);
                    }
                    f32x4 c0 = {0.f,0.f,0.f,0.f}, c1 = {0.f,0.f,0.f,0.f};
                    c0 = __builtin_amdgcn_mfma_f32_16x16x32_bf16(aw00, b0, c0, 0, 0, 0);
                    c1 = __builtin_amdgcn_mfma_f32_16x16x32_bf16(aw10, b0, c1, 0, 0, 0);
                    c0 = __builtin_amdgcn_mfma_f32_16x16x32_bf16(aw01, b1, c0, 0, 0, 0);
                    c1 = __builtin_amdgcn_mfma_f32_16x16x32_bf16(aw11, b1, c1, 0, 0, 0);
                    int cb = i0 + t * 16 + lm + 1026 - cbeg;
                    int base = i0 + 16 * t + 1026;
                    if (base >= cbeg && base + 46 < cend) {
                        #pragma unroll
                        for (int r = 0; r < 4; ++r) {
                            int m0 = lq * 4 + r, m1 = m0 + 16;
                            sch[sidx(m0, cb + m0)] = __float2half(c0[r]);
                            sch[sidx(m1, cb + m1)] = __float2half(c1[r]);
                        }
                    } else {
                        #pragma unroll
                        for (int r = 0; r < 4; ++r) {
                            int m0 = lq * 4 + r, m1 = m0 + 16;
                            int cA = cb + m0, cB = cb + m1;
                            if (cA >= 0 && cA < 512) sch[sidx(m0, cA)] = __float2half(c0[r]);
                            if (cB >= 0 && cB < 512) sch[sidx(m1, cB)] = __float2half(c1[r]);
                        }
                    }
                    b0 = n0; b1 = n1;
                }
            }
        }

        // ---- prefetch first content K-tile for this chunk ----
        const int tb = cbeg >> 4;                // 32 col-tiles per chunk
        bf16x8 kb0, kb1;
        {
            int t0 = tb + w + 8 * (it & 3);
            const short* kp0 = kbase + (size_t)(t0 * 16 + lm) * DH + lq * 8;
            kb0 = *(const bf16x8*)kp0; kb1 = *(const bf16x8*)(kp0 + 32);
        }
        __syncthreads();

        // ---- Qu fragments ----
        const short* qup0 = qu_bf + ((size_t)(bh * S + i0 + lm)) * DH + lq * 8;
        const short* qup1 = qup0 + 16 * DH;
        bf16x8 au00 = *(const bf16x8*)qup0, au01 = *(const bf16x8*)(qup0 + 32);
        bf16x8 au10 = *(const bf16x8*)qup1, au11 = *(const bf16x8*)(qup1 + 32);

        // ---- content: swapped-operand MFMA (A=K, B=Q); b64 RMW of scores ----
        #pragma unroll 1
        for (int g = 0; g < 4; ++g) {
            bf16x8 nb0, nb1;
            if (g + 1 < 4) {
                int u = tb + w + 8 * ((g + 1 + it) & 3);
                const short* np = kbase + (size_t)(u * 16 + lm) * DH + lq * 8;
                nb0 = *(const bf16x8*)np; nb1 = *(const bf16x8*)(np + 32);
            }
            int t = tb + w + 8 * ((g + it) & 3);
            int lc = (t << 4) - cbeg;                // 16-aligned local col base
            int aA = sidx(lm,      lc + lq * 4);     // 4 consecutive u16, 8B-aligned
            int aB = sidx(lm + 16, lc + lq * 4);
            h16x4 hA = *(const h16x4*)(sc + aA);
            h16x4 hB = *(const h16x4*)(sc + aB);
            f32x4 c0, c1;
            #pragma unroll
            for (int r = 0; r < 4; ++r) { c0[r] = (float)hA[r]; c1[r] = (float)hB[r]; }
            c0 = __builtin_amdgcn_mfma_f32_16x16x32_bf16(kb0, au00, c0, 0, 0, 0);
            c1 = __builtin_amdgcn_mfma_f32_16x16x32_bf16(kb0, au10, c1, 0, 0, 0);
            c0 = __builtin_amdgcn_mfma_f32_16x16x32_bf16(kb1, au01, c0, 0, 0, 0);
            c1 = __builtin_amdgcn_mfma_f32_16x16x32_bf16(kb1, au11, c1, 0, 0, 0);
            h16x4 oA, oB;
            #pragma unroll
            for (int r = 0; r < 4; ++r) { oA[r] = (_Float16)c0[r]; oB[r] = (_Float16)c1[r]; }
            *(h16x4*)(sc + aA) = oA;
            *(h16x4*)(sc + aB) = oB;
            kb0 = nb0; kb1 = nb1;
        }

        // ---- prefetch first PV V-chunk before the barrier ----
        const short* vtb = vt_bf + ((size_t)bh * DH + dslice * 16 + lm) * J + cbeg + jq * 256;
        bf16x8 cv0, cv1, cv2, cv3;
        {
            int j0 = (it & 1) * 128;
            cv0 = *(const bf16x8*)(vtb + j0 +  0 + lq * 8);
            cv1 = *(const bf16x8*)(vtb + j0 + 32 + lq * 8);
            cv2 = *(const bf16x8*)(vtb + j0 + 64 + lq * 8);
            cv3 = *(const bf16x8*)(vtb + j0 + 96 + lq * 8);
        }
        __syncthreads();

        // ---- softmax (no max-sub): exp in place fp16->bf16; partial sum ----
        {
            const int row = tid >> 4;            // 0..31
            const int cw  = (tid & 15) * 8;
            #pragma unroll
            for (int c = cw; c < 512; c += 128) {
                int idx = sidx(row, c);
                h16x8 v = *(const h16x8*)(sc + idx);
                us8 e;
                #pragma unroll
                for (int k = 0; k < 8; ++k) {
                    float ex = __builtin_amdgcn_exp2f((float)v[k] * 1.44269504f);
                    ssum += ex;
                    e[k] = f2bf_fast(ex);
                }
                *(us8*)(sc + idx) = e;
            }
        }
        __syncthreads();

        // ---- PV: wave -> d-slice (w&3), j-quarter (w>>2); 2 x 128 cols ----
        f32x4 pa0 = {0.f,0.f,0.f,0.f}, pa1 = {0.f,0.f,0.f,0.f};
        f32x4 pa2 = {0.f,0.f,0.f,0.f}, pa3 = {0.f,0.f,0.f,0.f};
        f32x4 pb0 = {0.f,0.f,0.f,0.f}, pb1 = {0.f,0.f,0.f,0.f};
        f32x4 pb2 = {0.f,0.f,0.f,0.f}, pb3 = {0.f,0.f,0.f,0.f};
        #pragma unroll 1
        for (int jo0 = 0; jo0 < 2; ++jo0) {       // 128 local j per iteration
            bf16x8 nv0, nv1, nv2, nv3;
            if (jo0 < 1) {
                int jn = ((jo0 + 1 + it) & 1) * 128;
                nv0 = *(const bf16x8*)(vtb + jn +  0 + lq * 8);
                nv1 = *(const bf16x8*)(vtb + jn + 32 + lq * 8);
                nv2 = *(const bf16x8*)(vtb + jn + 64 + lq * 8);
                nv3 = *(const bf16x8*)(vtb + jn + 96 + lq * 8);
            }
            int j0 = ((jo0 + it) & 1) * 128;
            int lb = jq * 256 + j0;
            bf16x8 a0 = *(const bf16x8*)(sc + sidx(lm, lb +  0 + lq * 8));
            bf16x8 a1 = *(const bf16x8*)(sc + sidx(lm, lb + 32 + lq * 8));
            bf16x8 a2 = *(const bf16x8*)(sc + sidx(lm, lb + 64 + lq * 8));
            bf16x8 a3 = *(const bf16x8*)(sc + sidx(lm, lb + 96 + lq * 8));
            bf16x8 c0 = *(const bf16x8*)(sc + sidx(16 + lm, lb +  0 + lq * 8));
            bf16x8 c1 = *(const bf16x8*)(sc + sidx(16 + lm, lb + 32 + lq * 8));
            bf16x8 c2 = *(const bf16x8*)(sc + sidx(16 + lm, lb + 64 + lq * 8));
            bf16x8 c3 = *(const bf16x8*)(sc + sidx(16 + lm, lb + 96 + lq * 8));
            pa0 = __builtin_amdgcn_mfma_f32_16x16x32_bf16(a0, cv0, pa0, 0, 0, 0);
            pb0 = __builtin_amdgcn_mfma_f32_16x16x32_bf16(c0, cv0, pb0, 0, 0, 0);
            pa1 = __builtin_amdgcn_mfma_f32_16x16x32_bf16(a1, cv1, pa1, 0, 0, 0);
            pb1 = __builtin_amdgcn_mfma_f32_16x16x32_bf16(c1, cv1, pb1, 0, 0, 0);
            pa2 = __builtin_amdgcn_mfma_f32_16x16x32_bf16(a2, cv2, pa2, 0, 0, 0);
            pb2 = __builtin_amdgcn_mfma_f32_16x16x32_bf16(c2, cv2, pb2, 0, 0, 0);
            pa3 = __builtin_amdgcn_mfma_f32_16x16x32_bf16(a3, cv3, pa3, 0, 0, 0);
            pb3 = __builtin_amdgcn_mfma_f32_16x16x32_bf16(c3, cv3, pb3, 0, 0, 0);
            if (jo0 < 1) { cv0 = nv0; cv1 = nv1; cv2 = nv2; cv3 = nv3; }
        }

        // ---- flush partial O to LDS accumulator (frees pa/pb per chunk) ----
        if (ch == 0) {
            #pragma unroll
            for (int r = 0; r < 4; ++r) {
                int m0 = lq * 4 + r, m1 = m0 + 16;
                oacc[jq * 2048 + m0 * 64 + dslice * 16 + lm] = pa0[r] + pa1[r] + pa2[r] + pa3[r];
                oacc[jq * 2048 + m1 * 64 + dslice * 16 + lm] = pb0[r] + pb1[r] + pb2[r] + pb3[r];
            }
        } else {
            #pragma unroll
            for (int r = 0; r < 4; ++r) {
                int m0 = lq * 4 + r, m1 = m0 + 16;
                oacc[jq * 2048 + m0 * 64 + dslice * 16 + lm] += pa0[r] + pa1[r] + pa2[r] + pa3[r];
                oacc[jq * 2048 + m1 * 64 + dslice * 16 + lm] += pb0[r] + pb1[r] + pb2[r] + pb3[r];
            }
        }
        __syncthreads();   // sc reusable by next chunk; oacc stable at exit
    }

    // ---- ml write: per-row softmax sum over both chunks ----
    {
        float s = ssum;
        #pragma unroll
        for (int off = 1; off < 16; off <<= 1) s += __shfl_xor(s, off);
        const int row = tid >> 4;
        if ((tid & 15) == 0) {
            ml[(size_t)slot * 64 + row * 2]     = 0.f;
            ml[(size_t)slot * 64 + row * 2 + 1] = s;
        }
    }

    float* op = opart + (size_t)slot * 2048;
    #pragma unroll
    for (int e = tid; e < 2048; e += 512)
        op[e] = oacc[e] + oacc[2048 + e];
}

// ---------------------------------------------------------------------------
// Merge the two j-half partials: O = (e^{m0-m} O0 + e^{m1-m} O1) / (...)
// (m0 = m1 = 0 with the no-max-sub softmax; formula unchanged.)
// ---------------------------------------------------------------------------
__global__ __launch_bounds__(256)
void attn_combine(const float* __restrict__ opart, const float* __restrict__ ml,
                  short* __restrict__ o_bf)
{
    const int blk = blockIdx.x;           // it*32 + bh
    const int it = blk >> 5, bh = blk & 31;
    const int h = bh & 15, b = bh >> 4;
    __shared__ float wgt[32][2];
    const int tid = threadIdx.x;
    if (tid < 32) {
        float m0 = ml[(size_t)(blk * 2 + 0) * 64 + tid * 2];
        float l0 = ml[(size_t)(blk * 2 + 0) * 64 + tid * 2 + 1];
        float m1 = ml[(size_t)(blk * 2 + 1) * 64 + tid * 2];
        float l1 = ml[(size_t)(blk * 2 + 1) * 64 + tid * 2 + 1];
        float mx = fmaxf(m0, m1);
        float e0 = __expf(m0 - mx), e1 = __expf(m1 - mx);
        float inv = 1.0f / (e0 * l0 + e1 * l1);
        wgt[tid][0] = e0 * inv;
        wgt[tid][1] = e1 * inv;
    }
    __syncthreads();
    const float* p0 = opart + (size_t)(blk * 2 + 0) * 2048;
    const float* p1 = opart + (size_t)(blk * 2 + 1) * 2048;
    #pragma unroll
    for (int e = tid; e < 2048; e += 256) {
        int m = e >> 6, d = e & 63;
        float val = p0[e] * wgt[m][0] + p1[e] * wgt[m][1];
        o_bf[((size_t)(it * 32 + m) * B + b) * (H * DH) + h * DH + d] = f2bs(val);
    }
}

// ---------------------------------------------------------------------------
extern "C" void kernel_launch(void* const* d_in, const int* in_sizes, int n_in,
                              void* d_out, int out_size, void* d_ws, size_t ws_size,
                              hipStream_t stream)
{
    const float* x    = (const float*)d_in[0];   // [S, B, D]
    const float* pemb = (const float*)d_in[1];   // [S+M, D]
    const float* mem  = (const float*)d_in[2];   // [M, B, D]
    const float* u    = (const float*)d_in[3];   // [H, DH]
    const float* v    = (const float*)d_in[4];   // [H, DH]
    const float* Wkv  = (const float*)d_in[5];   // [D, 2*H*DH]
    const float* Wq   = (const float*)d_in[6];   // [D, H*DH]
    const float* Wpos = (const float*)d_in[7];   // [D, H*DH]
    const float* Wout = (const float*)d_in[8];   // [H*DH, D]
    float* out = (float*)d_out;                  // [S, B, D]

    char* p = (char*)d_ws;
    short* a_bf  = (short*)p; p += (size_t)4096 * 1024 * 2;    // mem||x  [0,8M)
    short* p_bf  = (short*)p; p += (size_t)2048 * 1024 * 2;    // [8M,12M)
    short* wkvt  = (short*)p; p += (size_t)2048 * 1024 * 2;    // [12M,16M)
    short* wqt   = (short*)p; p += (size_t)1024 * 1024 * 2;    // [16M,18M)
    short* wpt   = (short*)p; p += (size_t)1024 * 1024 * 2;    // [18M,20M)
    short* wot   = (short*)p; p += (size_t)1024 * 1024 * 2;    // [20M,22M)
    short* k_bf  = (short*)p; p += (size_t)B * H * J * DH * 2;
    short* vt_bf = (short*)p; p += (size_t)B * H * J * DH * 2;
    short* qu_bf = (short*)p; p += (size_t)B * H * S * DH * 2;
    short* qv_bf = (short*)p; p += (size_t)B * H * S * DH * 2;
    short* r_bf  = (short*)p; p += (size_t)H * J * DH * 2;
    short* o_bf  = (short*)p;

    // attn partials alias prep buffers (dead after proj_fused):
    // opart: [0,16M) over a_bf/p_bf/wkvt (2048 slots x 2048 fp32 = 16 MB);
    // ml: [16M,16.5M) over wqt (2048 slots x 64 fp32).
    float* opart = (float*)d_ws;
    float* ml    = (float*)((char*)d_ws + (size_t)16 * 1024 * 1024);

    prep<<<7424, 256, 0, stream>>>(mem, x, pemb, Wkv, Wq, Wpos, Wout,
                                   a_bf, p_bf, wkvt, wqt, wpt, wot);
    proj_fused<<<768, 256, 0, stream>>>(a_bf, p_bf, wkvt, wqt, wpt,
                                        k_bf, vt_bf, qu_bf, qv_bf, r_bf, u, v);
    attn_mfma<<<dim3(B * H, S / 32, 2), 512, 0, stream>>>(
        qu_bf, qv_bf, k_bf, vt_bf, r_bf, opart, ml);
    attn_combine<<<(S / 32) * B * H, 256, 0, stream>>>(opart, ml, o_bf);
    gemm_out<<<dim3(8, 16), 256, 0, stream>>>(o_bf, wot, out);
}

// Round 7
// 293.604 us; speedup vs baseline: 1.0920x; 1.0920x over previous
//
#include <hip/hip_runtime.h>
#include <hip/hip_bf16.h>
#include <hip/hip_fp16.h>
#include <math.h>

#define D    1024
#define H    16
#define DH   64
#define S    1024
#define M    1024
#define B    2
#define J    2048          // M + S
#define SCALE 0.125f       // 1/sqrt(64)
#define SCALE_L2E 0.18033688f   // SCALE * log2(e): softmax uses bare exp2

typedef __attribute__((ext_vector_type(8))) short        bf16x8;
typedef __attribute__((ext_vector_type(4))) short        s16x4;
typedef __attribute__((ext_vector_type(8))) _Float16     h16x8;
typedef __attribute__((ext_vector_type(4))) _Float16     h16x4;
typedef __attribute__((ext_vector_type(8))) unsigned short us8;
typedef __attribute__((ext_vector_type(4))) float        f32x4;

__device__ __forceinline__ short f2bs(float f) {
    __hip_bfloat16 t = __float2bfloat16(f);
    short r; __builtin_memcpy(&r, &t, 2); return r;
}
// fast bf16 pack (round-half-up); inputs finite non-negative (probs)
__device__ __forceinline__ unsigned short f2bf_fast(float f) {
    unsigned int u; __builtin_memcpy(&u, &f, 4);
    return (unsigned short)((u + 0x8000u) >> 16);
}

// async global->LDS, 16 bytes per lane
__device__ __forceinline__ void g2l16(const short* g, short* l) {
    __builtin_amdgcn_global_load_lds(
        (const __attribute__((address_space(1))) unsigned int*)g,
        (__attribute__((address_space(3))) unsigned int*)l, 16, 0, 0);
}

// ---------------------------------------------------------------------------
// prep: blocks [0,6144)  fp32->bf16 flat convert (mem||x -> a_bf, pemb -> p_bf)
//       blocks [6144,7424) 64x64 weight transpose+convert W[k][n] -> Wt[n][k]
// ---------------------------------------------------------------------------
__global__ __launch_bounds__(256)
void prep(const float* __restrict__ mem, const float* __restrict__ x,
          const float* __restrict__ pemb,
          const float* __restrict__ Wkv, const float* __restrict__ Wq,
          const float* __restrict__ Wpos, const float* __restrict__ Wout,
          short* __restrict__ a_bf, short* __restrict__ p_bf,
          short* __restrict__ wkvt, short* __restrict__ wqt,
          short* __restrict__ wpt,  short* __restrict__ wot)
{
    __shared__ float t[64][65];
    int blk = blockIdx.x;
    const int tid = threadIdx.x;
    if (blk < 6144) {
        const int idx = (blk * 256 + tid) * 4;
        const int TWO_M = 2 * 1024 * 1024;
        float4 v; short* dst;
        if (idx < TWO_M)          { v = *(const float4*)(mem  + idx);           dst = a_bf + idx; }
        else if (idx < 2 * TWO_M) { v = *(const float4*)(x    + idx - TWO_M);   dst = a_bf + idx; }
        else                      { v = *(const float4*)(pemb + idx - 2*TWO_M); dst = p_bf + idx - 2*TWO_M; }
        s16x4 o = { f2bs(v.x), f2bs(v.y), f2bs(v.z), f2bs(v.w) };
        *(s16x4*)dst = o;
        return;
    }
    blk -= 6144;
    const float* src; short* dst; int N, t0;
    if (blk < 512)       { src = Wkv;  dst = wkvt; N = 2048; t0 = blk; }
    else if (blk < 768)  { src = Wq;   dst = wqt;  N = 1024; t0 = blk - 512; }
    else if (blk < 1024) { src = Wpos; dst = wpt;  N = 1024; t0 = blk - 768; }
    else                 { src = Wout; dst = wot;  N = 1024; t0 = blk - 1024; }
    const int ntn = N >> 6;
    const int k0 = (t0 / ntn) * 64, n0 = (t0 % ntn) * 64;
    #pragma unroll
    for (int e = tid; e < 4096; e += 256) {
        int r = e >> 6, c = e & 63;
        t[r][c] = src[(size_t)(k0 + r) * N + n0 + c];
    }
    __syncthreads();
    #pragma unroll
    for (int e = tid; e < 4096; e += 256) {
        int nr = e >> 6, kc = e & 63;
        dst[(size_t)(n0 + nr) * 1024 + k0 + kc] = f2bs(t[kc][nr]);
    }
}

// ---------------------------------------------------------------------------
// Shared MFMA GEMM core: BM=BN=128, BK=64, 256 thr, K=1024.
// ---------------------------------------------------------------------------
__device__ __forceinline__ void gemm_core(const short* __restrict__ A,
                                          const short* __restrict__ Bt,
                                          short* As, short* Bs,
                                          int bm0, int bn0, int tid,
                                          f32x4 acc[4][4])
{
    const int w    = tid >> 6;
    const int wy   = w >> 1, wx = w & 1;
    const int lane = tid & 63;
    const int lm   = lane & 15;
    const int lq   = lane >> 4;

    for (int k0 = 0; k0 < 1024; k0 += 64) {
        const short* Ab = A  + (size_t)bm0 * 1024 + k0;
        const short* Bb = Bt + (size_t)bn0 * 1024 + k0;
        #pragma unroll
        for (int t = 0; t < 4; ++t) {
            int s = t * 256 + tid;
            int r = s >> 3, c = s & 7;
            int cg = c ^ (r & 7);
            g2l16(Ab + r * 1024 + cg * 8, As + s * 8);
            g2l16(Bb + r * 1024 + cg * 8, Bs + s * 8);
        }
        __syncthreads();
        #pragma unroll
        for (int kk = 0; kk < 2; ++kk) {
            bf16x8 af[4], bg[4];
            #pragma unroll
            for (int r4 = 0; r4 < 4; ++r4) {
                int ar = wy * 64 + r4 * 16 + lm;
                int kc = kk * 4 + lq;
                af[r4] = *(const bf16x8*)(As + ((ar << 3) + (kc ^ (ar & 7))) * 8);
            }
            #pragma unroll
            for (int c4 = 0; c4 < 4; ++c4) {
                int br = wx * 64 + c4 * 16 + lm;
                int kc = kk * 4 + lq;
                bg[c4] = *(const bf16x8*)(Bs + ((br << 3) + (kc ^ (br & 7))) * 8);
            }
            #pragma unroll
            for (int r4 = 0; r4 < 4; ++r4)
                #pragma unroll
                for (int c4 = 0; c4 < 4; ++c4)
                    acc[r4][c4] = __builtin_amdgcn_mfma_f32_16x16x32_bf16(
                        af[r4], bg[c4], acc[r4][c4], 0, 0, 0);
        }
        __syncthreads();
    }
}

// ---------------------------------------------------------------------------
// Fused kv/q/r projections. R16: qu/qv scaled by SCALE*log2(e) so the attn
// softmax is a bare exp2 (saves one VALU mul per score element).
// ---------------------------------------------------------------------------
__global__ __launch_bounds__(256)
void proj_fused(const short* __restrict__ a_bf, const short* __restrict__ p_bf,
                const short* __restrict__ wkvt, const short* __restrict__ wqt,
                const short* __restrict__ wpt,
                short* __restrict__ k_bf, short* __restrict__ vt_bf,
                short* __restrict__ qu_bf, short* __restrict__ qv_bf,
                short* __restrict__ r_bf,
                const float* __restrict__ uvec, const float* __restrict__ vvec)
{
    __shared__ __align__(16) short As[128 * 64];
    __shared__ __align__(16) short Bs[128 * 64];

    int blk = blockIdx.x;
    int mode, bx, by;
    const short *A, *Bt;
    if (blk < 512)      { bx = blk & 15; by = blk >> 4;
                          if (bx >= 8) { mode = 4; A = wkvt; Bt = a_bf; }   // swapped V
                          else         { mode = 0; A = a_bf; Bt = wkvt; } }
    else if (blk < 640) { int b2 = blk - 512; mode = 1; bx = b2 & 7; by = b2 >> 3;
                          A = a_bf + (size_t)2048 * 1024; Bt = wqt; }
    else                { int b3 = blk - 640; mode = 2; bx = b3 & 7; by = b3 >> 3;
                          A = p_bf; Bt = wpt; }
    const int bn0 = (mode == 4) ? by * 128 : bx * 128;
    const int bm0 = (mode == 4) ? bx * 128 : by * 128;
    const int tid = threadIdx.x;
    const int w = tid >> 6, wy = w >> 1, wx = w & 1;
    const int lane = tid & 63, lm = lane & 15, lq = lane >> 4;

    f32x4 acc[4][4];
    #pragma unroll
    for (int r = 0; r < 4; ++r)
        #pragma unroll
        for (int c = 0; c < 4; ++c) acc[r][c] = (f32x4){0.f, 0.f, 0.f, 0.f};

    gemm_core(A, Bt, As, Bs, bm0, bn0, tid, acc);

    #pragma unroll
    for (int r4 = 0; r4 < 4; ++r4) {
        #pragma unroll
        for (int c4 = 0; c4 < 4; ++c4) {
            const int n = bn0 + wx * 64 + c4 * 16 + lm;
            float ubias = 0.f, vbias = 0.f;
            if (mode == 1) { ubias = uvec[n]; vbias = vvec[n]; }
            #pragma unroll
            for (int reg = 0; reg < 4; ++reg) {
                const int m = bm0 + wy * 64 + r4 * 16 + lq * 4 + reg;
                const float val = acc[r4][c4][reg];
                if (mode == 0) {
                    int j = m >> 1, b = m & 1;
                    int h = n >> 6, d = n & 63;
                    k_bf[(((size_t)b * H + h) * J + j) * DH + d] = f2bs(val);
                } else if (mode == 4) {
                    int n2 = m - 1024, h = n2 >> 6, d = n2 & 63;
                    int j = n >> 1, b = n & 1;
                    vt_bf[(((size_t)b * H + h) * DH + d) * J + j] = f2bs(val);
                } else if (mode == 1) {
                    int i = m >> 1, b = m & 1;
                    int h = n >> 6, d = n & 63;
                    size_t o = (((size_t)b * H + h) * S + i) * DH + d;
                    qu_bf[o] = f2bs((val + ubias) * SCALE_L2E);
                    qv_bf[o] = f2bs((val + vbias) * SCALE_L2E);
                } else {
                    int h = n >> 6, d = n & 63;
                    r_bf[((size_t)h * J + m) * DH + d] = f2bs(val);
                }
            }
        }
    }
}

// ---------------------------------------------------------------------------
// Output projection: M=2048, N=1024, fp32 out.
// ---------------------------------------------------------------------------
__global__ __launch_bounds__(256)
void gemm_out(const short* __restrict__ A, const short* __restrict__ Bt,
              float* __restrict__ out)
{
    __shared__ __align__(16) short As[128 * 64];
    __shared__ __align__(16) short Bs[128 * 64];
    const int bn0 = blockIdx.x * 128, bm0 = blockIdx.y * 128;
    const int tid = threadIdx.x;
    const int w = tid >> 6, wy = w >> 1, wx = w & 1;
    const int lane = tid & 63, lm = lane & 15, lq = lane >> 4;

    f32x4 acc[4][4];
    #pragma unroll
    for (int r = 0; r < 4; ++r)
        #pragma unroll
        for (int c = 0; c < 4; ++c) acc[r][c] = (f32x4){0.f, 0.f, 0.f, 0.f};

    gemm_core(A, Bt, As, Bs, bm0, bn0, tid, acc);

    #pragma unroll
    for (int r4 = 0; r4 < 4; ++r4)
        #pragma unroll
        for (int c4 = 0; c4 < 4; ++c4) {
            const int n = bn0 + wx * 64 + c4 * 16 + lm;
            #pragma unroll
            for (int reg = 0; reg < 4; ++reg) {
                const int m = bm0 + wy * 64 + r4 * 16 + lq * 4 + reg;
                out[(size_t)m * 1024 + n] = acc[r4][c4][reg];
            }
        }
}

// ---------------------------------------------------------------------------
// MFMA attention: block = 32 query rows x one (b,h) x one j-half. 512 thr,
// 64 KB LDS, 2 blocks/CU (R0 structure + R14 b64 content RMW).
// R16 changes:
//  (1) XCD-aware 1D grid: bh was blockIdx.x (fastest) -> consecutive blocks
//      had different (b,h) and round-robined over XCDs, so each XCD's
//      resident blocks spanned ~all 32 K/V/r streams (24 MB >> 4 MB L2):
//      every tile load was an L2 MISS (~500+ cyc to L3) — the stall that
//      made occupancy experiments R12/R13/R15 futile. New map: XCD = L&7
//      owns 4 contiguous bh streams, one at a time (64 blocks/stream =
//      exactly one XCD's 2-deep residency) -> ws/XCD ~1.5 MB -> L2 hits.
//  (2) Depth-2 rolling register prefetch in pos/content loops (VGPR is free
//      up to 128: LDS caps residency at 2 blocks/CU regardless).
//  (3) Softmax is bare exp2 (scale folded into qu/qv upstream).
// ---------------------------------------------------------------------------
__device__ __forceinline__ int sidx(int m, int c) {   // m in [0,32), c in [0,1024)
    return (m << 10) + (c ^ (m << 3));
}

__global__ __launch_bounds__(512)
void attn_mfma(const short* __restrict__ qu_bf, const short* __restrict__ qv_bf,
               const short* __restrict__ k_bf,  const short* __restrict__ vt_bf,
               const short* __restrict__ r_bf,
               float* __restrict__ opart, float* __restrict__ ml)
{
    __shared__ unsigned short sc[32 * 1024];   // 64 KB
    __half* sch = (__half*)sc;
    float*  scF = (float*)sc;                  // reused after PV reads

    // XCD-aware decode: L&7 = XCD (round-robin dispatch); each XCD owns
    // bh in [4*xcd, 4*xcd+4), processed stream-by-stream.
    const int L   = blockIdx.x;
    const int xcd = L & 7;
    const int pp  = L >> 3;                    // 0..255
    const int bh  = (xcd << 2) + (pp >> 6);    // 4 streams per XCD
    const int sub = pp & 63;
    const int it  = sub >> 1;
    const int jh  = sub & 1;

    const int i0  = it * 32;
    const int cbeg = jh << 10, cend = cbeg + 1024;
    const int h   = bh & (H - 1);
    const int tid = threadIdx.x;
    const int w    = tid >> 6;       // 0..7
    const int lane = tid & 63;
    const int lm   = lane & 15;
    const int lq   = lane >> 4;
    const int slot = (it * 32 + bh) * 2 + jh;

    // ---- A fragments ----
    const short* qup0 = qu_bf + ((size_t)(bh * S + i0 + lm)) * DH + lq * 8;
    const short* qup1 = qup0 + 16 * DH;
    bf16x8 au00 = *(const bf16x8*)qup0,        au01 = *(const bf16x8*)(qup0 + 32);
    bf16x8 au10 = *(const bf16x8*)qup1,        au11 = *(const bf16x8*)(qup1 + 32);
    const short* qvp0 = qv_bf + ((size_t)(bh * S + i0 + lm)) * DH + lq * 8;
    const short* qvp1 = qvp0 + 16 * DH;
    bf16x8 av00 = *(const bf16x8*)qvp0,        av01 = *(const bf16x8*)(qvp0 + 32);
    bf16x8 av10 = *(const bf16x8*)qvp1,        av11 = *(const bf16x8*)(qvp1 + 32);
    int r1a = i0 + 1 + lm;  if (r1a > S - 1) r1a = S - 1;   // clamped rows masked
    int r1b = i0 + 17 + lm; if (r1b > S - 1) r1b = S - 1;
    const short* qwp0 = qv_bf + ((size_t)(bh * S + r1a)) * DH + lq * 8;
    const short* qwp1 = qv_bf + ((size_t)(bh * S + r1b)) * DH + lq * 8;
    bf16x8 aw00 = *(const bf16x8*)qwp0,        aw01 = *(const bf16x8*)(qwp0 + 32);
    bf16x8 aw10 = *(const bf16x8*)qwp1,        aw11 = *(const bf16x8*)(qwp1 + 32);

    // ---- zero the pos hole column: row m, col i0+m+1025 (if in window) ----
    if (tid < 32) {
        int hole = i0 + tid + 1025;
        if (hole >= cbeg && hole < cend) sc[sidx(tid, hole - cbeg)] = 0;
    }

    const short* rbase = r_bf + (size_t)h * J * DH;

    // ---- pos main: col = i0 + 16t + lm + m - 1023; depth-2 prefetch ----
    {
        int tmp = cbeg + 977 - i0;
        int tlo = tmp > 0 ? ((tmp + 15) >> 4) : 0;
        int thi = (cend + 1022 - i0) >> 4; if (thi > 127) thi = 127;
        int t = tlo + w;
        if (t <= thi) {
            const short* rp = rbase + (size_t)(t * 16 + lm) * DH + lq * 8;
            bf16x8 b0 = *(const bf16x8*)rp, b1 = *(const bf16x8*)(rp + 32);
            bf16x8 p0, p1;
            if (t + 8 <= thi) {
                const short* rp2 = rbase + (size_t)((t + 8) * 16 + lm) * DH + lq * 8;
                p0 = *(const bf16x8*)rp2; p1 = *(const bf16x8*)(rp2 + 32);
            }
            for (; t <= thi; t += 8) {
                bf16x8 n0, n1;
                if (t + 16 <= thi) {
                    const short* rpn = rbase + (size_t)((t + 16) * 16 + lm) * DH + lq * 8;
                    n0 = *(const bf16x8*)rpn; n1 = *(const bf16x8*)(rpn + 32);
                }
                f32x4 c0 = {0.f,0.f,0.f,0.f}, c1 = {0.f,0.f,0.f,0.f};
                c0 = __builtin_amdgcn_mfma_f32_16x16x32_bf16(av00, b0, c0, 0, 0, 0);
                c1 = __builtin_amdgcn_mfma_f32_16x16x32_bf16(av10, b0, c1, 0, 0, 0);
                c0 = __builtin_amdgcn_mfma_f32_16x16x32_bf16(av01, b1, c0, 0, 0, 0);
                c1 = __builtin_amdgcn_mfma_f32_16x16x32_bf16(av11, b1, c1, 0, 0, 0);
                int cb = i0 + t * 16 + lm - 1023 - cbeg;     // local col for m=0
                int base = i0 + 16 * t - 1023;               // scalar col_min
                if (base >= cbeg && base + 46 < cend) {
                    #pragma unroll
                    for (int r = 0; r < 4; ++r) {
                        int m0 = lq * 4 + r, m1 = m0 + 16;
                        sch[sidx(m0, cb + m0)] = __float2half(c0[r]);
                        sch[sidx(m1, cb + m1)] = __float2half(c1[r]);
                    }
                } else {
                    #pragma unroll
                    for (int r = 0; r < 4; ++r) {
                        int m0 = lq * 4 + r, m1 = m0 + 16;
                        int cA = cb + m0, cB = cb + m1;
                        if (cA >= 0 && cA < 1024) sch[sidx(m0, cA)] = __float2half(c0[r]);
                        if (cB >= 0 && cB < 1024) sch[sidx(m1, cB)] = __float2half(c1[r]);
                    }
                }
                b0 = p0; b1 = p1; p0 = n0; p1 = n1;
            }
        }
    }

    // ---- pos wrap: col = i0 + 16t + lm + m + 1026, rows Qv[i+1]; depth-2 ----
    {
        int tmpw = cbeg - 1072 - i0;
        int tlw = tmpw > 0 ? ((tmpw + 15) >> 4) : 0;
        int thw = (cend - 1027 - i0) >> 4; if (thw > 127) thw = 127;
        int t = tlw + w;
        if (t <= thw) {
            const short* rp = rbase + (size_t)(t * 16 + lm) * DH + lq * 8;
            bf16x8 b0 = *(const bf16x8*)rp, b1 = *(const bf16x8*)(rp + 32);
            bf16x8 p0, p1;
            if (t + 8 <= thw) {
                const short* rp2 = rbase + (size_t)((t + 8) * 16 + lm) * DH + lq * 8;
                p0 = *(const bf16x8*)rp2; p1 = *(const bf16x8*)(rp2 + 32);
            }
            for (; t <= thw; t += 8) {
                bf16x8 n0, n1;
                if (t + 16 <= thw) {
                    const short* rpn = rbase + (size_t)((t + 16) * 16 + lm) * DH + lq * 8;
                    n0 = *(const bf16x8*)rpn; n1 = *(const bf16x8*)(rpn + 32);
                }
                f32x4 c0 = {0.f,0.f,0.f,0.f}, c1 = {0.f,0.f,0.f,0.f};
                c0 = __builtin_amdgcn_mfma_f32_16x16x32_bf16(aw00, b0, c0, 0, 0, 0);
                c1 = __builtin_amdgcn_mfma_f32_16x16x32_bf16(aw10, b0, c1, 0, 0, 0);
                c0 = __builtin_amdgcn_mfma_f32_16x16x32_bf16(aw01, b1, c0, 0, 0, 0);
                c1 = __builtin_amdgcn_mfma_f32_16x16x32_bf16(aw11, b1, c1, 0, 0, 0);
                int cb = i0 + t * 16 + lm + 1026 - cbeg;
                int base = i0 + 16 * t + 1026;
                if (base >= cbeg && base + 46 < cend) {
                    #pragma unroll
                    for (int r = 0; r < 4; ++r) {
                        int m0 = lq * 4 + r, m1 = m0 + 16;
                        sch[sidx(m0, cb + m0)] = __float2half(c0[r]);
                        sch[sidx(m1, cb + m1)] = __float2half(c1[r]);
                    }
                } else {
                    #pragma unroll
                    for (int r = 0; r < 4; ++r) {
                        int m0 = lq * 4 + r, m1 = m0 + 16;
                        int cA = cb + m0, cB = cb + m1;
                        if (cA >= 0 && cA < 1024) sch[sidx(m0, cA)] = __float2half(c0[r]);
                        if (cB >= 0 && cB < 1024) sch[sidx(m1, cB)] = __float2half(c1[r]);
                    }
                }
                b0 = p0; b1 = p1; p0 = n0; p1 = n1;
            }
        }
    }

    // ---- prefetch first two content K-tiles before the barrier ----
    const short* kbase = k_bf + (size_t)bh * J * DH;
    bf16x8 kb0, kb1, kc0, kc1;
    {
        int t0 = jh * 64 + w + 8 * ((it) & 7);
        int t1 = jh * 64 + w + 8 * ((1 + it) & 7);
        const short* kp0 = kbase + (size_t)(t0 * 16 + lm) * DH + lq * 8;
        const short* kp1 = kbase + (size_t)(t1 * 16 + lm) * DH + lq * 8;
        kb0 = *(const bf16x8*)kp0; kb1 = *(const bf16x8*)(kp0 + 32);
        kc0 = *(const bf16x8*)kp1; kc1 = *(const bf16x8*)(kp1 + 32);
    }
    __syncthreads();

    // ---- content: swapped-operand MFMA (A=K, B=Q), b64 score RMW,
    //      depth-2 rolling K prefetch ----
    #pragma unroll 1
    for (int g = 0; g < 8; ++g) {
        bf16x8 nb0, nb1;
        if (g + 2 < 8) {
            int u = jh * 64 + w + 8 * ((g + 2 + it) & 7);
            const short* np = kbase + (size_t)(u * 16 + lm) * DH + lq * 8;
            nb0 = *(const bf16x8*)np; nb1 = *(const bf16x8*)(np + 32);
        }
        int t = jh * 64 + w + 8 * ((g + it) & 7);
        int lc = t * 16 - cbeg;                  // 16-aligned local col base
        int aA = sidx(lm,      lc + lq * 4);     // 4 consecutive u16, 8B-aligned
        int aB = sidx(lm + 16, lc + lq * 4);
        h16x4 hA = *(const h16x4*)(sc + aA);
        h16x4 hB = *(const h16x4*)(sc + aB);
        f32x4 c0, c1;
        #pragma unroll
        for (int r = 0; r < 4; ++r) { c0[r] = (float)hA[r]; c1[r] = (float)hB[r]; }
        c0 = __builtin_amdgcn_mfma_f32_16x16x32_bf16(kb0, au00, c0, 0, 0, 0);
        c1 = __builtin_amdgcn_mfma_f32_16x16x32_bf16(kb0, au10, c1, 0, 0, 0);
        c0 = __builtin_amdgcn_mfma_f32_16x16x32_bf16(kb1, au01, c0, 0, 0, 0);
        c1 = __builtin_amdgcn_mfma_f32_16x16x32_bf16(kb1, au11, c1, 0, 0, 0);
        h16x4 oA, oB;
        #pragma unroll
        for (int r = 0; r < 4; ++r) { oA[r] = (_Float16)c0[r]; oB[r] = (_Float16)c1[r]; }
        *(h16x4*)(sc + aA) = oA;
        *(h16x4*)(sc + aB) = oB;
        kb0 = kc0; kb1 = kc1; kc0 = nb0; kc1 = nb1;
    }

    // ---- prefetch first PV V-chunk before the barrier ----
    const int dslice = w & 3, jq = w >> 2;
    const short* vtb = vt_bf + ((size_t)bh * DH + dslice * 16 + lm) * J + cbeg + jq * 512;
    bf16x8 cv0, cv1, cv2, cv3;
    {
        int j0 = (it & 3) * 128;
        cv0 = *(const bf16x8*)(vtb + j0 +  0 + lq * 8);
        cv1 = *(const bf16x8*)(vtb + j0 + 32 + lq * 8);
        cv2 = *(const bf16x8*)(vtb + j0 + 64 + lq * 8);
        cv3 = *(const bf16x8*)(vtb + j0 + 96 + lq * 8);
    }
    __syncthreads();

    // ---- softmax: bare exp2 (scale folded upstream); fp16->bf16; sum ----
    {
        const int row = tid >> 4;            // 0..31
        const int cw  = (tid & 15) * 8;
        float ssum = 0.f;
        #pragma unroll
        for (int c = cw; c < 1024; c += 128) {
            int idx = sidx(row, c);
            h16x8 v = *(const h16x8*)(sc + idx);
            us8 e;
            #pragma unroll
            for (int k = 0; k < 8; ++k) {
                float ex = __builtin_amdgcn_exp2f((float)v[k]);
                ssum += ex;
                e[k] = f2bf_fast(ex);
            }
            *(us8*)(sc + idx) = e;
        }
        #pragma unroll
        for (int off = 1; off < 16; off <<= 1) ssum += __shfl_xor(ssum, off);
        if ((tid & 15) == 0) {
            ml[(size_t)slot * 64 + row * 2]     = 0.f;
            ml[(size_t)slot * 64 + row * 2 + 1] = ssum;
        }
    }
    __syncthreads();

    // ---- PV: wave -> d-slice (w&3), j-quarter (w>>2); rolling V prefetch ----
    f32x4 pa0 = {0.f,0.f,0.f,0.f}, pa1 = {0.f,0.f,0.f,0.f};
    f32x4 pa2 = {0.f,0.f,0.f,0.f}, pa3 = {0.f,0.f,0.f,0.f};
    f32x4 pb0 = {0.f,0.f,0.f,0.f}, pb1 = {0.f,0.f,0.f,0.f};
    f32x4 pb2 = {0.f,0.f,0.f,0.f}, pb3 = {0.f,0.f,0.f,0.f};
    #pragma unroll 1
    for (int jo0 = 0; jo0 < 4; ++jo0) {       // 128 local j per iteration
        bf16x8 nv0, nv1, nv2, nv3;
        if (jo0 < 3) {
            int jn = ((jo0 + 1 + it) & 3) * 128;
            nv0 = *(const bf16x8*)(vtb + jn +  0 + lq * 8);
            nv1 = *(const bf16x8*)(vtb + jn + 32 + lq * 8);
            nv2 = *(const bf16x8*)(vtb + jn + 64 + lq * 8);
            nv3 = *(const bf16x8*)(vtb + jn + 96 + lq * 8);
        }
        int j0 = ((jo0 + it) & 3) * 128;
        int lb = jq * 512 + j0;
        bf16x8 a0 = *(const bf16x8*)(sc + sidx(lm, lb +  0 + lq * 8));
        bf16x8 a1 = *(const bf16x8*)(sc + sidx(lm, lb + 32 + lq * 8));
        bf16x8 a2 = *(const bf16x8*)(sc + sidx(lm, lb + 64 + lq * 8));
        bf16x8 a3 = *(const bf16x8*)(sc + sidx(lm, lb + 96 + lq * 8));
        bf16x8 c0 = *(const bf16x8*)(sc + sidx(16 + lm, lb +  0 + lq * 8));
        bf16x8 c1 = *(const bf16x8*)(sc + sidx(16 + lm, lb + 32 + lq * 8));
        bf16x8 c2 = *(const bf16x8*)(sc + sidx(16 + lm, lb + 64 + lq * 8));
        bf16x8 c3 = *(const bf16x8*)(sc + sidx(16 + lm, lb + 96 + lq * 8));
        pa0 = __builtin_amdgcn_mfma_f32_16x16x32_bf16(a0, cv0, pa0, 0, 0, 0);
        pb0 = __builtin_amdgcn_mfma_f32_16x16x32_bf16(c0, cv0, pb0, 0, 0, 0);
        pa1 = __builtin_amdgcn_mfma_f32_16x16x32_bf16(a1, cv1, pa1, 0, 0, 0);
        pb1 = __builtin_amdgcn_mfma_f32_16x16x32_bf16(c1, cv1, pb1, 0, 0, 0);
        pa2 = __builtin_amdgcn_mfma_f32_16x16x32_bf16(a2, cv2, pa2, 0, 0, 0);
        pb2 = __builtin_amdgcn_mfma_f32_16x16x32_bf16(c2, cv2, pb2, 0, 0, 0);
        pa3 = __builtin_amdgcn_mfma_f32_16x16x32_bf16(a3, cv3, pa3, 0, 0, 0);
        pb3 = __builtin_amdgcn_mfma_f32_16x16x32_bf16(c3, cv3, pb3, 0, 0, 0);
        if (jo0 < 3) { cv0 = nv0; cv1 = nv1; cv2 = nv2; cv3 = nv3; }
    }
    __syncthreads();   // all probs read; sc reusable as float scratch

    #pragma unroll
    for (int r = 0; r < 4; ++r) {
        int m0 = lq * 4 + r, m1 = m0 + 16;
        scF[jq * 2048 + m0 * 64 + dslice * 16 + lm] = pa0[r] + pa1[r] + pa2[r] + pa3[r];
        scF[jq * 2048 + m1 * 64 + dslice * 16 + lm] = pb0[r] + pb1[r] + pb2[r] + pb3[r];
    }
    __syncthreads();

    float* op = opart + (size_t)slot * 2048;
    #pragma unroll
    for (int e = tid; e < 2048; e += 512)
        op[e] = scF[e] + scF[2048 + e];
}

// ---------------------------------------------------------------------------
// Merge the two j-half partials: O = (e^{m0-m} O0 + e^{m1-m} O1) / (...)
// (m0 = m1 = 0 with the no-max-sub softmax; formula unchanged.)
// ---------------------------------------------------------------------------
__global__ __launch_bounds__(256)
void attn_combine(const float* __restrict__ opart, const float* __restrict__ ml,
                  short* __restrict__ o_bf)
{
    const int blk = blockIdx.x;           // it*32 + bh
    const int it = blk >> 5, bh = blk & 31;
    const int h = bh & 15, b = bh >> 4;
    __shared__ float wgt[32][2];
    const int tid = threadIdx.x;
    if (tid < 32) {
        float m0 = ml[(size_t)(blk * 2 + 0) * 64 + tid * 2];
        float l0 = ml[(size_t)(blk * 2 + 0) * 64 + tid * 2 + 1];
        float m1 = ml[(size_t)(blk * 2 + 1) * 64 + tid * 2];
        float l1 = ml[(size_t)(blk * 2 + 1) * 64 + tid * 2 + 1];
        float mx = fmaxf(m0, m1);
        float e0 = __expf(m0 - mx), e1 = __expf(m1 - mx);
        float inv = 1.0f / (e0 * l0 + e1 * l1);
        wgt[tid][0] = e0 * inv;
        wgt[tid][1] = e1 * inv;
    }
    __syncthreads();
    const float* p0 = opart + (size_t)(blk * 2 + 0) * 2048;
    const float* p1 = opart + (size_t)(blk * 2 + 1) * 2048;
    #pragma unroll
    for (int e = tid; e < 2048; e += 256) {
        int m = e >> 6, d = e & 63;
        float val = p0[e] * wgt[m][0] + p1[e] * wgt[m][1];
        o_bf[((size_t)(it * 32 + m) * B + b) * (H * DH) + h * DH + d] = f2bs(val);
    }
}

// ---------------------------------------------------------------------------
extern "C" void kernel_launch(void* const* d_in, const int* in_sizes, int n_in,
                              void* d_out, int out_size, void* d_ws, size_t ws_size,
                              hipStream_t stream)
{
    const float* x    = (const float*)d_in[0];   // [S, B, D]
    const float* pemb = (const float*)d_in[1];   // [S+M, D]
    const float* mem  = (const float*)d_in[2];   // [M, B, D]
    const float* u    = (const float*)d_in[3];   // [H, DH]
    const float* v    = (const float*)d_in[4];   // [H, DH]
    const float* Wkv  = (const float*)d_in[5];   // [D, 2*H*DH]
    const float* Wq   = (const float*)d_in[6];   // [D, H*DH]
    const float* Wpos = (const float*)d_in[7];   // [D, H*DH]
    const float* Wout = (const float*)d_in[8];   // [H*DH, D]
    float* out = (float*)d_out;                  // [S, B, D]

    char* p = (char*)d_ws;
    short* a_bf  = (short*)p; p += (size_t)4096 * 1024 * 2;    // mem||x  [0,8M)
    short* p_bf  = (short*)p; p += (size_t)2048 * 1024 * 2;    // [8M,12M)
    short* wkvt  = (short*)p; p += (size_t)2048 * 1024 * 2;    // [12M,16M)
    short* wqt   = (short*)p; p += (size_t)1024 * 1024 * 2;    // [16M,18M)
    short* wpt   = (short*)p; p += (size_t)1024 * 1024 * 2;    // [18M,20M)
    short* wot   = (short*)p; p += (size_t)1024 * 1024 * 2;    // [20M,22M)
    short* k_bf  = (short*)p; p += (size_t)B * H * J * DH * 2;
    short* vt_bf = (short*)p; p += (size_t)B * H * J * DH * 2;
    short* qu_bf = (short*)p; p += (size_t)B * H * S * DH * 2;
    short* qv_bf = (short*)p; p += (size_t)B * H * S * DH * 2;
    short* r_bf  = (short*)p; p += (size_t)H * J * DH * 2;
    short* o_bf  = (short*)p;

    // attn partials alias prep buffers (dead after proj_fused):
    // opart: [0,16M) over a_bf/p_bf/wkvt (2048 slots x 2048 fp32 = 16 MB);
    // ml: [16M,16.5M) over wqt (2048 slots x 64 fp32).
    float* opart = (float*)d_ws;
    float* ml    = (float*)((char*)d_ws + (size_t)16 * 1024 * 1024);

    prep<<<7424, 256, 0, stream>>>(mem, x, pemb, Wkv, Wq, Wpos, Wout,
                                   a_bf, p_bf, wkvt, wqt, wpt, wot);
    proj_fused<<<768, 256, 0, stream>>>(a_bf, p_bf, wkvt, wqt, wpt,
                                        k_bf, vt_bf, qu_bf, qv_bf, r_bf, u, v);
    attn_mfma<<<2048, 512, 0, stream>>>(
        qu_bf, qv_bf, k_bf, vt_bf, r_bf, opart, ml);
    attn_combine<<<(S / 32) * B * H, 256, 0, stream>>>(opart, ml, o_bf);
    gemm_out<<<dim3(8, 16), 256, 0, stream>>>(o_bf, wot, out);
}

// Round 8
// 292.357 us; speedup vs baseline: 1.0966x; 1.0043x over previous
//
#include <hip/hip_runtime.h>
#include <hip/hip_bf16.h>
#include <hip/hip_fp16.h>
#include <math.h>

#define D    1024
#define H    16
#define DH   64
#define S    1024
#define M    1024
#define B    2
#define J    2048          // M + S
#define SCALE 0.125f       // 1/sqrt(64)
#define SCALE_L2E 0.18033688f   // SCALE * log2(e): softmax uses bare exp2

typedef __attribute__((ext_vector_type(8))) short        bf16x8;
typedef __attribute__((ext_vector_type(4))) short        s16x4;
typedef __attribute__((ext_vector_type(8))) _Float16     h16x8;
typedef __attribute__((ext_vector_type(4))) _Float16     h16x4;
typedef __attribute__((ext_vector_type(8))) unsigned short us8;
typedef __attribute__((ext_vector_type(4))) unsigned short us4;
typedef __attribute__((ext_vector_type(4))) float        f32x4;

__device__ __forceinline__ short f2bs(float f) {
    __hip_bfloat16 t = __float2bfloat16(f);
    short r; __builtin_memcpy(&r, &t, 2); return r;
}
// fast bf16 pack (round-half-up); inputs finite non-negative (probs)
__device__ __forceinline__ unsigned short f2bf_fast(float f) {
    unsigned int u; __builtin_memcpy(&u, &f, 4);
    return (unsigned short)((u + 0x8000u) >> 16);
}

// async global->LDS, 16 bytes per lane
__device__ __forceinline__ void g2l16(const short* g, short* l) {
    __builtin_amdgcn_global_load_lds(
        (const __attribute__((address_space(1))) unsigned int*)g,
        (__attribute__((address_space(3))) unsigned int*)l, 16, 0, 0);
}

// ---------------------------------------------------------------------------
// prep: blocks [0,6144)  fp32->bf16 flat convert (mem||x -> a_bf, pemb -> p_bf)
//       blocks [6144,7424) 64x64 weight transpose+convert W[k][n] -> Wt[n][k]
// ---------------------------------------------------------------------------
__global__ __launch_bounds__(256)
void prep(const float* __restrict__ mem, const float* __restrict__ x,
          const float* __restrict__ pemb,
          const float* __restrict__ Wkv, const float* __restrict__ Wq,
          const float* __restrict__ Wpos, const float* __restrict__ Wout,
          short* __restrict__ a_bf, short* __restrict__ p_bf,
          short* __restrict__ wkvt, short* __restrict__ wqt,
          short* __restrict__ wpt,  short* __restrict__ wot)
{
    __shared__ float t[64][65];
    int blk = blockIdx.x;
    const int tid = threadIdx.x;
    if (blk < 6144) {
        const int idx = (blk * 256 + tid) * 4;
        const int TWO_M = 2 * 1024 * 1024;
        float4 v; short* dst;
        if (idx < TWO_M)          { v = *(const float4*)(mem  + idx);           dst = a_bf + idx; }
        else if (idx < 2 * TWO_M) { v = *(const float4*)(x    + idx - TWO_M);   dst = a_bf + idx; }
        else                      { v = *(const float4*)(pemb + idx - 2*TWO_M); dst = p_bf + idx - 2*TWO_M; }
        s16x4 o = { f2bs(v.x), f2bs(v.y), f2bs(v.z), f2bs(v.w) };
        *(s16x4*)dst = o;
        return;
    }
    blk -= 6144;
    const float* src; short* dst; int N, t0;
    if (blk < 512)       { src = Wkv;  dst = wkvt; N = 2048; t0 = blk; }
    else if (blk < 768)  { src = Wq;   dst = wqt;  N = 1024; t0 = blk - 512; }
    else if (blk < 1024) { src = Wpos; dst = wpt;  N = 1024; t0 = blk - 768; }
    else                 { src = Wout; dst = wot;  N = 1024; t0 = blk - 1024; }
    const int ntn = N >> 6;
    const int k0 = (t0 / ntn) * 64, n0 = (t0 % ntn) * 64;
    #pragma unroll
    for (int e = tid; e < 4096; e += 256) {
        int r = e >> 6, c = e & 63;
        t[r][c] = src[(size_t)(k0 + r) * N + n0 + c];
    }
    __syncthreads();
    #pragma unroll
    for (int e = tid; e < 4096; e += 256) {
        int nr = e >> 6, kc = e & 63;
        dst[(size_t)(n0 + nr) * 1024 + k0 + kc] = f2bs(t[kc][nr]);
    }
}

// ---------------------------------------------------------------------------
// Shared MFMA GEMM core: BM=BN=128, BK=64, 256 thr, K=1024.
// ---------------------------------------------------------------------------
__device__ __forceinline__ void gemm_core(const short* __restrict__ A,
                                          const short* __restrict__ Bt,
                                          short* As, short* Bs,
                                          int bm0, int bn0, int tid,
                                          f32x4 acc[4][4])
{
    const int w    = tid >> 6;
    const int wy   = w >> 1, wx = w & 1;
    const int lane = tid & 63;
    const int lm   = lane & 15;
    const int lq   = lane >> 4;

    for (int k0 = 0; k0 < 1024; k0 += 64) {
        const short* Ab = A  + (size_t)bm0 * 1024 + k0;
        const short* Bb = Bt + (size_t)bn0 * 1024 + k0;
        #pragma unroll
        for (int t = 0; t < 4; ++t) {
            int s = t * 256 + tid;
            int r = s >> 3, c = s & 7;
            int cg = c ^ (r & 7);
            g2l16(Ab + r * 1024 + cg * 8, As + s * 8);
            g2l16(Bb + r * 1024 + cg * 8, Bs + s * 8);
        }
        __syncthreads();
        #pragma unroll
        for (int kk = 0; kk < 2; ++kk) {
            bf16x8 af[4], bg[4];
            #pragma unroll
            for (int r4 = 0; r4 < 4; ++r4) {
                int ar = wy * 64 + r4 * 16 + lm;
                int kc = kk * 4 + lq;
                af[r4] = *(const bf16x8*)(As + ((ar << 3) + (kc ^ (ar & 7))) * 8);
            }
            #pragma unroll
            for (int c4 = 0; c4 < 4; ++c4) {
                int br = wx * 64 + c4 * 16 + lm;
                int kc = kk * 4 + lq;
                bg[c4] = *(const bf16x8*)(Bs + ((br << 3) + (kc ^ (br & 7))) * 8);
            }
            #pragma unroll
            for (int r4 = 0; r4 < 4; ++r4)
                #pragma unroll
                for (int c4 = 0; c4 < 4; ++c4)
                    acc[r4][c4] = __builtin_amdgcn_mfma_f32_16x16x32_bf16(
                        af[r4], bg[c4], acc[r4][c4], 0, 0, 0);
        }
        __syncthreads();
    }
}

// ---------------------------------------------------------------------------
// Fused kv/q/r projections. qu/qv scaled by SCALE*log2(e) (bare exp2 attn).
// ---------------------------------------------------------------------------
__global__ __launch_bounds__(256)
void proj_fused(const short* __restrict__ a_bf, const short* __restrict__ p_bf,
                const short* __restrict__ wkvt, const short* __restrict__ wqt,
                const short* __restrict__ wpt,
                short* __restrict__ k_bf, short* __restrict__ vt_bf,
                short* __restrict__ qu_bf, short* __restrict__ qv_bf,
                short* __restrict__ r_bf,
                const float* __restrict__ uvec, const float* __restrict__ vvec)
{
    __shared__ __align__(16) short As[128 * 64];
    __shared__ __align__(16) short Bs[128 * 64];

    int blk = blockIdx.x;
    int mode, bx, by;
    const short *A, *Bt;
    if (blk < 512)      { bx = blk & 15; by = blk >> 4;
                          if (bx >= 8) { mode = 4; A = wkvt; Bt = a_bf; }   // swapped V
                          else         { mode = 0; A = a_bf; Bt = wkvt; } }
    else if (blk < 640) { int b2 = blk - 512; mode = 1; bx = b2 & 7; by = b2 >> 3;
                          A = a_bf + (size_t)2048 * 1024; Bt = wqt; }
    else                { int b3 = blk - 640; mode = 2; bx = b3 & 7; by = b3 >> 3;
                          A = p_bf; Bt = wpt; }
    const int bn0 = (mode == 4) ? by * 128 : bx * 128;
    const int bm0 = (mode == 4) ? bx * 128 : by * 128;
    const int tid = threadIdx.x;
    const int w = tid >> 6, wy = w >> 1, wx = w & 1;
    const int lane = tid & 63, lm = lane & 15, lq = lane >> 4;

    f32x4 acc[4][4];
    #pragma unroll
    for (int r = 0; r < 4; ++r)
        #pragma unroll
        for (int c = 0; c < 4; ++c) acc[r][c] = (f32x4){0.f, 0.f, 0.f, 0.f};

    gemm_core(A, Bt, As, Bs, bm0, bn0, tid, acc);

    #pragma unroll
    for (int r4 = 0; r4 < 4; ++r4) {
        #pragma unroll
        for (int c4 = 0; c4 < 4; ++c4) {
            const int n = bn0 + wx * 64 + c4 * 16 + lm;
            float ubias = 0.f, vbias = 0.f;
            if (mode == 1) { ubias = uvec[n]; vbias = vvec[n]; }
            #pragma unroll
            for (int reg = 0; reg < 4; ++reg) {
                const int m = bm0 + wy * 64 + r4 * 16 + lq * 4 + reg;
                const float val = acc[r4][c4][reg];
                if (mode == 0) {
                    int j = m >> 1, b = m & 1;
                    int h = n >> 6, d = n & 63;
                    k_bf[(((size_t)b * H + h) * J + j) * DH + d] = f2bs(val);
                } else if (mode == 4) {
                    int n2 = m - 1024, h = n2 >> 6, d = n2 & 63;
                    int j = n >> 1, b = n & 1;
                    vt_bf[(((size_t)b * H + h) * DH + d) * J + j] = f2bs(val);
                } else if (mode == 1) {
                    int i = m >> 1, b = m & 1;
                    int h = n >> 6, d = n & 63;
                    size_t o = (((size_t)b * H + h) * S + i) * DH + d;
                    qu_bf[o] = f2bs((val + ubias) * SCALE_L2E);
                    qv_bf[o] = f2bs((val + vbias) * SCALE_L2E);
                } else {
                    int h = n >> 6, d = n & 63;
                    r_bf[((size_t)h * J + m) * DH + d] = f2bs(val);
                }
            }
        }
    }
}

// ---------------------------------------------------------------------------
// Output projection: M=2048, N=1024, fp32 out.
// ---------------------------------------------------------------------------
__global__ __launch_bounds__(256)
void gemm_out(const short* __restrict__ A, const short* __restrict__ Bt,
              float* __restrict__ out)
{
    __shared__ __align__(16) short As[128 * 64];
    __shared__ __align__(16) short Bs[128 * 64];
    const int bn0 = blockIdx.x * 128, bm0 = blockIdx.y * 128;
    const int tid = threadIdx.x;
    const int w = tid >> 6, wy = w >> 1, wx = w & 1;
    const int lane = tid & 63, lm = lane & 15, lq = lane >> 4;

    f32x4 acc[4][4];
    #pragma unroll
    for (int r = 0; r < 4; ++r)
        #pragma unroll
        for (int c = 0; c < 4; ++c) acc[r][c] = (f32x4){0.f, 0.f, 0.f, 0.f};

    gemm_core(A, Bt, As, Bs, bm0, bn0, tid, acc);

    #pragma unroll
    for (int r4 = 0; r4 < 4; ++r4)
        #pragma unroll
        for (int c4 = 0; c4 < 4; ++c4) {
            const int n = bn0 + wx * 64 + c4 * 16 + lm;
            #pragma unroll
            for (int reg = 0; reg < 4; ++reg) {
                const int m = bm0 + wy * 64 + r4 * 16 + lq * 4 + reg;
                out[(size_t)m * 1024 + n] = acc[r4][c4][reg];
            }
        }
}

// ---------------------------------------------------------------------------
// MFMA attention. R17 (base = R16, which = R0 + b64 content + XCD grid):
//  (1) FUSED content+softmax: the content MFMA's output IS the complete
//      logit (acc-init = pos from LDS). Apply exp2 in-register, write bf16
//      PROBS directly (same b64 stores), accumulate row partial sums in
//      registers -> shfl over lq -> per-wave partials in wsum[] -> ml after
//      the existing pre-PV barrier. Deletes the whole softmax phase: one
//      barrier fewer, -128 b128 LDS ops, -~280 VALU/wave, one serial
//      read->exp->write chain removed. (Coverage: pos main+hole+wrap
//      partition every column; content's 64 tiles cover all 1024 cols.)
//  (2) s_setprio(1) around MFMA clusters (T5: +4-7% attn in its favorable
//      regime = multi-block staggered phases, which we have).
// Phase structure is now: pos -> bar -> content+exp -> bar -> PV -> bar ->
// epilogue (4 barriers, was 5).
// ---------------------------------------------------------------------------
__device__ __forceinline__ int sidx(int m, int c) {   // m in [0,32), c in [0,1024)
    return (m << 10) + (c ^ (m << 3));
}

__global__ __launch_bounds__(512)
void attn_mfma(const short* __restrict__ qu_bf, const short* __restrict__ qv_bf,
               const short* __restrict__ k_bf,  const short* __restrict__ vt_bf,
               const short* __restrict__ r_bf,
               float* __restrict__ opart, float* __restrict__ ml)
{
    __shared__ unsigned short sc[32 * 1024];   // 64 KB
    __shared__ float wsum[16][2][8];           // 1 KB per-wave row partials
    __half* sch = (__half*)sc;
    float*  scF = (float*)sc;                  // reused after PV reads

    // XCD-aware decode: L&7 = XCD (round-robin dispatch); each XCD owns
    // bh in [4*xcd, 4*xcd+4), processed stream-by-stream.
    const int L   = blockIdx.x;
    const int xcd = L & 7;
    const int pp  = L >> 3;                    // 0..255
    const int bh  = (xcd << 2) + (pp >> 6);    // 4 streams per XCD
    const int sub = pp & 63;
    const int it  = sub >> 1;
    const int jh  = sub & 1;

    const int i0  = it * 32;
    const int cbeg = jh << 10, cend = cbeg + 1024;
    const int h   = bh & (H - 1);
    const int tid = threadIdx.x;
    const int w    = tid >> 6;       // 0..7
    const int lane = tid & 63;
    const int lm   = lane & 15;
    const int lq   = lane >> 4;
    const int slot = (it * 32 + bh) * 2 + jh;

    // ---- A fragments ----
    const short* qup0 = qu_bf + ((size_t)(bh * S + i0 + lm)) * DH + lq * 8;
    const short* qup1 = qup0 + 16 * DH;
    bf16x8 au00 = *(const bf16x8*)qup0,        au01 = *(const bf16x8*)(qup0 + 32);
    bf16x8 au10 = *(const bf16x8*)qup1,        au11 = *(const bf16x8*)(qup1 + 32);
    const short* qvp0 = qv_bf + ((size_t)(bh * S + i0 + lm)) * DH + lq * 8;
    const short* qvp1 = qvp0 + 16 * DH;
    bf16x8 av00 = *(const bf16x8*)qvp0,        av01 = *(const bf16x8*)(qvp0 + 32);
    bf16x8 av10 = *(const bf16x8*)qvp1,        av11 = *(const bf16x8*)(qvp1 + 32);
    int r1a = i0 + 1 + lm;  if (r1a > S - 1) r1a = S - 1;   // clamped rows masked
    int r1b = i0 + 17 + lm; if (r1b > S - 1) r1b = S - 1;
    const short* qwp0 = qv_bf + ((size_t)(bh * S + r1a)) * DH + lq * 8;
    const short* qwp1 = qv_bf + ((size_t)(bh * S + r1b)) * DH + lq * 8;
    bf16x8 aw00 = *(const bf16x8*)qwp0,        aw01 = *(const bf16x8*)(qwp0 + 32);
    bf16x8 aw10 = *(const bf16x8*)qwp1,        aw11 = *(const bf16x8*)(qwp1 + 32);

    // ---- zero the pos hole column: row m, col i0+m+1025 (if in window) ----
    if (tid < 32) {
        int hole = i0 + tid + 1025;
        if (hole >= cbeg && hole < cend) sc[sidx(tid, hole - cbeg)] = 0;
    }

    const short* rbase = r_bf + (size_t)h * J * DH;

    // ---- pos main: col = i0 + 16t + lm + m - 1023; depth-2 prefetch ----
    {
        int tmp = cbeg + 977 - i0;
        int tlo = tmp > 0 ? ((tmp + 15) >> 4) : 0;
        int thi = (cend + 1022 - i0) >> 4; if (thi > 127) thi = 127;
        int t = tlo + w;
        if (t <= thi) {
            const short* rp = rbase + (size_t)(t * 16 + lm) * DH + lq * 8;
            bf16x8 b0 = *(const bf16x8*)rp, b1 = *(const bf16x8*)(rp + 32);
            bf16x8 p0, p1;
            if (t + 8 <= thi) {
                const short* rp2 = rbase + (size_t)((t + 8) * 16 + lm) * DH + lq * 8;
                p0 = *(const bf16x8*)rp2; p1 = *(const bf16x8*)(rp2 + 32);
            }
            for (; t <= thi; t += 8) {
                bf16x8 n0, n1;
                if (t + 16 <= thi) {
                    const short* rpn = rbase + (size_t)((t + 16) * 16 + lm) * DH + lq * 8;
                    n0 = *(const bf16x8*)rpn; n1 = *(const bf16x8*)(rpn + 32);
                }
                f32x4 c0 = {0.f,0.f,0.f,0.f}, c1 = {0.f,0.f,0.f,0.f};
                __builtin_amdgcn_s_setprio(1);
                c0 = __builtin_amdgcn_mfma_f32_16x16x32_bf16(av00, b0, c0, 0, 0, 0);
                c1 = __builtin_amdgcn_mfma_f32_16x16x32_bf16(av10, b0, c1, 0, 0, 0);
                c0 = __builtin_amdgcn_mfma_f32_16x16x32_bf16(av01, b1, c0, 0, 0, 0);
                c1 = __builtin_amdgcn_mfma_f32_16x16x32_bf16(av11, b1, c1, 0, 0, 0);
                __builtin_amdgcn_s_setprio(0);
                int cb = i0 + t * 16 + lm - 1023 - cbeg;     // local col for m=0
                int base = i0 + 16 * t - 1023;               // scalar col_min
                if (base >= cbeg && base + 46 < cend) {
                    #pragma unroll
                    for (int r = 0; r < 4; ++r) {
                        int m0 = lq * 4 + r, m1 = m0 + 16;
                        sch[sidx(m0, cb + m0)] = __float2half(c0[r]);
                        sch[sidx(m1, cb + m1)] = __float2half(c1[r]);
                    }
                } else {
                    #pragma unroll
                    for (int r = 0; r < 4; ++r) {
                        int m0 = lq * 4 + r, m1 = m0 + 16;
                        int cA = cb + m0, cB = cb + m1;
                        if (cA >= 0 && cA < 1024) sch[sidx(m0, cA)] = __float2half(c0[r]);
                        if (cB >= 0 && cB < 1024) sch[sidx(m1, cB)] = __float2half(c1[r]);
                    }
                }
                b0 = p0; b1 = p1; p0 = n0; p1 = n1;
            }
        }
    }

    // ---- pos wrap: col = i0 + 16t + lm + m + 1026, rows Qv[i+1]; depth-2 ----
    {
        int tmpw = cbeg - 1072 - i0;
        int tlw = tmpw > 0 ? ((tmpw + 15) >> 4) : 0;
        int thw = (cend - 1027 - i0) >> 4; if (thw > 127) thw = 127;
        int t = tlw + w;
        if (t <= thw) {
            const short* rp = rbase + (size_t)(t * 16 + lm) * DH + lq * 8;
            bf16x8 b0 = *(const bf16x8*)rp, b1 = *(const bf16x8*)(rp + 32);
            bf16x8 p0, p1;
            if (t + 8 <= thw) {
                const short* rp2 = rbase + (size_t)((t + 8) * 16 + lm) * DH + lq * 8;
                p0 = *(const bf16x8*)rp2; p1 = *(const bf16x8*)(rp2 + 32);
            }
            for (; t <= thw; t += 8) {
                bf16x8 n0, n1;
                if (t + 16 <= thw) {
                    const short* rpn = rbase + (size_t)((t + 16) * 16 + lm) * DH + lq * 8;
                    n0 = *(const bf16x8*)rpn; n1 = *(const bf16x8*)(rpn + 32);
                }
                f32x4 c0 = {0.f,0.f,0.f,0.f}, c1 = {0.f,0.f,0.f,0.f};
                __builtin_amdgcn_s_setprio(1);
                c0 = __builtin_amdgcn_mfma_f32_16x16x32_bf16(aw00, b0, c0, 0, 0, 0);
                c1 = __builtin_amdgcn_mfma_f32_16x16x32_bf16(aw10, b0, c1, 0, 0, 0);
                c0 = __builtin_amdgcn_mfma_f32_16x16x32_bf16(aw01, b1, c0, 0, 0, 0);
                c1 = __builtin_amdgcn_mfma_f32_16x16x32_bf16(aw11, b1, c1, 0, 0, 0);
                __builtin_amdgcn_s_setprio(0);
                int cb = i0 + t * 16 + lm + 1026 - cbeg;
                int base = i0 + 16 * t + 1026;
                if (base >= cbeg && base + 46 < cend) {
                    #pragma unroll
                    for (int r = 0; r < 4; ++r) {
                        int m0 = lq * 4 + r, m1 = m0 + 16;
                        sch[sidx(m0, cb + m0)] = __float2half(c0[r]);
                        sch[sidx(m1, cb + m1)] = __float2half(c1[r]);
                    }
                } else {
                    #pragma unroll
                    for (int r = 0; r < 4; ++r) {
                        int m0 = lq * 4 + r, m1 = m0 + 16;
                        int cA = cb + m0, cB = cb + m1;
                        if (cA >= 0 && cA < 1024) sch[sidx(m0, cA)] = __float2half(c0[r]);
                        if (cB >= 0 && cB < 1024) sch[sidx(m1, cB)] = __float2half(c1[r]);
                    }
                }
                b0 = p0; b1 = p1; p0 = n0; p1 = n1;
            }
        }
    }

    // ---- prefetch first two content K-tiles before the barrier ----
    const short* kbase = k_bf + (size_t)bh * J * DH;
    bf16x8 kb0, kb1, kc0, kc1;
    {
        int t0 = jh * 64 + w + 8 * ((it) & 7);
        int t1 = jh * 64 + w + 8 * ((1 + it) & 7);
        const short* kp0 = kbase + (size_t)(t0 * 16 + lm) * DH + lq * 8;
        const short* kp1 = kbase + (size_t)(t1 * 16 + lm) * DH + lq * 8;
        kb0 = *(const bf16x8*)kp0; kb1 = *(const bf16x8*)(kp0 + 32);
        kc0 = *(const bf16x8*)kp1; kc1 = *(const bf16x8*)(kp1 + 32);
    }
    __syncthreads();

    // ---- content + softmax FUSED: swapped-operand MFMA (A=K, B=Q) gives
    //      lane (q-row lm / lm+16, 4 consecutive j-cols). acc-init = pos
    //      (b64 read) -> logits complete after 4 MFMA -> exp2 in-register,
    //      pack bf16 probs, b64 store; row partial sums in registers.
    float sum0 = 0.f, sum1 = 0.f;
    #pragma unroll 1
    for (int g = 0; g < 8; ++g) {
        bf16x8 nb0, nb1;
        if (g + 2 < 8) {
            int u = jh * 64 + w + 8 * ((g + 2 + it) & 7);
            const short* np = kbase + (size_t)(u * 16 + lm) * DH + lq * 8;
            nb0 = *(const bf16x8*)np; nb1 = *(const bf16x8*)(np + 32);
        }
        int t = jh * 64 + w + 8 * ((g + it) & 7);
        int lc = t * 16 - cbeg;                  // 16-aligned local col base
        int aA = sidx(lm,      lc + lq * 4);     // 4 consecutive u16, 8B-aligned
        int aB = sidx(lm + 16, lc + lq * 4);
        h16x4 hA = *(const h16x4*)(sc + aA);
        h16x4 hB = *(const h16x4*)(sc + aB);
        f32x4 c0, c1;
        #pragma unroll
        for (int r = 0; r < 4; ++r) { c0[r] = (float)hA[r]; c1[r] = (float)hB[r]; }
        __builtin_amdgcn_s_setprio(1);
        c0 = __builtin_amdgcn_mfma_f32_16x16x32_bf16(kb0, au00, c0, 0, 0, 0);
        c1 = __builtin_amdgcn_mfma_f32_16x16x32_bf16(kb0, au10, c1, 0, 0, 0);
        c0 = __builtin_amdgcn_mfma_f32_16x16x32_bf16(kb1, au01, c0, 0, 0, 0);
        c1 = __builtin_amdgcn_mfma_f32_16x16x32_bf16(kb1, au11, c1, 0, 0, 0);
        __builtin_amdgcn_s_setprio(0);
        us4 oA, oB;
        #pragma unroll
        for (int r = 0; r < 4; ++r) {
            float e0 = __builtin_amdgcn_exp2f(c0[r]);
            float e1 = __builtin_amdgcn_exp2f(c1[r]);
            sum0 += e0; sum1 += e1;
            oA[r] = f2bf_fast(e0);
            oB[r] = f2bf_fast(e1);
        }
        *(us4*)(sc + aA) = oA;
        *(us4*)(sc + aB) = oB;
        kb0 = kc0; kb1 = kc1; kc0 = nb0; kc1 = nb1;
    }
    // per-wave row partials: reduce over lq group (lanes lm, lm+16/32/48)
    sum0 += __shfl_xor(sum0, 16); sum0 += __shfl_xor(sum0, 32);
    sum1 += __shfl_xor(sum1, 16); sum1 += __shfl_xor(sum1, 32);
    if (lane < 16) { wsum[lane][0][w] = sum0; wsum[lane][1][w] = sum1; }

    // ---- prefetch first PV V-chunk before the barrier ----
    const int dslice = w & 3, jq = w >> 2;
    const short* vtb = vt_bf + ((size_t)bh * DH + dslice * 16 + lm) * J + cbeg + jq * 512;
    bf16x8 cv0, cv1, cv2, cv3;
    {
        int j0 = (it & 3) * 128;
        cv0 = *(const bf16x8*)(vtb + j0 +  0 + lq * 8);
        cv1 = *(const bf16x8*)(vtb + j0 + 32 + lq * 8);
        cv2 = *(const bf16x8*)(vtb + j0 + 64 + lq * 8);
        cv3 = *(const bf16x8*)(vtb + j0 + 96 + lq * 8);
    }
    __syncthreads();

    // ---- ml write (probs/wsum complete after barrier) ----
    if (tid < 32) {
        float s = 0.f;
        #pragma unroll
        for (int ww = 0; ww < 8; ++ww) s += wsum[tid & 15][tid >> 4][ww];
        ml[(size_t)slot * 64 + tid * 2]     = 0.f;
        ml[(size_t)slot * 64 + tid * 2 + 1] = s;
    }

    // ---- PV: wave -> d-slice (w&3), j-quarter (w>>2); rolling V prefetch ----
    f32x4 pa0 = {0.f,0.f,0.f,0.f}, pa1 = {0.f,0.f,0.f,0.f};
    f32x4 pa2 = {0.f,0.f,0.f,0.f}, pa3 = {0.f,0.f,0.f,0.f};
    f32x4 pb0 = {0.f,0.f,0.f,0.f}, pb1 = {0.f,0.f,0.f,0.f};
    f32x4 pb2 = {0.f,0.f,0.f,0.f}, pb3 = {0.f,0.f,0.f,0.f};
    #pragma unroll 1
    for (int jo0 = 0; jo0 < 4; ++jo0) {       // 128 local j per iteration
        bf16x8 nv0, nv1, nv2, nv3;
        if (jo0 < 3) {
            int jn = ((jo0 + 1 + it) & 3) * 128;
            nv0 = *(const bf16x8*)(vtb + jn +  0 + lq * 8);
            nv1 = *(const bf16x8*)(vtb + jn + 32 + lq * 8);
            nv2 = *(const bf16x8*)(vtb + jn + 64 + lq * 8);
            nv3 = *(const bf16x8*)(vtb + jn + 96 + lq * 8);
        }
        int j0 = ((jo0 + it) & 3) * 128;
        int lb = jq * 512 + j0;
        bf16x8 a0 = *(const bf16x8*)(sc + sidx(lm, lb +  0 + lq * 8));
        bf16x8 a1 = *(const bf16x8*)(sc + sidx(lm, lb + 32 + lq * 8));
        bf16x8 a2 = *(const bf16x8*)(sc + sidx(lm, lb + 64 + lq * 8));
        bf16x8 a3 = *(const bf16x8*)(sc + sidx(lm, lb + 96 + lq * 8));
        bf16x8 c0 = *(const bf16x8*)(sc + sidx(16 + lm, lb +  0 + lq * 8));
        bf16x8 c1 = *(const bf16x8*)(sc + sidx(16 + lm, lb + 32 + lq * 8));
        bf16x8 c2 = *(const bf16x8*)(sc + sidx(16 + lm, lb + 64 + lq * 8));
        bf16x8 c3 = *(const bf16x8*)(sc + sidx(16 + lm, lb + 96 + lq * 8));
        __builtin_amdgcn_s_setprio(1);
        pa0 = __builtin_amdgcn_mfma_f32_16x16x32_bf16(a0, cv0, pa0, 0, 0, 0);
        pb0 = __builtin_amdgcn_mfma_f32_16x16x32_bf16(c0, cv0, pb0, 0, 0, 0);
        pa1 = __builtin_amdgcn_mfma_f32_16x16x32_bf16(a1, cv1, pa1, 0, 0, 0);
        pb1 = __builtin_amdgcn_mfma_f32_16x16x32_bf16(c1, cv1, pb1, 0, 0, 0);
        pa2 = __builtin_amdgcn_mfma_f32_16x16x32_bf16(a2, cv2, pa2, 0, 0, 0);
        pb2 = __builtin_amdgcn_mfma_f32_16x16x32_bf16(c2, cv2, pb2, 0, 0, 0);
        pa3 = __builtin_amdgcn_mfma_f32_16x16x32_bf16(a3, cv3, pa3, 0, 0, 0);
        pb3 = __builtin_amdgcn_mfma_f32_16x16x32_bf16(c3, cv3, pb3, 0, 0, 0);
        __builtin_amdgcn_s_setprio(0);
        if (jo0 < 3) { cv0 = nv0; cv1 = nv1; cv2 = nv2; cv3 = nv3; }
    }
    __syncthreads();   // all probs read; sc reusable as float scratch

    #pragma unroll
    for (int r = 0; r < 4; ++r) {
        int m0 = lq * 4 + r, m1 = m0 + 16;
        scF[jq * 2048 + m0 * 64 + dslice * 16 + lm] = pa0[r] + pa1[r] + pa2[r] + pa3[r];
        scF[jq * 2048 + m1 * 64 + dslice * 16 + lm] = pb0[r] + pb1[r] + pb2[r] + pb3[r];
    }
    __syncthreads();

    float* op = opart + (size_t)slot * 2048;
    #pragma unroll
    for (int e = tid; e < 2048; e += 512)
        op[e] = scF[e] + scF[2048 + e];
}

// ---------------------------------------------------------------------------
// Merge the two j-half partials: O = (e^{m0-m} O0 + e^{m1-m} O1) / (...)
// (m0 = m1 = 0 with the no-max-sub softmax; formula unchanged.)
// ---------------------------------------------------------------------------
__global__ __launch_bounds__(256)
void attn_combine(const float* __restrict__ opart, const float* __restrict__ ml,
                  short* __restrict__ o_bf)
{
    const int blk = blockIdx.x;           // it*32 + bh
    const int it = blk >> 5, bh = blk & 31;
    const int h = bh & 15, b = bh >> 4;
    __shared__ float wgt[32][2];
    const int tid = threadIdx.x;
    if (tid < 32) {
        float m0 = ml[(size_t)(blk * 2 + 0) * 64 + tid * 2];
        float l0 = ml[(size_t)(blk * 2 + 0) * 64 + tid * 2 + 1];
        float m1 = ml[(size_t)(blk * 2 + 1) * 64 + tid * 2];
        float l1 = ml[(size_t)(blk * 2 + 1) * 64 + tid * 2 + 1];
        float mx = fmaxf(m0, m1);
        float e0 = __expf(m0 - mx), e1 = __expf(m1 - mx);
        float inv = 1.0f / (e0 * l0 + e1 * l1);
        wgt[tid][0] = e0 * inv;
        wgt[tid][1] = e1 * inv;
    }
    __syncthreads();
    const float* p0 = opart + (size_t)(blk * 2 + 0) * 2048;
    const float* p1 = opart + (size_t)(blk * 2 + 1) * 2048;
    #pragma unroll
    for (int e = tid; e < 2048; e += 256) {
        int m = e >> 6, d = e & 63;
        float val = p0[e] * wgt[m][0] + p1[e] * wgt[m][1];
        o_bf[((size_t)(it * 32 + m) * B + b) * (H * DH) + h * DH + d] = f2bs(val);
    }
}

// ---------------------------------------------------------------------------
extern "C" void kernel_launch(void* const* d_in, const int* in_sizes, int n_in,
                              void* d_out, int out_size, void* d_ws, size_t ws_size,
                              hipStream_t stream)
{
    const float* x    = (const float*)d_in[0];   // [S, B, D]
    const float* pemb = (const float*)d_in[1];   // [S+M, D]
    const float* mem  = (const float*)d_in[2];   // [M, B, D]
    const float* u    = (const float*)d_in[3];   // [H, DH]
    const float* v    = (const float*)d_in[4];   // [H, DH]
    const float* Wkv  = (const float*)d_in[5];   // [D, 2*H*DH]
    const float* Wq   = (const float*)d_in[6];   // [D, H*DH]
    const float* Wpos = (const float*)d_in[7];   // [D, H*DH]
    const float* Wout = (const float*)d_in[8];   // [H*DH, D]
    float* out = (float*)d_out;                  // [S, B, D]

    char* p = (char*)d_ws;
    short* a_bf  = (short*)p; p += (size_t)4096 * 1024 * 2;    // mem||x  [0,8M)
    short* p_bf  = (short*)p; p += (size_t)2048 * 1024 * 2;    // [8M,12M)
    short* wkvt  = (short*)p; p += (size_t)2048 * 1024 * 2;    // [12M,16M)
    short* wqt   = (short*)p; p += (size_t)1024 * 1024 * 2;    // [16M,18M)
    short* wpt   = (short*)p; p += (size_t)1024 * 1024 * 2;    // [18M,20M)
    short* wot   = (short*)p; p += (size_t)1024 * 1024 * 2;    // [20M,22M)
    short* k_bf  = (short*)p; p += (size_t)B * H * J * DH * 2;
    short* vt_bf = (short*)p; p += (size_t)B * H * J * DH * 2;
    short* qu_bf = (short*)p; p += (size_t)B * H * S * DH * 2;
    short* qv_bf = (short*)p; p += (size_t)B * H * S * DH * 2;
    short* r_bf  = (short*)p; p += (size_t)H * J * DH * 2;
    short* o_bf  = (short*)p;

    // attn partials alias prep buffers (dead after proj_fused):
    // opart: [0,16M) over a_bf/p_bf/wkvt (2048 slots x 2048 fp32 = 16 MB);
    // ml: [16M,16.5M) over wqt (2048 slots x 64 fp32).
    float* opart = (float*)d_ws;
    float* ml    = (float*)((char*)d_ws + (size_t)16 * 1024 * 1024);

    prep<<<7424, 256, 0, stream>>>(mem, x, pemb, Wkv, Wq, Wpos, Wout,
                                   a_bf, p_bf, wkvt, wqt, wpt, wot);
    proj_fused<<<768, 256, 0, stream>>>(a_bf, p_bf, wkvt, wqt, wpt,
                                        k_bf, vt_bf, qu_bf, qv_bf, r_bf, u, v);
    attn_mfma<<<2048, 512, 0, stream>>>(
        qu_bf, qv_bf, k_bf, vt_bf, r_bf, opart, ml);
    attn_combine<<<(S / 32) * B * H, 256, 0, stream>>>(opart, ml, o_bf);
    gemm_out<<<dim3(8, 16), 256, 0, stream>>>(o_bf, wot, out);
}

// Round 9
// 283.929 us; speedup vs baseline: 1.1292x; 1.0297x over previous
//
#include <hip/hip_runtime.h>
#include <hip/hip_bf16.h>
#include <hip/hip_fp16.h>
#include <math.h>

#define D    1024
#define H    16
#define DH   64
#define S    1024
#define M    1024
#define B    2
#define J    2048          // M + S
#define SCALE 0.125f       // 1/sqrt(64)
#define SCALE_L2E 0.18033688f   // SCALE * log2(e): softmax uses bare exp2

typedef __attribute__((ext_vector_type(8))) short        bf16x8;
typedef __attribute__((ext_vector_type(4))) short        s16x4;
typedef __attribute__((ext_vector_type(8))) _Float16     h16x8;
typedef __attribute__((ext_vector_type(4))) _Float16     h16x4;
typedef __attribute__((ext_vector_type(8))) unsigned short us8;
typedef __attribute__((ext_vector_type(4))) unsigned short us4;
typedef __attribute__((ext_vector_type(4))) float        f32x4;

__device__ __forceinline__ short f2bs(float f) {
    __hip_bfloat16 t = __float2bfloat16(f);
    short r; __builtin_memcpy(&r, &t, 2); return r;
}
// fast bf16 pack (round-half-up); inputs finite non-negative (probs)
__device__ __forceinline__ unsigned short f2bf_fast(float f) {
    unsigned int u; __builtin_memcpy(&u, &f, 4);
    return (unsigned short)((u + 0x8000u) >> 16);
}

// async global->LDS, 16 bytes per lane
__device__ __forceinline__ void g2l16(const short* g, short* l) {
    __builtin_amdgcn_global_load_lds(
        (const __attribute__((address_space(1))) unsigned int*)g,
        (__attribute__((address_space(3))) unsigned int*)l, 16, 0, 0);
}

// ---------------------------------------------------------------------------
// prep: blocks [0,6144)  fp32->bf16 flat convert (mem||x -> a_bf, pemb -> p_bf)
//       blocks [6144,7424) 64x64 weight transpose+convert W[k][n] -> Wt[n][k]
// ---------------------------------------------------------------------------
__global__ __launch_bounds__(256)
void prep(const float* __restrict__ mem, const float* __restrict__ x,
          const float* __restrict__ pemb,
          const float* __restrict__ Wkv, const float* __restrict__ Wq,
          const float* __restrict__ Wpos, const float* __restrict__ Wout,
          short* __restrict__ a_bf, short* __restrict__ p_bf,
          short* __restrict__ wkvt, short* __restrict__ wqt,
          short* __restrict__ wpt,  short* __restrict__ wot)
{
    __shared__ float t[64][65];
    int blk = blockIdx.x;
    const int tid = threadIdx.x;
    if (blk < 6144) {
        const int idx = (blk * 256 + tid) * 4;
        const int TWO_M = 2 * 1024 * 1024;
        float4 v; short* dst;
        if (idx < TWO_M)          { v = *(const float4*)(mem  + idx);           dst = a_bf + idx; }
        else if (idx < 2 * TWO_M) { v = *(const float4*)(x    + idx - TWO_M);   dst = a_bf + idx; }
        else                      { v = *(const float4*)(pemb + idx - 2*TWO_M); dst = p_bf + idx - 2*TWO_M; }
        s16x4 o = { f2bs(v.x), f2bs(v.y), f2bs(v.z), f2bs(v.w) };
        *(s16x4*)dst = o;
        return;
    }
    blk -= 6144;
    const float* src; short* dst; int N, t0;
    if (blk < 512)       { src = Wkv;  dst = wkvt; N = 2048; t0 = blk; }
    else if (blk < 768)  { src = Wq;   dst = wqt;  N = 1024; t0 = blk - 512; }
    else if (blk < 1024) { src = Wpos; dst = wpt;  N = 1024; t0 = blk - 768; }
    else                 { src = Wout; dst = wot;  N = 1024; t0 = blk - 1024; }
    const int ntn = N >> 6;
    const int k0 = (t0 / ntn) * 64, n0 = (t0 % ntn) * 64;
    #pragma unroll
    for (int e = tid; e < 4096; e += 256) {
        int r = e >> 6, c = e & 63;
        t[r][c] = src[(size_t)(k0 + r) * N + n0 + c];
    }
    __syncthreads();
    #pragma unroll
    for (int e = tid; e < 4096; e += 256) {
        int nr = e >> 6, kc = e & 63;
        dst[(size_t)(n0 + nr) * 1024 + k0 + kc] = f2bs(t[kc][nr]);
    }
}

// ---------------------------------------------------------------------------
// Shared MFMA GEMM core: BM=BN=128, BK=64, 256 thr, K=1024.
// ---------------------------------------------------------------------------
__device__ __forceinline__ void gemm_core(const short* __restrict__ A,
                                          const short* __restrict__ Bt,
                                          short* As, short* Bs,
                                          int bm0, int bn0, int tid,
                                          f32x4 acc[4][4])
{
    const int w    = tid >> 6;
    const int wy   = w >> 1, wx = w & 1;
    const int lane = tid & 63;
    const int lm   = lane & 15;
    const int lq   = lane >> 4;

    for (int k0 = 0; k0 < 1024; k0 += 64) {
        const short* Ab = A  + (size_t)bm0 * 1024 + k0;
        const short* Bb = Bt + (size_t)bn0 * 1024 + k0;
        #pragma unroll
        for (int t = 0; t < 4; ++t) {
            int s = t * 256 + tid;
            int r = s >> 3, c = s & 7;
            int cg = c ^ (r & 7);
            g2l16(Ab + r * 1024 + cg * 8, As + s * 8);
            g2l16(Bb + r * 1024 + cg * 8, Bs + s * 8);
        }
        __syncthreads();
        #pragma unroll
        for (int kk = 0; kk < 2; ++kk) {
            bf16x8 af[4], bg[4];
            #pragma unroll
            for (int r4 = 0; r4 < 4; ++r4) {
                int ar = wy * 64 + r4 * 16 + lm;
                int kc = kk * 4 + lq;
                af[r4] = *(const bf16x8*)(As + ((ar << 3) + (kc ^ (ar & 7))) * 8);
            }
            #pragma unroll
            for (int c4 = 0; c4 < 4; ++c4) {
                int br = wx * 64 + c4 * 16 + lm;
                int kc = kk * 4 + lq;
                bg[c4] = *(const bf16x8*)(Bs + ((br << 3) + (kc ^ (br & 7))) * 8);
            }
            #pragma unroll
            for (int r4 = 0; r4 < 4; ++r4)
                #pragma unroll
                for (int c4 = 0; c4 < 4; ++c4)
                    acc[r4][c4] = __builtin_amdgcn_mfma_f32_16x16x32_bf16(
                        af[r4], bg[c4], acc[r4][c4], 0, 0, 0);
        }
        __syncthreads();
    }
}

// ---------------------------------------------------------------------------
// Fused kv/q/r projections. qu/qv scaled by SCALE*log2(e) (bare exp2 attn).
// R18: XCD-aware block remap (T1, bijective: 768 = 8 x 96). Original order
// had bx fastest -> same-A-panel blocks round-robined over 8 XCDs, so each
// XCD re-fetched every panel: ~400 MB of staging traffic vs ~20 MB unique.
// Remap gives each XCD a contiguous 96-block range (shared A/B panels,
// per-XCD WS ~4 MB ~ L2) -> panel re-reads become L2 hits.
// ---------------------------------------------------------------------------
__global__ __launch_bounds__(256)
void proj_fused(const short* __restrict__ a_bf, const short* __restrict__ p_bf,
                const short* __restrict__ wkvt, const short* __restrict__ wqt,
                const short* __restrict__ wpt,
                short* __restrict__ k_bf, short* __restrict__ vt_bf,
                short* __restrict__ qu_bf, short* __restrict__ qv_bf,
                short* __restrict__ r_bf,
                const float* __restrict__ uvec, const float* __restrict__ vvec)
{
    __shared__ __align__(16) short As[128 * 64];
    __shared__ __align__(16) short Bs[128 * 64];

    // XCD remap: HW sends original id L to XCD L&7; logical id below makes
    // XCD x execute the contiguous logical range [x*96, (x+1)*96).
    int blk = (blockIdx.x & 7) * 96 + (blockIdx.x >> 3);

    int mode, bx, by;
    const short *A, *Bt;
    if (blk < 512)      { bx = blk & 15; by = blk >> 4;
                          if (bx >= 8) { mode = 4; A = wkvt; Bt = a_bf; }   // swapped V
                          else         { mode = 0; A = a_bf; Bt = wkvt; } }
    else if (blk < 640) { int b2 = blk - 512; mode = 1; bx = b2 & 7; by = b2 >> 3;
                          A = a_bf + (size_t)2048 * 1024; Bt = wqt; }
    else                { int b3 = blk - 640; mode = 2; bx = b3 & 7; by = b3 >> 3;
                          A = p_bf; Bt = wpt; }
    const int bn0 = (mode == 4) ? by * 128 : bx * 128;
    const int bm0 = (mode == 4) ? bx * 128 : by * 128;
    const int tid = threadIdx.x;
    const int w = tid >> 6, wy = w >> 1, wx = w & 1;
    const int lane = tid & 63, lm = lane & 15, lq = lane >> 4;

    f32x4 acc[4][4];
    #pragma unroll
    for (int r = 0; r < 4; ++r)
        #pragma unroll
        for (int c = 0; c < 4; ++c) acc[r][c] = (f32x4){0.f, 0.f, 0.f, 0.f};

    gemm_core(A, Bt, As, Bs, bm0, bn0, tid, acc);

    #pragma unroll
    for (int r4 = 0; r4 < 4; ++r4) {
        #pragma unroll
        for (int c4 = 0; c4 < 4; ++c4) {
            const int n = bn0 + wx * 64 + c4 * 16 + lm;
            float ubias = 0.f, vbias = 0.f;
            if (mode == 1) { ubias = uvec[n]; vbias = vvec[n]; }
            #pragma unroll
            for (int reg = 0; reg < 4; ++reg) {
                const int m = bm0 + wy * 64 + r4 * 16 + lq * 4 + reg;
                const float val = acc[r4][c4][reg];
                if (mode == 0) {
                    int j = m >> 1, b = m & 1;
                    int h = n >> 6, d = n & 63;
                    k_bf[(((size_t)b * H + h) * J + j) * DH + d] = f2bs(val);
                } else if (mode == 4) {
                    int n2 = m - 1024, h = n2 >> 6, d = n2 & 63;
                    int j = n >> 1, b = n & 1;
                    vt_bf[(((size_t)b * H + h) * DH + d) * J + j] = f2bs(val);
                } else if (mode == 1) {
                    int i = m >> 1, b = m & 1;
                    int h = n >> 6, d = n & 63;
                    size_t o = (((size_t)b * H + h) * S + i) * DH + d;
                    qu_bf[o] = f2bs((val + ubias) * SCALE_L2E);
                    qv_bf[o] = f2bs((val + vbias) * SCALE_L2E);
                } else {
                    int h = n >> 6, d = n & 63;
                    r_bf[((size_t)h * J + m) * DH + d] = f2bs(val);
                }
            }
        }
    }
}

// ---------------------------------------------------------------------------
// Output projection: M=2048, N=1024, fp32 out.
// R18: BM=64, BN=128 tile -> grid (8,32) = 256 blocks. The old 128x128 tile
// gave only 128 blocks on 256 CUs (half the machine idle by construction).
// Same waves/CU, all CUs used.
// ---------------------------------------------------------------------------
__global__ __launch_bounds__(256)
void gemm_out(const short* __restrict__ A, const short* __restrict__ Bt,
              float* __restrict__ out)
{
    __shared__ __align__(16) short As[64 * 64];    // 8 KB
    __shared__ __align__(16) short Bs[128 * 64];   // 16 KB
    const int bn0 = blockIdx.x * 128, bm0 = blockIdx.y * 64;
    const int tid = threadIdx.x;
    const int w = tid >> 6;                 // 0..3 = column-split wave index
    const int lane = tid & 63, lm = lane & 15, lq = lane >> 4;

    f32x4 acc[4][2];
    #pragma unroll
    for (int r = 0; r < 4; ++r)
        #pragma unroll
        for (int c = 0; c < 2; ++c) acc[r][c] = (f32x4){0.f, 0.f, 0.f, 0.f};

    for (int k0 = 0; k0 < 1024; k0 += 64) {
        const short* Ab = A  + (size_t)bm0 * 1024 + k0;
        const short* Bb = Bt + (size_t)bn0 * 1024 + k0;
        #pragma unroll
        for (int t = 0; t < 2; ++t) {       // A: 64 rows
            int s = t * 256 + tid;
            int r = s >> 3, c = s & 7;
            int cg = c ^ (r & 7);
            g2l16(Ab + r * 1024 + cg * 8, As + s * 8);
        }
        #pragma unroll
        for (int t = 0; t < 4; ++t) {       // B: 128 rows
            int s = t * 256 + tid;
            int r = s >> 3, c = s & 7;
            int cg = c ^ (r & 7);
            g2l16(Bb + r * 1024 + cg * 8, Bs + s * 8);
        }
        __syncthreads();
        #pragma unroll
        for (int kk = 0; kk < 2; ++kk) {
            bf16x8 af[4], bg[2];
            #pragma unroll
            for (int r4 = 0; r4 < 4; ++r4) {
                int ar = r4 * 16 + lm;
                int kc = kk * 4 + lq;
                af[r4] = *(const bf16x8*)(As + ((ar << 3) + (kc ^ (ar & 7))) * 8);
            }
            #pragma unroll
            for (int c4 = 0; c4 < 2; ++c4) {
                int br = w * 32 + c4 * 16 + lm;
                int kc = kk * 4 + lq;
                bg[c4] = *(const bf16x8*)(Bs + ((br << 3) + (kc ^ (br & 7))) * 8);
            }
            #pragma unroll
            for (int r4 = 0; r4 < 4; ++r4)
                #pragma unroll
                for (int c4 = 0; c4 < 2; ++c4)
                    acc[r4][c4] = __builtin_amdgcn_mfma_f32_16x16x32_bf16(
                        af[r4], bg[c4], acc[r4][c4], 0, 0, 0);
        }
        __syncthreads();
    }

    #pragma unroll
    for (int r4 = 0; r4 < 4; ++r4)
        #pragma unroll
        for (int c4 = 0; c4 < 2; ++c4) {
            const int n = bn0 + w * 32 + c4 * 16 + lm;
            #pragma unroll
            for (int reg = 0; reg < 4; ++reg) {
                const int m = bm0 + r4 * 16 + lq * 4 + reg;
                out[(size_t)m * 1024 + n] = acc[r4][c4][reg];
            }
        }
}

// ---------------------------------------------------------------------------
// MFMA attention (unchanged from R17: fused content+softmax, XCD grid,
// setprio, b64 score RMW, bare exp2).
// ---------------------------------------------------------------------------
__device__ __forceinline__ int sidx(int m, int c) {   // m in [0,32), c in [0,1024)
    return (m << 10) + (c ^ (m << 3));
}

__global__ __launch_bounds__(512)
void attn_mfma(const short* __restrict__ qu_bf, const short* __restrict__ qv_bf,
               const short* __restrict__ k_bf,  const short* __restrict__ vt_bf,
               const short* __restrict__ r_bf,
               float* __restrict__ opart, float* __restrict__ ml)
{
    __shared__ unsigned short sc[32 * 1024];   // 64 KB
    __shared__ float wsum[16][2][8];           // 1 KB per-wave row partials
    __half* sch = (__half*)sc;
    float*  scF = (float*)sc;                  // reused after PV reads

    // XCD-aware decode: L&7 = XCD (round-robin dispatch); each XCD owns
    // bh in [4*xcd, 4*xcd+4), processed stream-by-stream.
    const int L   = blockIdx.x;
    const int xcd = L & 7;
    const int pp  = L >> 3;                    // 0..255
    const int bh  = (xcd << 2) + (pp >> 6);    // 4 streams per XCD
    const int sub = pp & 63;
    const int it  = sub >> 1;
    const int jh  = sub & 1;

    const int i0  = it * 32;
    const int cbeg = jh << 10, cend = cbeg + 1024;
    const int h   = bh & (H - 1);
    const int tid = threadIdx.x;
    const int w    = tid >> 6;       // 0..7
    const int lane = tid & 63;
    const int lm   = lane & 15;
    const int lq   = lane >> 4;
    const int slot = (it * 32 + bh) * 2 + jh;

    // ---- A fragments ----
    const short* qup0 = qu_bf + ((size_t)(bh * S + i0 + lm)) * DH + lq * 8;
    const short* qup1 = qup0 + 16 * DH;
    bf16x8 au00 = *(const bf16x8*)qup0,        au01 = *(const bf16x8*)(qup0 + 32);
    bf16x8 au10 = *(const bf16x8*)qup1,        au11 = *(const bf16x8*)(qup1 + 32);
    const short* qvp0 = qv_bf + ((size_t)(bh * S + i0 + lm)) * DH + lq * 8;
    const short* qvp1 = qvp0 + 16 * DH;
    bf16x8 av00 = *(const bf16x8*)qvp0,        av01 = *(const bf16x8*)(qvp0 + 32);
    bf16x8 av10 = *(const bf16x8*)qvp1,        av11 = *(const bf16x8*)(qvp1 + 32);
    int r1a = i0 + 1 + lm;  if (r1a > S - 1) r1a = S - 1;   // clamped rows masked
    int r1b = i0 + 17 + lm; if (r1b > S - 1) r1b = S - 1;
    const short* qwp0 = qv_bf + ((size_t)(bh * S + r1a)) * DH + lq * 8;
    const short* qwp1 = qv_bf + ((size_t)(bh * S + r1b)) * DH + lq * 8;
    bf16x8 aw00 = *(const bf16x8*)qwp0,        aw01 = *(const bf16x8*)(qwp0 + 32);
    bf16x8 aw10 = *(const bf16x8*)qwp1,        aw11 = *(const bf16x8*)(qwp1 + 32);

    // ---- zero the pos hole column: row m, col i0+m+1025 (if in window) ----
    if (tid < 32) {
        int hole = i0 + tid + 1025;
        if (hole >= cbeg && hole < cend) sc[sidx(tid, hole - cbeg)] = 0;
    }

    const short* rbase = r_bf + (size_t)h * J * DH;

    // ---- pos main: col = i0 + 16t + lm + m - 1023; depth-2 prefetch ----
    {
        int tmp = cbeg + 977 - i0;
        int tlo = tmp > 0 ? ((tmp + 15) >> 4) : 0;
        int thi = (cend + 1022 - i0) >> 4; if (thi > 127) thi = 127;
        int t = tlo + w;
        if (t <= thi) {
            const short* rp = rbase + (size_t)(t * 16 + lm) * DH + lq * 8;
            bf16x8 b0 = *(const bf16x8*)rp, b1 = *(const bf16x8*)(rp + 32);
            bf16x8 p0, p1;
            if (t + 8 <= thi) {
                const short* rp2 = rbase + (size_t)((t + 8) * 16 + lm) * DH + lq * 8;
                p0 = *(const bf16x8*)rp2; p1 = *(const bf16x8*)(rp2 + 32);
            }
            for (; t <= thi; t += 8) {
                bf16x8 n0, n1;
                if (t + 16 <= thi) {
                    const short* rpn = rbase + (size_t)((t + 16) * 16 + lm) * DH + lq * 8;
                    n0 = *(const bf16x8*)rpn; n1 = *(const bf16x8*)(rpn + 32);
                }
                f32x4 c0 = {0.f,0.f,0.f,0.f}, c1 = {0.f,0.f,0.f,0.f};
                __builtin_amdgcn_s_setprio(1);
                c0 = __builtin_amdgcn_mfma_f32_16x16x32_bf16(av00, b0, c0, 0, 0, 0);
                c1 = __builtin_amdgcn_mfma_f32_16x16x32_bf16(av10, b0, c1, 0, 0, 0);
                c0 = __builtin_amdgcn_mfma_f32_16x16x32_bf16(av01, b1, c0, 0, 0, 0);
                c1 = __builtin_amdgcn_mfma_f32_16x16x32_bf16(av11, b1, c1, 0, 0, 0);
                __builtin_amdgcn_s_setprio(0);
                int cb = i0 + t * 16 + lm - 1023 - cbeg;     // local col for m=0
                int base = i0 + 16 * t - 1023;               // scalar col_min
                if (base >= cbeg && base + 46 < cend) {
                    #pragma unroll
                    for (int r = 0; r < 4; ++r) {
                        int m0 = lq * 4 + r, m1 = m0 + 16;
                        sch[sidx(m0, cb + m0)] = __float2half(c0[r]);
                        sch[sidx(m1, cb + m1)] = __float2half(c1[r]);
                    }
                } else {
                    #pragma unroll
                    for (int r = 0; r < 4; ++r) {
                        int m0 = lq * 4 + r, m1 = m0 + 16;
                        int cA = cb + m0, cB = cb + m1;
                        if (cA >= 0 && cA < 1024) sch[sidx(m0, cA)] = __float2half(c0[r]);
                        if (cB >= 0 && cB < 1024) sch[sidx(m1, cB)] = __float2half(c1[r]);
                    }
                }
                b0 = p0; b1 = p1; p0 = n0; p1 = n1;
            }
        }
    }

    // ---- pos wrap: col = i0 + 16t + lm + m + 1026, rows Qv[i+1]; depth-2 ----
    {
        int tmpw = cbeg - 1072 - i0;
        int tlw = tmpw > 0 ? ((tmpw + 15) >> 4) : 0;
        int thw = (cend - 1027 - i0) >> 4; if (thw > 127) thw = 127;
        int t = tlw + w;
        if (t <= thw) {
            const short* rp = rbase + (size_t)(t * 16 + lm) * DH + lq * 8;
            bf16x8 b0 = *(const bf16x8*)rp, b1 = *(const bf16x8*)(rp + 32);
            bf16x8 p0, p1;
            if (t + 8 <= thw) {
                const short* rp2 = rbase + (size_t)((t + 8) * 16 + lm) * DH + lq * 8;
                p0 = *(const bf16x8*)rp2; p1 = *(const bf16x8*)(rp2 + 32);
            }
            for (; t <= thw; t += 8) {
                bf16x8 n0, n1;
                if (t + 16 <= thw) {
                    const short* rpn = rbase + (size_t)((t + 16) * 16 + lm) * DH + lq * 8;
                    n0 = *(const bf16x8*)rpn; n1 = *(const bf16x8*)(rpn + 32);
                }
                f32x4 c0 = {0.f,0.f,0.f,0.f}, c1 = {0.f,0.f,0.f,0.f};
                __builtin_amdgcn_s_setprio(1);
                c0 = __builtin_amdgcn_mfma_f32_16x16x32_bf16(aw00, b0, c0, 0, 0, 0);
                c1 = __builtin_amdgcn_mfma_f32_16x16x32_bf16(aw10, b0, c1, 0, 0, 0);
                c0 = __builtin_amdgcn_mfma_f32_16x16x32_bf16(aw01, b1, c0, 0, 0, 0);
                c1 = __builtin_amdgcn_mfma_f32_16x16x32_bf16(aw11, b1, c1, 0, 0, 0);
                __builtin_amdgcn_s_setprio(0);
                int cb = i0 + t * 16 + lm + 1026 - cbeg;
                int base = i0 + 16 * t + 1026;
                if (base >= cbeg && base + 46 < cend) {
                    #pragma unroll
                    for (int r = 0; r < 4; ++r) {
                        int m0 = lq * 4 + r, m1 = m0 + 16;
                        sch[sidx(m0, cb + m0)] = __float2half(c0[r]);
                        sch[sidx(m1, cb + m1)] = __float2half(c1[r]);
                    }
                } else {
                    #pragma unroll
                    for (int r = 0; r < 4; ++r) {
                        int m0 = lq * 4 + r, m1 = m0 + 16;
                        int cA = cb + m0, cB = cb + m1;
                        if (cA >= 0 && cA < 1024) sch[sidx(m0, cA)] = __float2half(c0[r]);
                        if (cB >= 0 && cB < 1024) sch[sidx(m1, cB)] = __float2half(c1[r]);
                    }
                }
                b0 = p0; b1 = p1; p0 = n0; p1 = n1;
            }
        }
    }

    // ---- prefetch first two content K-tiles before the barrier ----
    const short* kbase = k_bf + (size_t)bh * J * DH;
    bf16x8 kb0, kb1, kc0, kc1;
    {
        int t0 = jh * 64 + w + 8 * ((it) & 7);
        int t1 = jh * 64 + w + 8 * ((1 + it) & 7);
        const short* kp0 = kbase + (size_t)(t0 * 16 + lm) * DH + lq * 8;
        const short* kp1 = kbase + (size_t)(t1 * 16 + lm) * DH + lq * 8;
        kb0 = *(const bf16x8*)kp0; kb1 = *(const bf16x8*)(kp0 + 32);
        kc0 = *(const bf16x8*)kp1; kc1 = *(const bf16x8*)(kp1 + 32);
    }
    __syncthreads();

    // ---- content + softmax FUSED ----
    float sum0 = 0.f, sum1 = 0.f;
    #pragma unroll 1
    for (int g = 0; g < 8; ++g) {
        bf16x8 nb0, nb1;
        if (g + 2 < 8) {
            int u = jh * 64 + w + 8 * ((g + 2 + it) & 7);
            const short* np = kbase + (size_t)(u * 16 + lm) * DH + lq * 8;
            nb0 = *(const bf16x8*)np; nb1 = *(const bf16x8*)(np + 32);
        }
        int t = jh * 64 + w + 8 * ((g + it) & 7);
        int lc = t * 16 - cbeg;                  // 16-aligned local col base
        int aA = sidx(lm,      lc + lq * 4);     // 4 consecutive u16, 8B-aligned
        int aB = sidx(lm + 16, lc + lq * 4);
        h16x4 hA = *(const h16x4*)(sc + aA);
        h16x4 hB = *(const h16x4*)(sc + aB);
        f32x4 c0, c1;
        #pragma unroll
        for (int r = 0; r < 4; ++r) { c0[r] = (float)hA[r]; c1[r] = (float)hB[r]; }
        __builtin_amdgcn_s_setprio(1);
        c0 = __builtin_amdgcn_mfma_f32_16x16x32_bf16(kb0, au00, c0, 0, 0, 0);
        c1 = __builtin_amdgcn_mfma_f32_16x16x32_bf16(kb0, au10, c1, 0, 0, 0);
        c0 = __builtin_amdgcn_mfma_f32_16x16x32_bf16(kb1, au01, c0, 0, 0, 0);
        c1 = __builtin_amdgcn_mfma_f32_16x16x32_bf16(kb1, au11, c1, 0, 0, 0);
        __builtin_amdgcn_s_setprio(0);
        us4 oA, oB;
        #pragma unroll
        for (int r = 0; r < 4; ++r) {
            float e0 = __builtin_amdgcn_exp2f(c0[r]);
            float e1 = __builtin_amdgcn_exp2f(c1[r]);
            sum0 += e0; sum1 += e1;
            oA[r] = f2bf_fast(e0);
            oB[r] = f2bf_fast(e1);
        }
        *(us4*)(sc + aA) = oA;
        *(us4*)(sc + aB) = oB;
        kb0 = kc0; kb1 = kc1; kc0 = nb0; kc1 = nb1;
    }
    // per-wave row partials: reduce over lq group (lanes lm, lm+16/32/48)
    sum0 += __shfl_xor(sum0, 16); sum0 += __shfl_xor(sum0, 32);
    sum1 += __shfl_xor(sum1, 16); sum1 += __shfl_xor(sum1, 32);
    if (lane < 16) { wsum[lane][0][w] = sum0; wsum[lane][1][w] = sum1; }

    // ---- prefetch first PV V-chunk before the barrier ----
    const int dslice = w & 3, jq = w >> 2;
    const short* vtb = vt_bf + ((size_t)bh * DH + dslice * 16 + lm) * J + cbeg + jq * 512;
    bf16x8 cv0, cv1, cv2, cv3;
    {
        int j0 = (it & 3) * 128;
        cv0 = *(const bf16x8*)(vtb + j0 +  0 + lq * 8);
        cv1 = *(const bf16x8*)(vtb + j0 + 32 + lq * 8);
        cv2 = *(const bf16x8*)(vtb + j0 + 64 + lq * 8);
        cv3 = *(const bf16x8*)(vtb + j0 + 96 + lq * 8);
    }
    __syncthreads();

    // ---- ml write (probs/wsum complete after barrier) ----
    if (tid < 32) {
        float s = 0.f;
        #pragma unroll
        for (int ww = 0; ww < 8; ++ww) s += wsum[tid & 15][tid >> 4][ww];
        ml[(size_t)slot * 64 + tid * 2]     = 0.f;
        ml[(size_t)slot * 64 + tid * 2 + 1] = s;
    }

    // ---- PV: wave -> d-slice (w&3), j-quarter (w>>2); rolling V prefetch ----
    f32x4 pa0 = {0.f,0.f,0.f,0.f}, pa1 = {0.f,0.f,0.f,0.f};
    f32x4 pa2 = {0.f,0.f,0.f,0.f}, pa3 = {0.f,0.f,0.f,0.f};
    f32x4 pb0 = {0.f,0.f,0.f,0.f}, pb1 = {0.f,0.f,0.f,0.f};
    f32x4 pb2 = {0.f,0.f,0.f,0.f}, pb3 = {0.f,0.f,0.f,0.f};
    #pragma unroll 1
    for (int jo0 = 0; jo0 < 4; ++jo0) {       // 128 local j per iteration
        bf16x8 nv0, nv1, nv2, nv3;
        if (jo0 < 3) {
            int jn = ((jo0 + 1 + it) & 3) * 128;
            nv0 = *(const bf16x8*)(vtb + jn +  0 + lq * 8);
            nv1 = *(const bf16x8*)(vtb + jn + 32 + lq * 8);
            nv2 = *(const bf16x8*)(vtb + jn + 64 + lq * 8);
            nv3 = *(const bf16x8*)(vtb + jn + 96 + lq * 8);
        }
        int j0 = ((jo0 + it) & 3) * 128;
        int lb = jq * 512 + j0;
        bf16x8 a0 = *(const bf16x8*)(sc + sidx(lm, lb +  0 + lq * 8));
        bf16x8 a1 = *(const bf16x8*)(sc + sidx(lm, lb + 32 + lq * 8));
        bf16x8 a2 = *(const bf16x8*)(sc + sidx(lm, lb + 64 + lq * 8));
        bf16x8 a3 = *(const bf16x8*)(sc + sidx(lm, lb + 96 + lq * 8));
        bf16x8 c0 = *(const bf16x8*)(sc + sidx(16 + lm, lb +  0 + lq * 8));
        bf16x8 c1 = *(const bf16x8*)(sc + sidx(16 + lm, lb + 32 + lq * 8));
        bf16x8 c2 = *(const bf16x8*)(sc + sidx(16 + lm, lb + 64 + lq * 8));
        bf16x8 c3 = *(const bf16x8*)(sc + sidx(16 + lm, lb + 96 + lq * 8));
        __builtin_amdgcn_s_setprio(1);
        pa0 = __builtin_amdgcn_mfma_f32_16x16x32_bf16(a0, cv0, pa0, 0, 0, 0);
        pb0 = __builtin_amdgcn_mfma_f32_16x16x32_bf16(c0, cv0, pb0, 0, 0, 0);
        pa1 = __builtin_amdgcn_mfma_f32_16x16x32_bf16(a1, cv1, pa1, 0, 0, 0);
        pb1 = __builtin_amdgcn_mfma_f32_16x16x32_bf16(c1, cv1, pb1, 0, 0, 0);
        pa2 = __builtin_amdgcn_mfma_f32_16x16x32_bf16(a2, cv2, pa2, 0, 0, 0);
        pb2 = __builtin_amdgcn_mfma_f32_16x16x32_bf16(c2, cv2, pb2, 0, 0, 0);
        pa3 = __builtin_amdgcn_mfma_f32_16x16x32_bf16(a3, cv3, pa3, 0, 0, 0);
        pb3 = __builtin_amdgcn_mfma_f32_16x16x32_bf16(c3, cv3, pb3, 0, 0, 0);
        __builtin_amdgcn_s_setprio(0);
        if (jo0 < 3) { cv0 = nv0; cv1 = nv1; cv2 = nv2; cv3 = nv3; }
    }
    __syncthreads();   // all probs read; sc reusable as float scratch

    #pragma unroll
    for (int r = 0; r < 4; ++r) {
        int m0 = lq * 4 + r, m1 = m0 + 16;
        scF[jq * 2048 + m0 * 64 + dslice * 16 + lm] = pa0[r] + pa1[r] + pa2[r] + pa3[r];
        scF[jq * 2048 + m1 * 64 + dslice * 16 + lm] = pb0[r] + pb1[r] + pb2[r] + pb3[r];
    }
    __syncthreads();

    float* op = opart + (size_t)slot * 2048;
    #pragma unroll
    for (int e = tid; e < 2048; e += 512)
        op[e] = scF[e] + scF[2048 + e];
}

// ---------------------------------------------------------------------------
// Merge the two j-half partials. R18: vectorized (float4 loads, s16x4 store).
// ---------------------------------------------------------------------------
__global__ __launch_bounds__(256)
void attn_combine(const float* __restrict__ opart, const float* __restrict__ ml,
                  short* __restrict__ o_bf)
{
    const int blk = blockIdx.x;           // it*32 + bh
    const int it = blk >> 5, bh = blk & 31;
    const int h = bh & 15, bb = bh >> 4;
    __shared__ float wgt[32][2];
    const int tid = threadIdx.x;
    if (tid < 32) {
        float m0 = ml[(size_t)(blk * 2 + 0) * 64 + tid * 2];
        float l0 = ml[(size_t)(blk * 2 + 0) * 64 + tid * 2 + 1];
        float m1 = ml[(size_t)(blk * 2 + 1) * 64 + tid * 2];
        float l1 = ml[(size_t)(blk * 2 + 1) * 64 + tid * 2 + 1];
        float mx = fmaxf(m0, m1);
        float e0 = __expf(m0 - mx), e1 = __expf(m1 - mx);
        float inv = 1.0f / (e0 * l0 + e1 * l1);
        wgt[tid][0] = e0 * inv;
        wgt[tid][1] = e1 * inv;
    }
    __syncthreads();
    const float* p0 = opart + (size_t)(blk * 2 + 0) * 2048;
    const float* p1 = opart + (size_t)(blk * 2 + 1) * 2048;
    #pragma unroll
    for (int e4 = tid; e4 < 512; e4 += 256) {
        int e = e4 * 4;
        int m = e >> 6, d = e & 63;
        float4 a = *(const float4*)(p0 + e);
        float4 b = *(const float4*)(p1 + e);
        float w0 = wgt[m][0], w1 = wgt[m][1];
        s16x4 o = { f2bs(a.x * w0 + b.x * w1), f2bs(a.y * w0 + b.y * w1),
                    f2bs(a.z * w0 + b.z * w1), f2bs(a.w * w0 + b.w * w1) };
        *(s16x4*)(o_bf + ((size_t)(it * 32 + m) * B + bb) * (H * DH) + h * DH + d) = o;
    }
}

// ---------------------------------------------------------------------------
extern "C" void kernel_launch(void* const* d_in, const int* in_sizes, int n_in,
                              void* d_out, int out_size, void* d_ws, size_t ws_size,
                              hipStream_t stream)
{
    const float* x    = (const float*)d_in[0];   // [S, B, D]
    const float* pemb = (const float*)d_in[1];   // [S+M, D]
    const float* mem  = (const float*)d_in[2];   // [M, B, D]
    const float* u    = (const float*)d_in[3];   // [H, DH]
    const float* v    = (const float*)d_in[4];   // [H, DH]
    const float* Wkv  = (const float*)d_in[5];   // [D, 2*H*DH]
    const float* Wq   = (const float*)d_in[6];   // [D, H*DH]
    const float* Wpos = (const float*)d_in[7];   // [D, H*DH]
    const float* Wout = (const float*)d_in[8];   // [H*DH, D]
    float* out = (float*)d_out;                  // [S, B, D]

    char* p = (char*)d_ws;
    short* a_bf  = (short*)p; p += (size_t)4096 * 1024 * 2;    // mem||x  [0,8M)
    short* p_bf  = (short*)p; p += (size_t)2048 * 1024 * 2;    // [8M,12M)
    short* wkvt  = (short*)p; p += (size_t)2048 * 1024 * 2;    // [12M,16M)
    short* wqt   = (short*)p; p += (size_t)1024 * 1024 * 2;    // [16M,18M)
    short* wpt   = (short*)p; p += (size_t)1024 * 1024 * 2;    // [18M,20M)
    short* wot   = (short*)p; p += (size_t)1024 * 1024 * 2;    // [20M,22M)
    short* k_bf  = (short*)p; p += (size_t)B * H * J * DH * 2;
    short* vt_bf = (short*)p; p += (size_t)B * H * J * DH * 2;
    short* qu_bf = (short*)p; p += (size_t)B * H * S * DH * 2;
    short* qv_bf = (short*)p; p += (size_t)B * H * S * DH * 2;
    short* r_bf  = (short*)p; p += (size_t)H * J * DH * 2;
    short* o_bf  = (short*)p;

    // attn partials alias prep buffers (dead after proj_fused):
    // opart: [0,16M) over a_bf/p_bf/wkvt (2048 slots x 2048 fp32 = 16 MB);
    // ml: [16M,16.5M) over wqt (2048 slots x 64 fp32).
    float* opart = (float*)d_ws;
    float* ml    = (float*)((char*)d_ws + (size_t)16 * 1024 * 1024);

    prep<<<7424, 256, 0, stream>>>(mem, x, pemb, Wkv, Wq, Wpos, Wout,
                                   a_bf, p_bf, wkvt, wqt, wpt, wot);
    proj_fused<<<768, 256, 0, stream>>>(a_bf, p_bf, wkvt, wqt, wpt,
                                        k_bf, vt_bf, qu_bf, qv_bf, r_bf, u, v);
    attn_mfma<<<2048, 512, 0, stream>>>(
        qu_bf, qv_bf, k_bf, vt_bf, r_bf, opart, ml);
    attn_combine<<<(S / 32) * B * H, 256, 0, stream>>>(opart, ml, o_bf);
    gemm_out<<<dim3(8, 32), 256, 0, stream>>>(o_bf, wot, out);
}

// Round 10
// 282.862 us; speedup vs baseline: 1.1335x; 1.0038x over previous
//
#include <hip/hip_runtime.h>
#include <hip/hip_bf16.h>
#include <hip/hip_fp16.h>
#include <math.h>

#define D    1024
#define H    16
#define DH   64
#define S    1024
#define M    1024
#define B    2
#define J    2048          // M + S
#define SCALE 0.125f       // 1/sqrt(64)
#define SCALE_L2E 0.18033688f   // SCALE * log2(e): softmax uses bare exp2

typedef __attribute__((ext_vector_type(8))) short        bf16x8;
typedef __attribute__((ext_vector_type(4))) short        s16x4;
typedef __attribute__((ext_vector_type(8))) _Float16     h16x8;
typedef __attribute__((ext_vector_type(4))) _Float16     h16x4;
typedef __attribute__((ext_vector_type(8))) unsigned short us8;
typedef __attribute__((ext_vector_type(4))) unsigned short us4;
typedef __attribute__((ext_vector_type(4))) float        f32x4;

__device__ __forceinline__ short f2bs(float f) {
    __hip_bfloat16 t = __float2bfloat16(f);
    short r; __builtin_memcpy(&r, &t, 2); return r;
}
// fast bf16 pack (round-half-up); inputs finite non-negative (probs)
__device__ __forceinline__ unsigned short f2bf_fast(float f) {
    unsigned int u; __builtin_memcpy(&u, &f, 4);
    return (unsigned short)((u + 0x8000u) >> 16);
}

// async global->LDS, 16 bytes per lane
__device__ __forceinline__ void g2l16(const short* g, short* l) {
    __builtin_amdgcn_global_load_lds(
        (const __attribute__((address_space(1))) unsigned int*)g,
        (__attribute__((address_space(3))) unsigned int*)l, 16, 0, 0);
}

// ---------------------------------------------------------------------------
// prep: blocks [0,6144)  fp32->bf16 flat convert (mem||x -> a_bf, pemb -> p_bf)
//       blocks [6144,7424) 64x64 weight transpose+convert W[k][n] -> Wt[n][k]
// ---------------------------------------------------------------------------
__global__ __launch_bounds__(256)
void prep(const float* __restrict__ mem, const float* __restrict__ x,
          const float* __restrict__ pemb,
          const float* __restrict__ Wkv, const float* __restrict__ Wq,
          const float* __restrict__ Wpos, const float* __restrict__ Wout,
          short* __restrict__ a_bf, short* __restrict__ p_bf,
          short* __restrict__ wkvt, short* __restrict__ wqt,
          short* __restrict__ wpt,  short* __restrict__ wot)
{
    __shared__ float t[64][65];
    int blk = blockIdx.x;
    const int tid = threadIdx.x;
    if (blk < 6144) {
        const int idx = (blk * 256 + tid) * 4;
        const int TWO_M = 2 * 1024 * 1024;
        float4 v; short* dst;
        if (idx < TWO_M)          { v = *(const float4*)(mem  + idx);           dst = a_bf + idx; }
        else if (idx < 2 * TWO_M) { v = *(const float4*)(x    + idx - TWO_M);   dst = a_bf + idx; }
        else                      { v = *(const float4*)(pemb + idx - 2*TWO_M); dst = p_bf + idx - 2*TWO_M; }
        s16x4 o = { f2bs(v.x), f2bs(v.y), f2bs(v.z), f2bs(v.w) };
        *(s16x4*)dst = o;
        return;
    }
    blk -= 6144;
    const float* src; short* dst; int N, t0;
    if (blk < 512)       { src = Wkv;  dst = wkvt; N = 2048; t0 = blk; }
    else if (blk < 768)  { src = Wq;   dst = wqt;  N = 1024; t0 = blk - 512; }
    else if (blk < 1024) { src = Wpos; dst = wpt;  N = 1024; t0 = blk - 768; }
    else                 { src = Wout; dst = wot;  N = 1024; t0 = blk - 1024; }
    const int ntn = N >> 6;
    const int k0 = (t0 / ntn) * 64, n0 = (t0 % ntn) * 64;
    #pragma unroll
    for (int e = tid; e < 4096; e += 256) {
        int r = e >> 6, c = e & 63;
        t[r][c] = src[(size_t)(k0 + r) * N + n0 + c];
    }
    __syncthreads();
    #pragma unroll
    for (int e = tid; e < 4096; e += 256) {
        int nr = e >> 6, kc = e & 63;
        dst[(size_t)(n0 + nr) * 1024 + k0 + kc] = f2bs(t[kc][nr]);
    }
}

// ---------------------------------------------------------------------------
// Shared MFMA GEMM core: BM=BN=128, BK=64, 256 thr, K=1024.
// ---------------------------------------------------------------------------
__device__ __forceinline__ void gemm_core(const short* __restrict__ A,
                                          const short* __restrict__ Bt,
                                          short* As, short* Bs,
                                          int bm0, int bn0, int tid,
                                          f32x4 acc[4][4])
{
    const int w    = tid >> 6;
    const int wy   = w >> 1, wx = w & 1;
    const int lane = tid & 63;
    const int lm   = lane & 15;
    const int lq   = lane >> 4;

    for (int k0 = 0; k0 < 1024; k0 += 64) {
        const short* Ab = A  + (size_t)bm0 * 1024 + k0;
        const short* Bb = Bt + (size_t)bn0 * 1024 + k0;
        #pragma unroll
        for (int t = 0; t < 4; ++t) {
            int s = t * 256 + tid;
            int r = s >> 3, c = s & 7;
            int cg = c ^ (r & 7);
            g2l16(Ab + r * 1024 + cg * 8, As + s * 8);
            g2l16(Bb + r * 1024 + cg * 8, Bs + s * 8);
        }
        __syncthreads();
        #pragma unroll
        for (int kk = 0; kk < 2; ++kk) {
            bf16x8 af[4], bg[4];
            #pragma unroll
            for (int r4 = 0; r4 < 4; ++r4) {
                int ar = wy * 64 + r4 * 16 + lm;
                int kc = kk * 4 + lq;
                af[r4] = *(const bf16x8*)(As + ((ar << 3) + (kc ^ (ar & 7))) * 8);
            }
            #pragma unroll
            for (int c4 = 0; c4 < 4; ++c4) {
                int br = wx * 64 + c4 * 16 + lm;
                int kc = kk * 4 + lq;
                bg[c4] = *(const bf16x8*)(Bs + ((br << 3) + (kc ^ (br & 7))) * 8);
            }
            #pragma unroll
            for (int r4 = 0; r4 < 4; ++r4)
                #pragma unroll
                for (int c4 = 0; c4 < 4; ++c4)
                    acc[r4][c4] = __builtin_amdgcn_mfma_f32_16x16x32_bf16(
                        af[r4], bg[c4], acc[r4][c4], 0, 0, 0);
        }
        __syncthreads();
    }
}

// ---------------------------------------------------------------------------
// Fused kv/q/r projections. qu/qv scaled by SCALE*log2(e) (bare exp2 attn).
// R18 XCD-aware block remap (bijective: 768 = 8 x 96).
// ---------------------------------------------------------------------------
__global__ __launch_bounds__(256)
void proj_fused(const short* __restrict__ a_bf, const short* __restrict__ p_bf,
                const short* __restrict__ wkvt, const short* __restrict__ wqt,
                const short* __restrict__ wpt,
                short* __restrict__ k_bf, short* __restrict__ vt_bf,
                short* __restrict__ qu_bf, short* __restrict__ qv_bf,
                short* __restrict__ r_bf,
                const float* __restrict__ uvec, const float* __restrict__ vvec)
{
    __shared__ __align__(16) short As[128 * 64];
    __shared__ __align__(16) short Bs[128 * 64];

    // XCD remap: HW sends original id L to XCD L&7; logical id below makes
    // XCD x execute the contiguous logical range [x*96, (x+1)*96).
    int blk = (blockIdx.x & 7) * 96 + (blockIdx.x >> 3);

    int mode, bx, by;
    const short *A, *Bt;
    if (blk < 512)      { bx = blk & 15; by = blk >> 4;
                          if (bx >= 8) { mode = 4; A = wkvt; Bt = a_bf; }   // swapped V
                          else         { mode = 0; A = a_bf; Bt = wkvt; } }
    else if (blk < 640) { int b2 = blk - 512; mode = 1; bx = b2 & 7; by = b2 >> 3;
                          A = a_bf + (size_t)2048 * 1024; Bt = wqt; }
    else                { int b3 = blk - 640; mode = 2; bx = b3 & 7; by = b3 >> 3;
                          A = p_bf; Bt = wpt; }
    const int bn0 = (mode == 4) ? by * 128 : bx * 128;
    const int bm0 = (mode == 4) ? bx * 128 : by * 128;
    const int tid = threadIdx.x;
    const int w = tid >> 6, wy = w >> 1, wx = w & 1;
    const int lane = tid & 63, lm = lane & 15, lq = lane >> 4;

    f32x4 acc[4][4];
    #pragma unroll
    for (int r = 0; r < 4; ++r)
        #pragma unroll
        for (int c = 0; c < 4; ++c) acc[r][c] = (f32x4){0.f, 0.f, 0.f, 0.f};

    gemm_core(A, Bt, As, Bs, bm0, bn0, tid, acc);

    #pragma unroll
    for (int r4 = 0; r4 < 4; ++r4) {
        #pragma unroll
        for (int c4 = 0; c4 < 4; ++c4) {
            const int n = bn0 + wx * 64 + c4 * 16 + lm;
            float ubias = 0.f, vbias = 0.f;
            if (mode == 1) { ubias = uvec[n]; vbias = vvec[n]; }
            #pragma unroll
            for (int reg = 0; reg < 4; ++reg) {
                const int m = bm0 + wy * 64 + r4 * 16 + lq * 4 + reg;
                const float val = acc[r4][c4][reg];
                if (mode == 0) {
                    int j = m >> 1, b = m & 1;
                    int h = n >> 6, d = n & 63;
                    k_bf[(((size_t)b * H + h) * J + j) * DH + d] = f2bs(val);
                } else if (mode == 4) {
                    int n2 = m - 1024, h = n2 >> 6, d = n2 & 63;
                    int j = n >> 1, b = n & 1;
                    vt_bf[(((size_t)b * H + h) * DH + d) * J + j] = f2bs(val);
                } else if (mode == 1) {
                    int i = m >> 1, b = m & 1;
                    int h = n >> 6, d = n & 63;
                    size_t o = (((size_t)b * H + h) * S + i) * DH + d;
                    qu_bf[o] = f2bs((val + ubias) * SCALE_L2E);
                    qv_bf[o] = f2bs((val + vbias) * SCALE_L2E);
                } else {
                    int h = n >> 6, d = n & 63;
                    r_bf[((size_t)h * J + m) * DH + d] = f2bs(val);
                }
            }
        }
    }
}

// ---------------------------------------------------------------------------
// Output projection: M=2048, N=1024, fp32 out. BM=64, BN=128, 256 blocks.
// R19: 1D grid + XCD remap (256 = 8 x 32): each XCD owns 32 contiguous
// logical blocks (4 A-panels + all wot, ~3 MB <= L2) instead of the
// round-robin scatter that re-fetched A-panels per XCD.
// ---------------------------------------------------------------------------
__global__ __launch_bounds__(256)
void gemm_out(const short* __restrict__ A, const short* __restrict__ Bt,
              float* __restrict__ out)
{
    __shared__ __align__(16) short As[64 * 64];    // 8 KB
    __shared__ __align__(16) short Bs[128 * 64];   // 16 KB
    const int lb = (blockIdx.x & 7) * 32 + (blockIdx.x >> 3);  // XCD-contig
    const int bn0 = (lb & 7) * 128, bm0 = (lb >> 3) * 64;
    const int tid = threadIdx.x;
    const int w = tid >> 6;                 // 0..3 = column-split wave index
    const int lane = tid & 63, lm = lane & 15, lq = lane >> 4;

    f32x4 acc[4][2];
    #pragma unroll
    for (int r = 0; r < 4; ++r)
        #pragma unroll
        for (int c = 0; c < 2; ++c) acc[r][c] = (f32x4){0.f, 0.f, 0.f, 0.f};

    for (int k0 = 0; k0 < 1024; k0 += 64) {
        const short* Ab = A  + (size_t)bm0 * 1024 + k0;
        const short* Bb = Bt + (size_t)bn0 * 1024 + k0;
        #pragma unroll
        for (int t = 0; t < 2; ++t) {       // A: 64 rows
            int s = t * 256 + tid;
            int r = s >> 3, c = s & 7;
            int cg = c ^ (r & 7);
            g2l16(Ab + r * 1024 + cg * 8, As + s * 8);
        }
        #pragma unroll
        for (int t = 0; t < 4; ++t) {       // B: 128 rows
            int s = t * 256 + tid;
            int r = s >> 3, c = s & 7;
            int cg = c ^ (r & 7);
            g2l16(Bb + r * 1024 + cg * 8, Bs + s * 8);
        }
        __syncthreads();
        #pragma unroll
        for (int kk = 0; kk < 2; ++kk) {
            bf16x8 af[4], bg[2];
            #pragma unroll
            for (int r4 = 0; r4 < 4; ++r4) {
                int ar = r4 * 16 + lm;
                int kc = kk * 4 + lq;
                af[r4] = *(const bf16x8*)(As + ((ar << 3) + (kc ^ (ar & 7))) * 8);
            }
            #pragma unroll
            for (int c4 = 0; c4 < 2; ++c4) {
                int br = w * 32 + c4 * 16 + lm;
                int kc = kk * 4 + lq;
                bg[c4] = *(const bf16x8*)(Bs + ((br << 3) + (kc ^ (br & 7))) * 8);
            }
            #pragma unroll
            for (int r4 = 0; r4 < 4; ++r4)
                #pragma unroll
                for (int c4 = 0; c4 < 2; ++c4)
                    acc[r4][c4] = __builtin_amdgcn_mfma_f32_16x16x32_bf16(
                        af[r4], bg[c4], acc[r4][c4], 0, 0, 0);
        }
        __syncthreads();
    }

    #pragma unroll
    for (int r4 = 0; r4 < 4; ++r4)
        #pragma unroll
        for (int c4 = 0; c4 < 2; ++c4) {
            const int n = bn0 + w * 32 + c4 * 16 + lm;
            #pragma unroll
            for (int reg = 0; reg < 4; ++reg) {
                const int m = bm0 + r4 * 16 + lq * 4 + reg;
                out[(size_t)m * 1024 + n] = acc[r4][c4][reg];
            }
        }
}

// ---------------------------------------------------------------------------
// MFMA attention (R17 structure). R19: depth-2 rolling prefetch of the
// SCORE reads in the content loop — the per-iteration serial chain was
// ds_read_b64 (~120 cyc, single-outstanding) -> cvt -> MFMA -> exp -> write;
// tiles are per-wave disjoint so reading tile g+1's scores before storing
// tile g's probs is race-free, hiding the LDS latency under the MFMAs.
// ---------------------------------------------------------------------------
__device__ __forceinline__ int sidx(int m, int c) {   // m in [0,32), c in [0,1024)
    return (m << 10) + (c ^ (m << 3));
}

__global__ __launch_bounds__(512)
void attn_mfma(const short* __restrict__ qu_bf, const short* __restrict__ qv_bf,
               const short* __restrict__ k_bf,  const short* __restrict__ vt_bf,
               const short* __restrict__ r_bf,
               float* __restrict__ opart, float* __restrict__ ml)
{
    __shared__ unsigned short sc[32 * 1024];   // 64 KB
    __shared__ float wsum[16][2][8];           // 1 KB per-wave row partials
    __half* sch = (__half*)sc;
    float*  scF = (float*)sc;                  // reused after PV reads

    // XCD-aware decode: L&7 = XCD (round-robin dispatch); each XCD owns
    // bh in [4*xcd, 4*xcd+4), processed stream-by-stream.
    const int L   = blockIdx.x;
    const int xcd = L & 7;
    const int pp  = L >> 3;                    // 0..255
    const int bh  = (xcd << 2) + (pp >> 6);    // 4 streams per XCD
    const int sub = pp & 63;
    const int it  = sub >> 1;
    const int jh  = sub & 1;

    const int i0  = it * 32;
    const int cbeg = jh << 10, cend = cbeg + 1024;
    const int h   = bh & (H - 1);
    const int tid = threadIdx.x;
    const int w    = tid >> 6;       // 0..7
    const int lane = tid & 63;
    const int lm   = lane & 15;
    const int lq   = lane >> 4;
    const int slot = (it * 32 + bh) * 2 + jh;

    // ---- A fragments ----
    const short* qup0 = qu_bf + ((size_t)(bh * S + i0 + lm)) * DH + lq * 8;
    const short* qup1 = qup0 + 16 * DH;
    bf16x8 au00 = *(const bf16x8*)qup0,        au01 = *(const bf16x8*)(qup0 + 32);
    bf16x8 au10 = *(const bf16x8*)qup1,        au11 = *(const bf16x8*)(qup1 + 32);
    const short* qvp0 = qv_bf + ((size_t)(bh * S + i0 + lm)) * DH + lq * 8;
    const short* qvp1 = qvp0 + 16 * DH;
    bf16x8 av00 = *(const bf16x8*)qvp0,        av01 = *(const bf16x8*)(qvp0 + 32);
    bf16x8 av10 = *(const bf16x8*)qvp1,        av11 = *(const bf16x8*)(qvp1 + 32);
    int r1a = i0 + 1 + lm;  if (r1a > S - 1) r1a = S - 1;   // clamped rows masked
    int r1b = i0 + 17 + lm; if (r1b > S - 1) r1b = S - 1;
    const short* qwp0 = qv_bf + ((size_t)(bh * S + r1a)) * DH + lq * 8;
    const short* qwp1 = qv_bf + ((size_t)(bh * S + r1b)) * DH + lq * 8;
    bf16x8 aw00 = *(const bf16x8*)qwp0,        aw01 = *(const bf16x8*)(qwp0 + 32);
    bf16x8 aw10 = *(const bf16x8*)qwp1,        aw11 = *(const bf16x8*)(qwp1 + 32);

    // ---- zero the pos hole column: row m, col i0+m+1025 (if in window) ----
    if (tid < 32) {
        int hole = i0 + tid + 1025;
        if (hole >= cbeg && hole < cend) sc[sidx(tid, hole - cbeg)] = 0;
    }

    const short* rbase = r_bf + (size_t)h * J * DH;

    // ---- pos main: col = i0 + 16t + lm + m - 1023; depth-2 prefetch ----
    {
        int tmp = cbeg + 977 - i0;
        int tlo = tmp > 0 ? ((tmp + 15) >> 4) : 0;
        int thi = (cend + 1022 - i0) >> 4; if (thi > 127) thi = 127;
        int t = tlo + w;
        if (t <= thi) {
            const short* rp = rbase + (size_t)(t * 16 + lm) * DH + lq * 8;
            bf16x8 b0 = *(const bf16x8*)rp, b1 = *(const bf16x8*)(rp + 32);
            bf16x8 p0, p1;
            if (t + 8 <= thi) {
                const short* rp2 = rbase + (size_t)((t + 8) * 16 + lm) * DH + lq * 8;
                p0 = *(const bf16x8*)rp2; p1 = *(const bf16x8*)(rp2 + 32);
            }
            for (; t <= thi; t += 8) {
                bf16x8 n0, n1;
                if (t + 16 <= thi) {
                    const short* rpn = rbase + (size_t)((t + 16) * 16 + lm) * DH + lq * 8;
                    n0 = *(const bf16x8*)rpn; n1 = *(const bf16x8*)(rpn + 32);
                }
                f32x4 c0 = {0.f,0.f,0.f,0.f}, c1 = {0.f,0.f,0.f,0.f};
                __builtin_amdgcn_s_setprio(1);
                c0 = __builtin_amdgcn_mfma_f32_16x16x32_bf16(av00, b0, c0, 0, 0, 0);
                c1 = __builtin_amdgcn_mfma_f32_16x16x32_bf16(av10, b0, c1, 0, 0, 0);
                c0 = __builtin_amdgcn_mfma_f32_16x16x32_bf16(av01, b1, c0, 0, 0, 0);
                c1 = __builtin_amdgcn_mfma_f32_16x16x32_bf16(av11, b1, c1, 0, 0, 0);
                __builtin_amdgcn_s_setprio(0);
                int cb = i0 + t * 16 + lm - 1023 - cbeg;     // local col for m=0
                int base = i0 + 16 * t - 1023;               // scalar col_min
                if (base >= cbeg && base + 46 < cend) {
                    #pragma unroll
                    for (int r = 0; r < 4; ++r) {
                        int m0 = lq * 4 + r, m1 = m0 + 16;
                        sch[sidx(m0, cb + m0)] = __float2half(c0[r]);
                        sch[sidx(m1, cb + m1)] = __float2half(c1[r]);
                    }
                } else {
                    #pragma unroll
                    for (int r = 0; r < 4; ++r) {
                        int m0 = lq * 4 + r, m1 = m0 + 16;
                        int cA = cb + m0, cB = cb + m1;
                        if (cA >= 0 && cA < 1024) sch[sidx(m0, cA)] = __float2half(c0[r]);
                        if (cB >= 0 && cB < 1024) sch[sidx(m1, cB)] = __float2half(c1[r]);
                    }
                }
                b0 = p0; b1 = p1; p0 = n0; p1 = n1;
            }
        }
    }

    // ---- pos wrap: col = i0 + 16t + lm + m + 1026, rows Qv[i+1]; depth-2 ----
    {
        int tmpw = cbeg - 1072 - i0;
        int tlw = tmpw > 0 ? ((tmpw + 15) >> 4) : 0;
        int thw = (cend - 1027 - i0) >> 4; if (thw > 127) thw = 127;
        int t = tlw + w;
        if (t <= thw) {
            const short* rp = rbase + (size_t)(t * 16 + lm) * DH + lq * 8;
            bf16x8 b0 = *(const bf16x8*)rp, b1 = *(const bf16x8*)(rp + 32);
            bf16x8 p0, p1;
            if (t + 8 <= thw) {
                const short* rp2 = rbase + (size_t)((t + 8) * 16 + lm) * DH + lq * 8;
                p0 = *(const bf16x8*)rp2; p1 = *(const bf16x8*)(rp2 + 32);
            }
            for (; t <= thw; t += 8) {
                bf16x8 n0, n1;
                if (t + 16 <= thw) {
                    const short* rpn = rbase + (size_t)((t + 16) * 16 + lm) * DH + lq * 8;
                    n0 = *(const bf16x8*)rpn; n1 = *(const bf16x8*)(rpn + 32);
                }
                f32x4 c0 = {0.f,0.f,0.f,0.f}, c1 = {0.f,0.f,0.f,0.f};
                __builtin_amdgcn_s_setprio(1);
                c0 = __builtin_amdgcn_mfma_f32_16x16x32_bf16(aw00, b0, c0, 0, 0, 0);
                c1 = __builtin_amdgcn_mfma_f32_16x16x32_bf16(aw10, b0, c1, 0, 0, 0);
                c0 = __builtin_amdgcn_mfma_f32_16x16x32_bf16(aw01, b1, c0, 0, 0, 0);
                c1 = __builtin_amdgcn_mfma_f32_16x16x32_bf16(aw11, b1, c1, 0, 0, 0);
                __builtin_amdgcn_s_setprio(0);
                int cb = i0 + t * 16 + lm + 1026 - cbeg;
                int base = i0 + 16 * t + 1026;
                if (base >= cbeg && base + 46 < cend) {
                    #pragma unroll
                    for (int r = 0; r < 4; ++r) {
                        int m0 = lq * 4 + r, m1 = m0 + 16;
                        sch[sidx(m0, cb + m0)] = __float2half(c0[r]);
                        sch[sidx(m1, cb + m1)] = __float2half(c1[r]);
                    }
                } else {
                    #pragma unroll
                    for (int r = 0; r < 4; ++r) {
                        int m0 = lq * 4 + r, m1 = m0 + 16;
                        int cA = cb + m0, cB = cb + m1;
                        if (cA >= 0 && cA < 1024) sch[sidx(m0, cA)] = __float2half(c0[r]);
                        if (cB >= 0 && cB < 1024) sch[sidx(m1, cB)] = __float2half(c1[r]);
                    }
                }
                b0 = p0; b1 = p1; p0 = n0; p1 = n1;
            }
        }
    }

    // ---- prefetch first two content K-tiles before the barrier ----
    const short* kbase = k_bf + (size_t)bh * J * DH;
    bf16x8 kb0, kb1, kc0, kc1;
    {
        int t0 = jh * 64 + w + 8 * ((it) & 7);
        int t1 = jh * 64 + w + 8 * ((1 + it) & 7);
        const short* kp0 = kbase + (size_t)(t0 * 16 + lm) * DH + lq * 8;
        const short* kp1 = kbase + (size_t)(t1 * 16 + lm) * DH + lq * 8;
        kb0 = *(const bf16x8*)kp0; kb1 = *(const bf16x8*)(kp0 + 32);
        kc0 = *(const bf16x8*)kp1; kc1 = *(const bf16x8*)(kp1 + 32);
    }
    __syncthreads();

    // ---- content + softmax FUSED; R19: score reads also roll depth-2 ----
    float sum0 = 0.f, sum1 = 0.f;
    int aA, aB; h16x4 hA, hB;
    {
        int t0 = jh * 64 + w + 8 * (it & 7);
        int lc0 = t0 * 16 - cbeg;
        aA = sidx(lm,      lc0 + lq * 4);
        aB = sidx(lm + 16, lc0 + lq * 4);
        hA = *(const h16x4*)(sc + aA);
        hB = *(const h16x4*)(sc + aB);
    }
    #pragma unroll 1
    for (int g = 0; g < 8; ++g) {
        bf16x8 nb0, nb1;
        if (g + 2 < 8) {
            int u = jh * 64 + w + 8 * ((g + 2 + it) & 7);
            const short* np = kbase + (size_t)(u * 16 + lm) * DH + lq * 8;
            nb0 = *(const bf16x8*)np; nb1 = *(const bf16x8*)(np + 32);
        }
        // score prefetch for tile g+1 (disjoint from tile g's store below)
        int aA_n, aB_n; h16x4 hA_n, hB_n;
        if (g + 1 < 8) {
            int tn = jh * 64 + w + 8 * ((g + 1 + it) & 7);
            int lcn = tn * 16 - cbeg;
            aA_n = sidx(lm,      lcn + lq * 4);
            aB_n = sidx(lm + 16, lcn + lq * 4);
            hA_n = *(const h16x4*)(sc + aA_n);
            hB_n = *(const h16x4*)(sc + aB_n);
        }
        f32x4 c0, c1;
        #pragma unroll
        for (int r = 0; r < 4; ++r) { c0[r] = (float)hA[r]; c1[r] = (float)hB[r]; }
        __builtin_amdgcn_s_setprio(1);
        c0 = __builtin_amdgcn_mfma_f32_16x16x32_bf16(kb0, au00, c0, 0, 0, 0);
        c1 = __builtin_amdgcn_mfma_f32_16x16x32_bf16(kb0, au10, c1, 0, 0, 0);
        c0 = __builtin_amdgcn_mfma_f32_16x16x32_bf16(kb1, au01, c0, 0, 0, 0);
        c1 = __builtin_amdgcn_mfma_f32_16x16x32_bf16(kb1, au11, c1, 0, 0, 0);
        __builtin_amdgcn_s_setprio(0);
        us4 oA, oB;
        #pragma unroll
        for (int r = 0; r < 4; ++r) {
            float e0 = __builtin_amdgcn_exp2f(c0[r]);
            float e1 = __builtin_amdgcn_exp2f(c1[r]);
            sum0 += e0; sum1 += e1;
            oA[r] = f2bf_fast(e0);
            oB[r] = f2bf_fast(e1);
        }
        *(us4*)(sc + aA) = oA;
        *(us4*)(sc + aB) = oB;
        kb0 = kc0; kb1 = kc1; kc0 = nb0; kc1 = nb1;
        hA = hA_n; hB = hB_n; aA = aA_n; aB = aB_n;
    }
    // per-wave row partials: reduce over lq group (lanes lm, lm+16/32/48)
    sum0 += __shfl_xor(sum0, 16); sum0 += __shfl_xor(sum0, 32);
    sum1 += __shfl_xor(sum1, 16); sum1 += __shfl_xor(sum1, 32);
    if (lane < 16) { wsum[lane][0][w] = sum0; wsum[lane][1][w] = sum1; }

    // ---- prefetch first PV V-chunk before the barrier ----
    const int dslice = w & 3, jq = w >> 2;
    const short* vtb = vt_bf + ((size_t)bh * DH + dslice * 16 + lm) * J + cbeg + jq * 512;
    bf16x8 cv0, cv1, cv2, cv3;
    {
        int j0 = (it & 3) * 128;
        cv0 = *(const bf16x8*)(vtb + j0 +  0 + lq * 8);
        cv1 = *(const bf16x8*)(vtb + j0 + 32 + lq * 8);
        cv2 = *(const bf16x8*)(vtb + j0 + 64 + lq * 8);
        cv3 = *(const bf16x8*)(vtb + j0 + 96 + lq * 8);
    }
    __syncthreads();

    // ---- ml write (probs/wsum complete after barrier) ----
    if (tid < 32) {
        float s = 0.f;
        #pragma unroll
        for (int ww = 0; ww < 8; ++ww) s += wsum[tid & 15][tid >> 4][ww];
        ml[(size_t)slot * 64 + tid * 2]     = 0.f;
        ml[(size_t)slot * 64 + tid * 2 + 1] = s;
    }

    // ---- PV: wave -> d-slice (w&3), j-quarter (w>>2); rolling V prefetch ----
    f32x4 pa0 = {0.f,0.f,0.f,0.f}, pa1 = {0.f,0.f,0.f,0.f};
    f32x4 pa2 = {0.f,0.f,0.f,0.f}, pa3 = {0.f,0.f,0.f,0.f};
    f32x4 pb0 = {0.f,0.f,0.f,0.f}, pb1 = {0.f,0.f,0.f,0.f};
    f32x4 pb2 = {0.f,0.f,0.f,0.f}, pb3 = {0.f,0.f,0.f,0.f};
    #pragma unroll 1
    for (int jo0 = 0; jo0 < 4; ++jo0) {       // 128 local j per iteration
        bf16x8 nv0, nv1, nv2, nv3;
        if (jo0 < 3) {
            int jn = ((jo0 + 1 + it) & 3) * 128;
            nv0 = *(const bf16x8*)(vtb + jn +  0 + lq * 8);
            nv1 = *(const bf16x8*)(vtb + jn + 32 + lq * 8);
            nv2 = *(const bf16x8*)(vtb + jn + 64 + lq * 8);
            nv3 = *(const bf16x8*)(vtb + jn + 96 + lq * 8);
        }
        int j0 = ((jo0 + it) & 3) * 128;
        int lb = jq * 512 + j0;
        bf16x8 a0 = *(const bf16x8*)(sc + sidx(lm, lb +  0 + lq * 8));
        bf16x8 a1 = *(const bf16x8*)(sc + sidx(lm, lb + 32 + lq * 8));
        bf16x8 a2 = *(const bf16x8*)(sc + sidx(lm, lb + 64 + lq * 8));
        bf16x8 a3 = *(const bf16x8*)(sc + sidx(lm, lb + 96 + lq * 8));
        bf16x8 c0 = *(const bf16x8*)(sc + sidx(16 + lm, lb +  0 + lq * 8));
        bf16x8 c1 = *(const bf16x8*)(sc + sidx(16 + lm, lb + 32 + lq * 8));
        bf16x8 c2 = *(const bf16x8*)(sc + sidx(16 + lm, lb + 64 + lq * 8));
        bf16x8 c3 = *(const bf16x8*)(sc + sidx(16 + lm, lb + 96 + lq * 8));
        __builtin_amdgcn_s_setprio(1);
        pa0 = __builtin_amdgcn_mfma_f32_16x16x32_bf16(a0, cv0, pa0, 0, 0, 0);
        pb0 = __builtin_amdgcn_mfma_f32_16x16x32_bf16(c0, cv0, pb0, 0, 0, 0);
        pa1 = __builtin_amdgcn_mfma_f32_16x16x32_bf16(a1, cv1, pa1, 0, 0, 0);
        pb1 = __builtin_amdgcn_mfma_f32_16x16x32_bf16(c1, cv1, pb1, 0, 0, 0);
        pa2 = __builtin_amdgcn_mfma_f32_16x16x32_bf16(a2, cv2, pa2, 0, 0, 0);
        pb2 = __builtin_amdgcn_mfma_f32_16x16x32_bf16(c2, cv2, pb2, 0, 0, 0);
        pa3 = __builtin_amdgcn_mfma_f32_16x16x32_bf16(a3, cv3, pa3, 0, 0, 0);
        pb3 = __builtin_amdgcn_mfma_f32_16x16x32_bf16(c3, cv3, pb3, 0, 0, 0);
        __builtin_amdgcn_s_setprio(0);
        if (jo0 < 3) { cv0 = nv0; cv1 = nv1; cv2 = nv2; cv3 = nv3; }
    }
    __syncthreads();   // all probs read; sc reusable as float scratch

    #pragma unroll
    for (int r = 0; r < 4; ++r) {
        int m0 = lq * 4 + r, m1 = m0 + 16;
        scF[jq * 2048 + m0 * 64 + dslice * 16 + lm] = pa0[r] + pa1[r] + pa2[r] + pa3[r];
        scF[jq * 2048 + m1 * 64 + dslice * 16 + lm] = pb0[r] + pb1[r] + pb2[r] + pb3[r];
    }
    __syncthreads();

    float* op = opart + (size_t)slot * 2048;
    #pragma unroll
    for (int e = tid; e < 2048; e += 512)
        op[e] = scF[e] + scF[2048 + e];
}

// ---------------------------------------------------------------------------
// Merge the two j-half partials (vectorized).
// ---------------------------------------------------------------------------
__global__ __launch_bounds__(256)
void attn_combine(const float* __restrict__ opart, const float* __restrict__ ml,
                  short* __restrict__ o_bf)
{
    const int blk = blockIdx.x;           // it*32 + bh
    const int it = blk >> 5, bh = blk & 31;
    const int h = bh & 15, bb = bh >> 4;
    __shared__ float wgt[32][2];
    const int tid = threadIdx.x;
    if (tid < 32) {
        float m0 = ml[(size_t)(blk * 2 + 0) * 64 + tid * 2];
        float l0 = ml[(size_t)(blk * 2 + 0) * 64 + tid * 2 + 1];
        float m1 = ml[(size_t)(blk * 2 + 1) * 64 + tid * 2];
        float l1 = ml[(size_t)(blk * 2 + 1) * 64 + tid * 2 + 1];
        float mx = fmaxf(m0, m1);
        float e0 = __expf(m0 - mx), e1 = __expf(m1 - mx);
        float inv = 1.0f / (e0 * l0 + e1 * l1);
        wgt[tid][0] = e0 * inv;
        wgt[tid][1] = e1 * inv;
    }
    __syncthreads();
    const float* p0 = opart + (size_t)(blk * 2 + 0) * 2048;
    const float* p1 = opart + (size_t)(blk * 2 + 1) * 2048;
    #pragma unroll
    for (int e4 = tid; e4 < 512; e4 += 256) {
        int e = e4 * 4;
        int m = e >> 6, d = e & 63;
        float4 a = *(const float4*)(p0 + e);
        float4 b = *(const float4*)(p1 + e);
        float w0 = wgt[m][0], w1 = wgt[m][1];
        s16x4 o = { f2bs(a.x * w0 + b.x * w1), f2bs(a.y * w0 + b.y * w1),
                    f2bs(a.z * w0 + b.z * w1), f2bs(a.w * w0 + b.w * w1) };
        *(s16x4*)(o_bf + ((size_t)(it * 32 + m) * B + bb) * (H * DH) + h * DH + d) = o;
    }
}

// ---------------------------------------------------------------------------
extern "C" void kernel_launch(void* const* d_in, const int* in_sizes, int n_in,
                              void* d_out, int out_size, void* d_ws, size_t ws_size,
                              hipStream_t stream)
{
    const float* x    = (const float*)d_in[0];   // [S, B, D]
    const float* pemb = (const float*)d_in[1];   // [S+M, D]
    const float* mem  = (const float*)d_in[2];   // [M, B, D]
    const float* u    = (const float*)d_in[3];   // [H, DH]
    const float* v    = (const float*)d_in[4];   // [H, DH]
    const float* Wkv  = (const float*)d_in[5];   // [D, 2*H*DH]
    const float* Wq   = (const float*)d_in[6];   // [D, H*DH]
    const float* Wpos = (const float*)d_in[7];   // [D, H*DH]
    const float* Wout = (const float*)d_in[8];   // [H*DH, D]
    float* out = (float*)d_out;                  // [S, B, D]

    char* p = (char*)d_ws;
    short* a_bf  = (short*)p; p += (size_t)4096 * 1024 * 2;    // mem||x  [0,8M)
    short* p_bf  = (short*)p; p += (size_t)2048 * 1024 * 2;    // [8M,12M)
    short* wkvt  = (short*)p; p += (size_t)2048 * 1024 * 2;    // [12M,16M)
    short* wqt   = (short*)p; p += (size_t)1024 * 1024 * 2;    // [16M,18M)
    short* wpt   = (short*)p; p += (size_t)1024 * 1024 * 2;    // [18M,20M)
    short* wot   = (short*)p; p += (size_t)1024 * 1024 * 2;    // [20M,22M)
    short* k_bf  = (short*)p; p += (size_t)B * H * J * DH * 2;
    short* vt_bf = (short*)p; p += (size_t)B * H * J * DH * 2;
    short* qu_bf = (short*)p; p += (size_t)B * H * S * DH * 2;
    short* qv_bf = (short*)p; p += (size_t)B * H * S * DH * 2;
    short* r_bf  = (short*)p; p += (size_t)H * J * DH * 2;
    short* o_bf  = (short*)p;

    // attn partials alias prep buffers (dead after proj_fused):
    // opart: [0,16M) over a_bf/p_bf/wkvt (2048 slots x 2048 fp32 = 16 MB);
    // ml: [16M,16.5M) over wqt (2048 slots x 64 fp32).
    float* opart = (float*)d_ws;
    float* ml    = (float*)((char*)d_ws + (size_t)16 * 1024 * 1024);

    prep<<<7424, 256, 0, stream>>>(mem, x, pemb, Wkv, Wq, Wpos, Wout,
                                   a_bf, p_bf, wkvt, wqt, wpt, wot);
    proj_fused<<<768, 256, 0, stream>>>(a_bf, p_bf, wkvt, wqt, wpt,
                                        k_bf, vt_bf, qu_bf, qv_bf, r_bf, u, v);
    attn_mfma<<<2048, 512, 0, stream>>>(
        qu_bf, qv_bf, k_bf, vt_bf, r_bf, opart, ml);
    attn_combine<<<(S / 32) * B * H, 256, 0, stream>>>(opart, ml, o_bf);
    gemm_out<<<256, 256, 0, stream>>>(o_bf, wot, out);
}

// Round 11
// 279.900 us; speedup vs baseline: 1.1454x; 1.0106x over previous
//
#include <hip/hip_runtime.h>
#include <hip/hip_bf16.h>
#include <hip/hip_fp16.h>
#include <math.h>

#define D    1024
#define H    16
#define DH   64
#define S    1024
#define M    1024
#define B    2
#define J    2048          // M + S
#define SCALE 0.125f       // 1/sqrt(64)
#define SCALE_L2E 0.18033688f   // SCALE * log2(e): softmax uses bare exp2

typedef __attribute__((ext_vector_type(8))) short        bf16x8;
typedef __attribute__((ext_vector_type(4))) short        s16x4;
typedef __attribute__((ext_vector_type(8))) _Float16     h16x8;
typedef __attribute__((ext_vector_type(4))) _Float16     h16x4;
typedef __attribute__((ext_vector_type(8))) unsigned short us8;
typedef __attribute__((ext_vector_type(4))) unsigned short us4;
typedef __attribute__((ext_vector_type(4))) float        f32x4;

__device__ __forceinline__ short f2bs(float f) {
    __hip_bfloat16 t = __float2bfloat16(f);
    short r; __builtin_memcpy(&r, &t, 2); return r;
}
// fast bf16 pack (round-half-up); inputs finite non-negative (probs)
__device__ __forceinline__ unsigned short f2bf_fast(float f) {
    unsigned int u; __builtin_memcpy(&u, &f, 4);
    return (unsigned short)((u + 0x8000u) >> 16);
}

// async global->LDS, 16 bytes per lane
__device__ __forceinline__ void g2l16(const short* g, short* l) {
    __builtin_amdgcn_global_load_lds(
        (const __attribute__((address_space(1))) unsigned int*)g,
        (__attribute__((address_space(3))) unsigned int*)l, 16, 0, 0);
}

// ---------------------------------------------------------------------------
// prep: blocks [0,6144)  fp32->bf16 flat convert (mem||x -> a_bf, pemb -> p_bf)
//       blocks [6144,7424) 64x64 weight transpose+convert W[k][n] -> Wt[n][k]
// ---------------------------------------------------------------------------
__global__ __launch_bounds__(256)
void prep(const float* __restrict__ mem, const float* __restrict__ x,
          const float* __restrict__ pemb,
          const float* __restrict__ Wkv, const float* __restrict__ Wq,
          const float* __restrict__ Wpos, const float* __restrict__ Wout,
          short* __restrict__ a_bf, short* __restrict__ p_bf,
          short* __restrict__ wkvt, short* __restrict__ wqt,
          short* __restrict__ wpt,  short* __restrict__ wot)
{
    __shared__ float t[64][65];
    int blk = blockIdx.x;
    const int tid = threadIdx.x;
    if (blk < 6144) {
        const int idx = (blk * 256 + tid) * 4;
        const int TWO_M = 2 * 1024 * 1024;
        float4 v; short* dst;
        if (idx < TWO_M)          { v = *(const float4*)(mem  + idx);           dst = a_bf + idx; }
        else if (idx < 2 * TWO_M) { v = *(const float4*)(x    + idx - TWO_M);   dst = a_bf + idx; }
        else                      { v = *(const float4*)(pemb + idx - 2*TWO_M); dst = p_bf + idx - 2*TWO_M; }
        s16x4 o = { f2bs(v.x), f2bs(v.y), f2bs(v.z), f2bs(v.w) };
        *(s16x4*)dst = o;
        return;
    }
    blk -= 6144;
    const float* src; short* dst; int N, t0;
    if (blk < 512)       { src = Wkv;  dst = wkvt; N = 2048; t0 = blk; }
    else if (blk < 768)  { src = Wq;   dst = wqt;  N = 1024; t0 = blk - 512; }
    else if (blk < 1024) { src = Wpos; dst = wpt;  N = 1024; t0 = blk - 768; }
    else                 { src = Wout; dst = wot;  N = 1024; t0 = blk - 1024; }
    const int ntn = N >> 6;
    const int k0 = (t0 / ntn) * 64, n0 = (t0 % ntn) * 64;
    #pragma unroll
    for (int e = tid; e < 4096; e += 256) {
        int r = e >> 6, c = e & 63;
        t[r][c] = src[(size_t)(k0 + r) * N + n0 + c];
    }
    __syncthreads();
    #pragma unroll
    for (int e = tid; e < 4096; e += 256) {
        int nr = e >> 6, kc = e & 63;
        dst[(size_t)(n0 + nr) * 1024 + k0 + kc] = f2bs(t[kc][nr]);
    }
}

// ---------------------------------------------------------------------------
// Shared MFMA GEMM core: BM=BN=128, BK=64, 256 thr, K=1024.
// ---------------------------------------------------------------------------
__device__ __forceinline__ void gemm_core(const short* __restrict__ A,
                                          const short* __restrict__ Bt,
                                          short* As, short* Bs,
                                          int bm0, int bn0, int tid,
                                          f32x4 acc[4][4])
{
    const int w    = tid >> 6;
    const int wy   = w >> 1, wx = w & 1;
    const int lane = tid & 63;
    const int lm   = lane & 15;
    const int lq   = lane >> 4;

    for (int k0 = 0; k0 < 1024; k0 += 64) {
        const short* Ab = A  + (size_t)bm0 * 1024 + k0;
        const short* Bb = Bt + (size_t)bn0 * 1024 + k0;
        #pragma unroll
        for (int t = 0; t < 4; ++t) {
            int s = t * 256 + tid;
            int r = s >> 3, c = s & 7;
            int cg = c ^ (r & 7);
            g2l16(Ab + r * 1024 + cg * 8, As + s * 8);
            g2l16(Bb + r * 1024 + cg * 8, Bs + s * 8);
        }
        __syncthreads();
        #pragma unroll
        for (int kk = 0; kk < 2; ++kk) {
            bf16x8 af[4], bg[4];
            #pragma unroll
            for (int r4 = 0; r4 < 4; ++r4) {
                int ar = wy * 64 + r4 * 16 + lm;
                int kc = kk * 4 + lq;
                af[r4] = *(const bf16x8*)(As + ((ar << 3) + (kc ^ (ar & 7))) * 8);
            }
            #pragma unroll
            for (int c4 = 0; c4 < 4; ++c4) {
                int br = wx * 64 + c4 * 16 + lm;
                int kc = kk * 4 + lq;
                bg[c4] = *(const bf16x8*)(Bs + ((br << 3) + (kc ^ (br & 7))) * 8);
            }
            #pragma unroll
            for (int r4 = 0; r4 < 4; ++r4)
                #pragma unroll
                for (int c4 = 0; c4 < 4; ++c4)
                    acc[r4][c4] = __builtin_amdgcn_mfma_f32_16x16x32_bf16(
                        af[r4], bg[c4], acc[r4][c4], 0, 0, 0);
        }
        __syncthreads();
    }
}

// ---------------------------------------------------------------------------
// Fused kv/q/r projections. qu/qv scaled by SCALE*log2(e) (bare exp2 attn).
// R18 XCD-aware block remap (bijective: 768 = 8 x 96).
// ---------------------------------------------------------------------------
__global__ __launch_bounds__(256)
void proj_fused(const short* __restrict__ a_bf, const short* __restrict__ p_bf,
                const short* __restrict__ wkvt, const short* __restrict__ wqt,
                const short* __restrict__ wpt,
                short* __restrict__ k_bf, short* __restrict__ vt_bf,
                short* __restrict__ qu_bf, short* __restrict__ qv_bf,
                short* __restrict__ r_bf,
                const float* __restrict__ uvec, const float* __restrict__ vvec)
{
    __shared__ __align__(16) short As[128 * 64];
    __shared__ __align__(16) short Bs[128 * 64];

    // XCD remap: HW sends original id L to XCD L&7; logical id below makes
    // XCD x execute the contiguous logical range [x*96, (x+1)*96).
    int blk = (blockIdx.x & 7) * 96 + (blockIdx.x >> 3);

    int mode, bx, by;
    const short *A, *Bt;
    if (blk < 512)      { bx = blk & 15; by = blk >> 4;
                          if (bx >= 8) { mode = 4; A = wkvt; Bt = a_bf; }   // swapped V
                          else         { mode = 0; A = a_bf; Bt = wkvt; } }
    else if (blk < 640) { int b2 = blk - 512; mode = 1; bx = b2 & 7; by = b2 >> 3;
                          A = a_bf + (size_t)2048 * 1024; Bt = wqt; }
    else                { int b3 = blk - 640; mode = 2; bx = b3 & 7; by = b3 >> 3;
                          A = p_bf; Bt = wpt; }
    const int bn0 = (mode == 4) ? by * 128 : bx * 128;
    const int bm0 = (mode == 4) ? bx * 128 : by * 128;
    const int tid = threadIdx.x;
    const int w = tid >> 6, wy = w >> 1, wx = w & 1;
    const int lane = tid & 63, lm = lane & 15, lq = lane >> 4;

    f32x4 acc[4][4];
    #pragma unroll
    for (int r = 0; r < 4; ++r)
        #pragma unroll
        for (int c = 0; c < 4; ++c) acc[r][c] = (f32x4){0.f, 0.f, 0.f, 0.f};

    gemm_core(A, Bt, As, Bs, bm0, bn0, tid, acc);

    #pragma unroll
    for (int r4 = 0; r4 < 4; ++r4) {
        #pragma unroll
        for (int c4 = 0; c4 < 4; ++c4) {
            const int n = bn0 + wx * 64 + c4 * 16 + lm;
            float ubias = 0.f, vbias = 0.f;
            if (mode == 1) { ubias = uvec[n]; vbias = vvec[n]; }
            #pragma unroll
            for (int reg = 0; reg < 4; ++reg) {
                const int m = bm0 + wy * 64 + r4 * 16 + lq * 4 + reg;
                const float val = acc[r4][c4][reg];
                if (mode == 0) {
                    int j = m >> 1, b = m & 1;
                    int h = n >> 6, d = n & 63;
                    k_bf[(((size_t)b * H + h) * J + j) * DH + d] = f2bs(val);
                } else if (mode == 4) {
                    int n2 = m - 1024, h = n2 >> 6, d = n2 & 63;
                    int j = n >> 1, b = n & 1;
                    vt_bf[(((size_t)b * H + h) * DH + d) * J + j] = f2bs(val);
                } else if (mode == 1) {
                    int i = m >> 1, b = m & 1;
                    int h = n >> 6, d = n & 63;
                    size_t o = (((size_t)b * H + h) * S + i) * DH + d;
                    qu_bf[o] = f2bs((val + ubias) * SCALE_L2E);
                    qv_bf[o] = f2bs((val + vbias) * SCALE_L2E);
                } else {
                    int h = n >> 6, d = n & 63;
                    r_bf[((size_t)h * J + m) * DH + d] = f2bs(val);
                }
            }
        }
    }
}

// ---------------------------------------------------------------------------
// Output projection: M=2048, N=1024, fp32 out. BM=64, BN=128, 256 blocks,
// XCD-contiguous logical order.
// ---------------------------------------------------------------------------
__global__ __launch_bounds__(256)
void gemm_out(const short* __restrict__ A, const short* __restrict__ Bt,
              float* __restrict__ out)
{
    __shared__ __align__(16) short As[64 * 64];    // 8 KB
    __shared__ __align__(16) short Bs[128 * 64];   // 16 KB
    const int lb = (blockIdx.x & 7) * 32 + (blockIdx.x >> 3);  // XCD-contig
    const int bn0 = (lb & 7) * 128, bm0 = (lb >> 3) * 64;
    const int tid = threadIdx.x;
    const int w = tid >> 6;                 // 0..3 = column-split wave index
    const int lane = tid & 63, lm = lane & 15, lq = lane >> 4;

    f32x4 acc[4][2];
    #pragma unroll
    for (int r = 0; r < 4; ++r)
        #pragma unroll
        for (int c = 0; c < 2; ++c) acc[r][c] = (f32x4){0.f, 0.f, 0.f, 0.f};

    for (int k0 = 0; k0 < 1024; k0 += 64) {
        const short* Ab = A  + (size_t)bm0 * 1024 + k0;
        const short* Bb = Bt + (size_t)bn0 * 1024 + k0;
        #pragma unroll
        for (int t = 0; t < 2; ++t) {       // A: 64 rows
            int s = t * 256 + tid;
            int r = s >> 3, c = s & 7;
            int cg = c ^ (r & 7);
            g2l16(Ab + r * 1024 + cg * 8, As + s * 8);
        }
        #pragma unroll
        for (int t = 0; t < 4; ++t) {       // B: 128 rows
            int s = t * 256 + tid;
            int r = s >> 3, c = s & 7;
            int cg = c ^ (r & 7);
            g2l16(Bb + r * 1024 + cg * 8, Bs + s * 8);
        }
        __syncthreads();
        #pragma unroll
        for (int kk = 0; kk < 2; ++kk) {
            bf16x8 af[4], bg[2];
            #pragma unroll
            for (int r4 = 0; r4 < 4; ++r4) {
                int ar = r4 * 16 + lm;
                int kc = kk * 4 + lq;
                af[r4] = *(const bf16x8*)(As + ((ar << 3) + (kc ^ (ar & 7))) * 8);
            }
            #pragma unroll
            for (int c4 = 0; c4 < 2; ++c4) {
                int br = w * 32 + c4 * 16 + lm;
                int kc = kk * 4 + lq;
                bg[c4] = *(const bf16x8*)(Bs + ((br << 3) + (kc ^ (br & 7))) * 8);
            }
            #pragma unroll
            for (int r4 = 0; r4 < 4; ++r4)
                #pragma unroll
                for (int c4 = 0; c4 < 2; ++c4)
                    acc[r4][c4] = __builtin_amdgcn_mfma_f32_16x16x32_bf16(
                        af[r4], bg[c4], acc[r4][c4], 0, 0, 0);
        }
        __syncthreads();
    }

    #pragma unroll
    for (int r4 = 0; r4 < 4; ++r4)
        #pragma unroll
        for (int c4 = 0; c4 < 2; ++c4) {
            const int n = bn0 + w * 32 + c4 * 16 + lm;
            #pragma unroll
            for (int reg = 0; reg < 4; ++reg) {
                const int m = bm0 + r4 * 16 + lq * 4 + reg;
                out[(size_t)m * 1024 + n] = acc[r4][c4][reg];
            }
        }
}

// ---------------------------------------------------------------------------
// MFMA attention. R20: one block owns (bh, it) and loops BOTH jh halves,
// keeping PV accumulators (pa/pb) and softmax row-sums live in registers
// across the loop. This deletes attn_combine entirely (41 MB traffic + a
// launch), the 16 MB opart write, and the ml round-trip; one epilogue per
// block instead of two. Q fragments reloaded per jh (cheap L2 hits) to
// hold VGPR near ~110 (no forced launch bounds — R10/R15 lessons).
// Grid: 1024 blocks (XCD-decoded), 2 resident/CU, 2 rounds.
// ---------------------------------------------------------------------------
__device__ __forceinline__ int sidx(int m, int c) {   // m in [0,32), c in [0,1024)
    return (m << 10) + (c ^ (m << 3));
}

__global__ __launch_bounds__(512)
void attn_mfma(const short* __restrict__ qu_bf, const short* __restrict__ qv_bf,
               const short* __restrict__ k_bf,  const short* __restrict__ vt_bf,
               const short* __restrict__ r_bf,
               short* __restrict__ o_bf)
{
    __shared__ unsigned short sc[32 * 1024];   // 64 KB
    __shared__ float wsum[16][2][8];           // per-wave row partials
    __shared__ float rtot[32];                 // final row sums
    __half* sch = (__half*)sc;
    float*  scF = (float*)sc;                  // reused after PV reads

    // XCD-aware decode: L&7 = XCD; each XCD owns bh in [4*xcd, 4*xcd+4).
    const int L   = blockIdx.x;
    const int xcd = L & 7;
    const int pp  = L >> 3;                    // 0..127
    const int bh  = (xcd << 2) + (pp >> 5);    // 4 streams per XCD
    const int it  = pp & 31;

    const int i0  = it * 32;
    const int h   = bh & (H - 1);
    const int tid = threadIdx.x;
    const int w    = tid >> 6;       // 0..7
    const int lane = tid & 63;
    const int lm   = lane & 15;
    const int lq   = lane >> 4;
    const int dslice = w & 3, jq = w >> 2;

    const short* rbase = r_bf + (size_t)h * J * DH;
    const short* kbase = k_bf + (size_t)bh * J * DH;

    float sum0 = 0.f, sum1 = 0.f;
    f32x4 pa0 = {0.f,0.f,0.f,0.f}, pa1 = {0.f,0.f,0.f,0.f};
    f32x4 pa2 = {0.f,0.f,0.f,0.f}, pa3 = {0.f,0.f,0.f,0.f};
    f32x4 pb0 = {0.f,0.f,0.f,0.f}, pb1 = {0.f,0.f,0.f,0.f};
    f32x4 pb2 = {0.f,0.f,0.f,0.f}, pb3 = {0.f,0.f,0.f,0.f};

    #pragma unroll 1
    for (int jh = 0; jh < 2; ++jh) {
        const int cbeg = jh << 10, cend = cbeg + 1024;
        if (jh) __syncthreads();   // prev PV score reads done before overwrite

        // ---- Qv / Qw fragments (per iteration; short live ranges) ----
        const short* qvp0 = qv_bf + ((size_t)(bh * S + i0 + lm)) * DH + lq * 8;
        const short* qvp1 = qvp0 + 16 * DH;
        bf16x8 av00 = *(const bf16x8*)qvp0, av01 = *(const bf16x8*)(qvp0 + 32);
        bf16x8 av10 = *(const bf16x8*)qvp1, av11 = *(const bf16x8*)(qvp1 + 32);
        int r1a = i0 + 1 + lm;  if (r1a > S - 1) r1a = S - 1;   // clamped rows masked
        int r1b = i0 + 17 + lm; if (r1b > S - 1) r1b = S - 1;
        const short* qwp0 = qv_bf + ((size_t)(bh * S + r1a)) * DH + lq * 8;
        const short* qwp1 = qv_bf + ((size_t)(bh * S + r1b)) * DH + lq * 8;
        bf16x8 aw00 = *(const bf16x8*)qwp0, aw01 = *(const bf16x8*)(qwp0 + 32);
        bf16x8 aw10 = *(const bf16x8*)qwp1, aw11 = *(const bf16x8*)(qwp1 + 32);

        // ---- zero the pos hole column: row m, col i0+m+1025 (if in window) ----
        if (tid < 32) {
            int hole = i0 + tid + 1025;
            if (hole >= cbeg && hole < cend) sc[sidx(tid, hole - cbeg)] = 0;
        }

        // ---- pos main: col = i0 + 16t + lm + m - 1023; depth-2 prefetch ----
        {
            int tmp = cbeg + 977 - i0;
            int tlo = tmp > 0 ? ((tmp + 15) >> 4) : 0;
            int thi = (cend + 1022 - i0) >> 4; if (thi > 127) thi = 127;
            int t = tlo + w;
            if (t <= thi) {
                const short* rp = rbase + (size_t)(t * 16 + lm) * DH + lq * 8;
                bf16x8 b0 = *(const bf16x8*)rp, b1 = *(const bf16x8*)(rp + 32);
                bf16x8 p0, p1;
                if (t + 8 <= thi) {
                    const short* rp2 = rbase + (size_t)((t + 8) * 16 + lm) * DH + lq * 8;
                    p0 = *(const bf16x8*)rp2; p1 = *(const bf16x8*)(rp2 + 32);
                }
                for (; t <= thi; t += 8) {
                    bf16x8 n0, n1;
                    if (t + 16 <= thi) {
                        const short* rpn = rbase + (size_t)((t + 16) * 16 + lm) * DH + lq * 8;
                        n0 = *(const bf16x8*)rpn; n1 = *(const bf16x8*)(rpn + 32);
                    }
                    f32x4 c0 = {0.f,0.f,0.f,0.f}, c1 = {0.f,0.f,0.f,0.f};
                    __builtin_amdgcn_s_setprio(1);
                    c0 = __builtin_amdgcn_mfma_f32_16x16x32_bf16(av00, b0, c0, 0, 0, 0);
                    c1 = __builtin_amdgcn_mfma_f32_16x16x32_bf16(av10, b0, c1, 0, 0, 0);
                    c0 = __builtin_amdgcn_mfma_f32_16x16x32_bf16(av01, b1, c0, 0, 0, 0);
                    c1 = __builtin_amdgcn_mfma_f32_16x16x32_bf16(av11, b1, c1, 0, 0, 0);
                    __builtin_amdgcn_s_setprio(0);
                    int cb = i0 + t * 16 + lm - 1023 - cbeg;     // local col for m=0
                    int base = i0 + 16 * t - 1023;               // scalar col_min
                    if (base >= cbeg && base + 46 < cend) {
                        #pragma unroll
                        for (int r = 0; r < 4; ++r) {
                            int m0 = lq * 4 + r, m1 = m0 + 16;
                            sch[sidx(m0, cb + m0)] = __float2half(c0[r]);
                            sch[sidx(m1, cb + m1)] = __float2half(c1[r]);
                        }
                    } else {
                        #pragma unroll
                        for (int r = 0; r < 4; ++r) {
                            int m0 = lq * 4 + r, m1 = m0 + 16;
                            int cA = cb + m0, cB = cb + m1;
                            if (cA >= 0 && cA < 1024) sch[sidx(m0, cA)] = __float2half(c0[r]);
                            if (cB >= 0 && cB < 1024) sch[sidx(m1, cB)] = __float2half(c1[r]);
                        }
                    }
                    b0 = p0; b1 = p1; p0 = n0; p1 = n1;
                }
            }
        }

        // ---- pos wrap: col = i0 + 16t + lm + m + 1026, rows Qv[i+1] ----
        {
            int tmpw = cbeg - 1072 - i0;
            int tlw = tmpw > 0 ? ((tmpw + 15) >> 4) : 0;
            int thw = (cend - 1027 - i0) >> 4; if (thw > 127) thw = 127;
            int t = tlw + w;
            if (t <= thw) {
                const short* rp = rbase + (size_t)(t * 16 + lm) * DH + lq * 8;
                bf16x8 b0 = *(const bf16x8*)rp, b1 = *(const bf16x8*)(rp + 32);
                bf16x8 p0, p1;
                if (t + 8 <= thw) {
                    const short* rp2 = rbase + (size_t)((t + 8) * 16 + lm) * DH + lq * 8;
                    p0 = *(const bf16x8*)rp2; p1 = *(const bf16x8*)(rp2 + 32);
                }
                for (; t <= thw; t += 8) {
                    bf16x8 n0, n1;
                    if (t + 16 <= thw) {
                        const short* rpn = rbase + (size_t)((t + 16) * 16 + lm) * DH + lq * 8;
                        n0 = *(const bf16x8*)rpn; n1 = *(const bf16x8*)(rpn + 32);
                    }
                    f32x4 c0 = {0.f,0.f,0.f,0.f}, c1 = {0.f,0.f,0.f,0.f};
                    __builtin_amdgcn_s_setprio(1);
                    c0 = __builtin_amdgcn_mfma_f32_16x16x32_bf16(aw00, b0, c0, 0, 0, 0);
                    c1 = __builtin_amdgcn_mfma_f32_16x16x32_bf16(aw10, b0, c1, 0, 0, 0);
                    c0 = __builtin_amdgcn_mfma_f32_16x16x32_bf16(aw01, b1, c0, 0, 0, 0);
                    c1 = __builtin_amdgcn_mfma_f32_16x16x32_bf16(aw11, b1, c1, 0, 0, 0);
                    __builtin_amdgcn_s_setprio(0);
                    int cb = i0 + t * 16 + lm + 1026 - cbeg;
                    int base = i0 + 16 * t + 1026;
                    if (base >= cbeg && base + 46 < cend) {
                        #pragma unroll
                        for (int r = 0; r < 4; ++r) {
                            int m0 = lq * 4 + r, m1 = m0 + 16;
                            sch[sidx(m0, cb + m0)] = __float2half(c0[r]);
                            sch[sidx(m1, cb + m1)] = __float2half(c1[r]);
                        }
                    } else {
                        #pragma unroll
                        for (int r = 0; r < 4; ++r) {
                            int m0 = lq * 4 + r, m1 = m0 + 16;
                            int cA = cb + m0, cB = cb + m1;
                            if (cA >= 0 && cA < 1024) sch[sidx(m0, cA)] = __float2half(c0[r]);
                            if (cB >= 0 && cB < 1024) sch[sidx(m1, cB)] = __float2half(c1[r]);
                        }
                    }
                    b0 = p0; b1 = p1; p0 = n0; p1 = n1;
                }
            }
        }

        // ---- prefetch first two content K-tiles before the barrier ----
        bf16x8 kb0, kb1, kc0, kc1;
        {
            int t0 = jh * 64 + w + 8 * ((it) & 7);
            int t1 = jh * 64 + w + 8 * ((1 + it) & 7);
            const short* kp0 = kbase + (size_t)(t0 * 16 + lm) * DH + lq * 8;
            const short* kp1 = kbase + (size_t)(t1 * 16 + lm) * DH + lq * 8;
            kb0 = *(const bf16x8*)kp0; kb1 = *(const bf16x8*)(kp0 + 32);
            kc0 = *(const bf16x8*)kp1; kc1 = *(const bf16x8*)(kp1 + 32);
        }
        __syncthreads();

        // ---- Qu fragments ----
        const short* qup0 = qu_bf + ((size_t)(bh * S + i0 + lm)) * DH + lq * 8;
        const short* qup1 = qup0 + 16 * DH;
        bf16x8 au00 = *(const bf16x8*)qup0, au01 = *(const bf16x8*)(qup0 + 32);
        bf16x8 au10 = *(const bf16x8*)qup1, au11 = *(const bf16x8*)(qup1 + 32);

        // ---- content + softmax FUSED ----
        #pragma unroll 1
        for (int g = 0; g < 8; ++g) {
            bf16x8 nb0, nb1;
            if (g + 2 < 8) {
                int u = jh * 64 + w + 8 * ((g + 2 + it) & 7);
                const short* np = kbase + (size_t)(u * 16 + lm) * DH + lq * 8;
                nb0 = *(const bf16x8*)np; nb1 = *(const bf16x8*)(np + 32);
            }
            int t = jh * 64 + w + 8 * ((g + it) & 7);
            int lc = t * 16 - cbeg;                  // 16-aligned local col base
            int aA = sidx(lm,      lc + lq * 4);     // 4 consecutive u16, 8B-aligned
            int aB = sidx(lm + 16, lc + lq * 4);
            h16x4 hA = *(const h16x4*)(sc + aA);
            h16x4 hB = *(const h16x4*)(sc + aB);
            f32x4 c0, c1;
            #pragma unroll
            for (int r = 0; r < 4; ++r) { c0[r] = (float)hA[r]; c1[r] = (float)hB[r]; }
            __builtin_amdgcn_s_setprio(1);
            c0 = __builtin_amdgcn_mfma_f32_16x16x32_bf16(kb0, au00, c0, 0, 0, 0);
            c1 = __builtin_amdgcn_mfma_f32_16x16x32_bf16(kb0, au10, c1, 0, 0, 0);
            c0 = __builtin_amdgcn_mfma_f32_16x16x32_bf16(kb1, au01, c0, 0, 0, 0);
            c1 = __builtin_amdgcn_mfma_f32_16x16x32_bf16(kb1, au11, c1, 0, 0, 0);
            __builtin_amdgcn_s_setprio(0);
            us4 oA, oB;
            #pragma unroll
            for (int r = 0; r < 4; ++r) {
                float e0 = __builtin_amdgcn_exp2f(c0[r]);
                float e1 = __builtin_amdgcn_exp2f(c1[r]);
                sum0 += e0; sum1 += e1;
                oA[r] = f2bf_fast(e0);
                oB[r] = f2bf_fast(e1);
            }
            *(us4*)(sc + aA) = oA;
            *(us4*)(sc + aB) = oB;
            kb0 = kc0; kb1 = kc1; kc0 = nb0; kc1 = nb1;
        }

        // ---- prefetch first PV V-chunk before the barrier ----
        const short* vtb = vt_bf + ((size_t)bh * DH + dslice * 16 + lm) * J + cbeg + jq * 512;
        bf16x8 cv0, cv1, cv2, cv3;
        {
            int j0 = (it & 3) * 128;
            cv0 = *(const bf16x8*)(vtb + j0 +  0 + lq * 8);
            cv1 = *(const bf16x8*)(vtb + j0 + 32 + lq * 8);
            cv2 = *(const bf16x8*)(vtb + j0 + 64 + lq * 8);
            cv3 = *(const bf16x8*)(vtb + j0 + 96 + lq * 8);
        }
        __syncthreads();

        // ---- PV: wave -> d-slice (w&3), j-quarter (w>>2); accumulate ----
        #pragma unroll 1
        for (int jo0 = 0; jo0 < 4; ++jo0) {       // 128 local j per iteration
            bf16x8 nv0, nv1, nv2, nv3;
            if (jo0 < 3) {
                int jn = ((jo0 + 1 + it) & 3) * 128;
                nv0 = *(const bf16x8*)(vtb + jn +  0 + lq * 8);
                nv1 = *(const bf16x8*)(vtb + jn + 32 + lq * 8);
                nv2 = *(const bf16x8*)(vtb + jn + 64 + lq * 8);
                nv3 = *(const bf16x8*)(vtb + jn + 96 + lq * 8);
            }
            int j0 = ((jo0 + it) & 3) * 128;
            int lb = jq * 512 + j0;
            bf16x8 a0 = *(const bf16x8*)(sc + sidx(lm, lb +  0 + lq * 8));
            bf16x8 a1 = *(const bf16x8*)(sc + sidx(lm, lb + 32 + lq * 8));
            bf16x8 a2 = *(const bf16x8*)(sc + sidx(lm, lb + 64 + lq * 8));
            bf16x8 a3 = *(const bf16x8*)(sc + sidx(lm, lb + 96 + lq * 8));
            bf16x8 c0 = *(const bf16x8*)(sc + sidx(16 + lm, lb +  0 + lq * 8));
            bf16x8 c1 = *(const bf16x8*)(sc + sidx(16 + lm, lb + 32 + lq * 8));
            bf16x8 c2 = *(const bf16x8*)(sc + sidx(16 + lm, lb + 64 + lq * 8));
            bf16x8 c3 = *(const bf16x8*)(sc + sidx(16 + lm, lb + 96 + lq * 8));
            __builtin_amdgcn_s_setprio(1);
            pa0 = __builtin_amdgcn_mfma_f32_16x16x32_bf16(a0, cv0, pa0, 0, 0, 0);
            pb0 = __builtin_amdgcn_mfma_f32_16x16x32_bf16(c0, cv0, pb0, 0, 0, 0);
            pa1 = __builtin_amdgcn_mfma_f32_16x16x32_bf16(a1, cv1, pa1, 0, 0, 0);
            pb1 = __builtin_amdgcn_mfma_f32_16x16x32_bf16(c1, cv1, pb1, 0, 0, 0);
            pa2 = __builtin_amdgcn_mfma_f32_16x16x32_bf16(a2, cv2, pa2, 0, 0, 0);
            pb2 = __builtin_amdgcn_mfma_f32_16x16x32_bf16(c2, cv2, pb2, 0, 0, 0);
            pa3 = __builtin_amdgcn_mfma_f32_16x16x32_bf16(a3, cv3, pa3, 0, 0, 0);
            pb3 = __builtin_amdgcn_mfma_f32_16x16x32_bf16(c3, cv3, pb3, 0, 0, 0);
            __builtin_amdgcn_s_setprio(0);
            if (jo0 < 3) { cv0 = nv0; cv1 = nv1; cv2 = nv2; cv3 = nv3; }
        }
    }

    // ---- epilogue: row sums, O reduce, normalize, write o_bf ----
    sum0 += __shfl_xor(sum0, 16); sum0 += __shfl_xor(sum0, 32);
    sum1 += __shfl_xor(sum1, 16); sum1 += __shfl_xor(sum1, 32);
    if (lane < 16) { wsum[lane][0][w] = sum0; wsum[lane][1][w] = sum1; }
    __syncthreads();   // all PV score reads done; sc reusable; wsum visible

    #pragma unroll
    for (int r = 0; r < 4; ++r) {
        int m0 = lq * 4 + r, m1 = m0 + 16;
        scF[jq * 2048 + m0 * 64 + dslice * 16 + lm] = pa0[r] + pa1[r] + pa2[r] + pa3[r];
        scF[jq * 2048 + m1 * 64 + dslice * 16 + lm] = pb0[r] + pb1[r] + pb2[r] + pb3[r];
    }
    if (tid < 32) {
        float s = 0.f;
        #pragma unroll
        for (int ww = 0; ww < 8; ++ww) s += wsum[tid & 15][tid >> 4][ww];
        rtot[tid] = 1.0f / s;
    }
    __syncthreads();

    const int bb = bh >> 4;
    #pragma unroll
    for (int e = tid; e < 2048; e += 512) {
        int m = e >> 6, d = e & 63;
        float val = (scF[e] + scF[2048 + e]) * rtot[m];
        o_bf[((size_t)(i0 + m) * B + bb) * (H * DH) + h * DH + d] = f2bs(val);
    }
}

// ---------------------------------------------------------------------------
extern "C" void kernel_launch(void* const* d_in, const int* in_sizes, int n_in,
                              void* d_out, int out_size, void* d_ws, size_t ws_size,
                              hipStream_t stream)
{
    const float* x    = (const float*)d_in[0];   // [S, B, D]
    const float* pemb = (const float*)d_in[1];   // [S+M, D]
    const float* mem  = (const float*)d_in[2];   // [M, B, D]
    const float* u    = (const float*)d_in[3];   // [H, DH]
    const float* v    = (const float*)d_in[4];   // [H, DH]
    const float* Wkv  = (const float*)d_in[5];   // [D, 2*H*DH]
    const float* Wq   = (const float*)d_in[6];   // [D, H*DH]
    const float* Wpos = (const float*)d_in[7];   // [D, H*DH]
    const float* Wout = (const float*)d_in[8];   // [H*DH, D]
    float* out = (float*)d_out;                  // [S, B, D]

    char* p = (char*)d_ws;
    short* a_bf  = (short*)p; p += (size_t)4096 * 1024 * 2;    // mem||x  [0,8M)
    short* p_bf  = (short*)p; p += (size_t)2048 * 1024 * 2;    // [8M,12M)
    short* wkvt  = (short*)p; p += (size_t)2048 * 1024 * 2;    // [12M,16M)
    short* wqt   = (short*)p; p += (size_t)1024 * 1024 * 2;    // [16M,18M)
    short* wpt   = (short*)p; p += (size_t)1024 * 1024 * 2;    // [18M,20M)
    short* wot   = (short*)p; p += (size_t)1024 * 1024 * 2;    // [20M,22M)
    short* k_bf  = (short*)p; p += (size_t)B * H * J * DH * 2;
    short* vt_bf = (short*)p; p += (size_t)B * H * J * DH * 2;
    short* qu_bf = (short*)p; p += (size_t)B * H * S * DH * 2;
    short* qv_bf = (short*)p; p += (size_t)B * H * S * DH * 2;
    short* r_bf  = (short*)p; p += (size_t)H * J * DH * 2;
    short* o_bf  = (short*)p;

    prep<<<7424, 256, 0, stream>>>(mem, x, pemb, Wkv, Wq, Wpos, Wout,
                                   a_bf, p_bf, wkvt, wqt, wpt, wot);
    proj_fused<<<768, 256, 0, stream>>>(a_bf, p_bf, wkvt, wqt, wpt,
                                        k_bf, vt_bf, qu_bf, qv_bf, r_bf, u, v);
    attn_mfma<<<1024, 512, 0, stream>>>(
        qu_bf, qv_bf, k_bf, vt_bf, r_bf, o_bf);
    gemm_out<<<256, 256, 0, stream>>>(o_bf, wot, out);
}

// Round 12
// 276.151 us; speedup vs baseline: 1.1610x; 1.0136x over previous
//
#include <hip/hip_runtime.h>
#include <hip/hip_bf16.h>
#include <hip/hip_fp16.h>
#include <math.h>

#define D    1024
#define H    16
#define DH   64
#define S    1024
#define M    1024
#define B    2
#define J    2048          // M + S
#define SCALE 0.125f       // 1/sqrt(64)
#define SCALE_L2E 0.18033688f   // SCALE * log2(e): softmax uses bare exp2

typedef __attribute__((ext_vector_type(8))) short        bf16x8;
typedef __attribute__((ext_vector_type(4))) short        s16x4;
typedef __attribute__((ext_vector_type(8))) _Float16     h16x8;
typedef __attribute__((ext_vector_type(4))) _Float16     h16x4;
typedef __attribute__((ext_vector_type(8))) unsigned short us8;
typedef __attribute__((ext_vector_type(4))) unsigned short us4;
typedef __attribute__((ext_vector_type(4))) float        f32x4;

__device__ __forceinline__ short f2bs(float f) {
    __hip_bfloat16 t = __float2bfloat16(f);
    short r; __builtin_memcpy(&r, &t, 2); return r;
}
// fast bf16 pack (round-half-up); inputs finite non-negative (probs)
__device__ __forceinline__ unsigned short f2bf_fast(float f) {
    unsigned int u; __builtin_memcpy(&u, &f, 4);
    return (unsigned short)((u + 0x8000u) >> 16);
}

// async global->LDS, 16 bytes per lane
__device__ __forceinline__ void g2l16(const short* g, short* l) {
    __builtin_amdgcn_global_load_lds(
        (const __attribute__((address_space(1))) unsigned int*)g,
        (__attribute__((address_space(3))) unsigned int*)l, 16, 0, 0);
}

// ---------------------------------------------------------------------------
// prep: blocks [0,6144)  fp32->bf16 flat convert (mem||x -> a_bf, pemb -> p_bf)
//       blocks [6144,7424) 64x64 weight transpose+convert W[k][n] -> Wt[n][k]
// ---------------------------------------------------------------------------
__global__ __launch_bounds__(256)
void prep(const float* __restrict__ mem, const float* __restrict__ x,
          const float* __restrict__ pemb,
          const float* __restrict__ Wkv, const float* __restrict__ Wq,
          const float* __restrict__ Wpos, const float* __restrict__ Wout,
          short* __restrict__ a_bf, short* __restrict__ p_bf,
          short* __restrict__ wkvt, short* __restrict__ wqt,
          short* __restrict__ wpt,  short* __restrict__ wot)
{
    __shared__ float t[64][65];
    int blk = blockIdx.x;
    const int tid = threadIdx.x;
    if (blk < 6144) {
        const int idx = (blk * 256 + tid) * 4;
        const int TWO_M = 2 * 1024 * 1024;
        float4 v; short* dst;
        if (idx < TWO_M)          { v = *(const float4*)(mem  + idx);           dst = a_bf + idx; }
        else if (idx < 2 * TWO_M) { v = *(const float4*)(x    + idx - TWO_M);   dst = a_bf + idx; }
        else                      { v = *(const float4*)(pemb + idx - 2*TWO_M); dst = p_bf + idx - 2*TWO_M; }
        s16x4 o = { f2bs(v.x), f2bs(v.y), f2bs(v.z), f2bs(v.w) };
        *(s16x4*)dst = o;
        return;
    }
    blk -= 6144;
    const float* src; short* dst; int N, t0;
    if (blk < 512)       { src = Wkv;  dst = wkvt; N = 2048; t0 = blk; }
    else if (blk < 768)  { src = Wq;   dst = wqt;  N = 1024; t0 = blk - 512; }
    else if (blk < 1024) { src = Wpos; dst = wpt;  N = 1024; t0 = blk - 768; }
    else                 { src = Wout; dst = wot;  N = 1024; t0 = blk - 1024; }
    const int ntn = N >> 6;
    const int k0 = (t0 / ntn) * 64, n0 = (t0 % ntn) * 64;
    #pragma unroll
    for (int e = tid; e < 4096; e += 256) {
        int r = e >> 6, c = e & 63;
        t[r][c] = src[(size_t)(k0 + r) * N + n0 + c];
    }
    __syncthreads();
    #pragma unroll
    for (int e = tid; e < 4096; e += 256) {
        int nr = e >> 6, kc = e & 63;
        dst[(size_t)(n0 + nr) * 1024 + k0 + kc] = f2bs(t[kc][nr]);
    }
}

// ---------------------------------------------------------------------------
// Shared MFMA GEMM core: BM=BN=128, BK=64, 256 thr, K=1024.
// ---------------------------------------------------------------------------
__device__ __forceinline__ void gemm_core(const short* __restrict__ A,
                                          const short* __restrict__ Bt,
                                          short* As, short* Bs,
                                          int bm0, int bn0, int tid,
                                          f32x4 acc[4][4])
{
    const int w    = tid >> 6;
    const int wy   = w >> 1, wx = w & 1;
    const int lane = tid & 63;
    const int lm   = lane & 15;
    const int lq   = lane >> 4;

    for (int k0 = 0; k0 < 1024; k0 += 64) {
        const short* Ab = A  + (size_t)bm0 * 1024 + k0;
        const short* Bb = Bt + (size_t)bn0 * 1024 + k0;
        #pragma unroll
        for (int t = 0; t < 4; ++t) {
            int s = t * 256 + tid;
            int r = s >> 3, c = s & 7;
            int cg = c ^ (r & 7);
            g2l16(Ab + r * 1024 + cg * 8, As + s * 8);
            g2l16(Bb + r * 1024 + cg * 8, Bs + s * 8);
        }
        __syncthreads();
        #pragma unroll
        for (int kk = 0; kk < 2; ++kk) {
            bf16x8 af[4], bg[4];
            #pragma unroll
            for (int r4 = 0; r4 < 4; ++r4) {
                int ar = wy * 64 + r4 * 16 + lm;
                int kc = kk * 4 + lq;
                af[r4] = *(const bf16x8*)(As + ((ar << 3) + (kc ^ (ar & 7))) * 8);
            }
            #pragma unroll
            for (int c4 = 0; c4 < 4; ++c4) {
                int br = wx * 64 + c4 * 16 + lm;
                int kc = kk * 4 + lq;
                bg[c4] = *(const bf16x8*)(Bs + ((br << 3) + (kc ^ (br & 7))) * 8);
            }
            #pragma unroll
            for (int r4 = 0; r4 < 4; ++r4)
                #pragma unroll
                for (int c4 = 0; c4 < 4; ++c4)
                    acc[r4][c4] = __builtin_amdgcn_mfma_f32_16x16x32_bf16(
                        af[r4], bg[c4], acc[r4][c4], 0, 0, 0);
        }
        __syncthreads();
    }
}

// ---------------------------------------------------------------------------
// Fused kv/q/r projections. qu/qv scaled by SCALE*log2(e) (bare exp2 attn).
// R18 XCD-aware block remap (bijective: 768 = 8 x 96).
// ---------------------------------------------------------------------------
__global__ __launch_bounds__(256)
void proj_fused(const short* __restrict__ a_bf, const short* __restrict__ p_bf,
                const short* __restrict__ wkvt, const short* __restrict__ wqt,
                const short* __restrict__ wpt,
                short* __restrict__ k_bf, short* __restrict__ vt_bf,
                short* __restrict__ qu_bf, short* __restrict__ qv_bf,
                short* __restrict__ r_bf,
                const float* __restrict__ uvec, const float* __restrict__ vvec)
{
    __shared__ __align__(16) short As[128 * 64];
    __shared__ __align__(16) short Bs[128 * 64];

    // XCD remap: HW sends original id L to XCD L&7; logical id below makes
    // XCD x execute the contiguous logical range [x*96, (x+1)*96).
    int blk = (blockIdx.x & 7) * 96 + (blockIdx.x >> 3);

    int mode, bx, by;
    const short *A, *Bt;
    if (blk < 512)      { bx = blk & 15; by = blk >> 4;
                          if (bx >= 8) { mode = 4; A = wkvt; Bt = a_bf; }   // swapped V
                          else         { mode = 0; A = a_bf; Bt = wkvt; } }
    else if (blk < 640) { int b2 = blk - 512; mode = 1; bx = b2 & 7; by = b2 >> 3;
                          A = a_bf + (size_t)2048 * 1024; Bt = wqt; }
    else                { int b3 = blk - 640; mode = 2; bx = b3 & 7; by = b3 >> 3;
                          A = p_bf; Bt = wpt; }
    const int bn0 = (mode == 4) ? by * 128 : bx * 128;
    const int bm0 = (mode == 4) ? bx * 128 : by * 128;
    const int tid = threadIdx.x;
    const int w = tid >> 6, wy = w >> 1, wx = w & 1;
    const int lane = tid & 63, lm = lane & 15, lq = lane >> 4;

    f32x4 acc[4][4];
    #pragma unroll
    for (int r = 0; r < 4; ++r)
        #pragma unroll
        for (int c = 0; c < 4; ++c) acc[r][c] = (f32x4){0.f, 0.f, 0.f, 0.f};

    gemm_core(A, Bt, As, Bs, bm0, bn0, tid, acc);

    #pragma unroll
    for (int r4 = 0; r4 < 4; ++r4) {
        #pragma unroll
        for (int c4 = 0; c4 < 4; ++c4) {
            const int n = bn0 + wx * 64 + c4 * 16 + lm;
            float ubias = 0.f, vbias = 0.f;
            if (mode == 1) { ubias = uvec[n]; vbias = vvec[n]; }
            #pragma unroll
            for (int reg = 0; reg < 4; ++reg) {
                const int m = bm0 + wy * 64 + r4 * 16 + lq * 4 + reg;
                const float val = acc[r4][c4][reg];
                if (mode == 0) {
                    int j = m >> 1, b = m & 1;
                    int h = n >> 6, d = n & 63;
                    k_bf[(((size_t)b * H + h) * J + j) * DH + d] = f2bs(val);
                } else if (mode == 4) {
                    int n2 = m - 1024, h = n2 >> 6, d = n2 & 63;
                    int j = n >> 1, b = n & 1;
                    vt_bf[(((size_t)b * H + h) * DH + d) * J + j] = f2bs(val);
                } else if (mode == 1) {
                    int i = m >> 1, b = m & 1;
                    int h = n >> 6, d = n & 63;
                    size_t o = (((size_t)b * H + h) * S + i) * DH + d;
                    qu_bf[o] = f2bs((val + ubias) * SCALE_L2E);
                    qv_bf[o] = f2bs((val + vbias) * SCALE_L2E);
                } else {
                    int h = n >> 6, d = n & 63;
                    r_bf[((size_t)h * J + m) * DH + d] = f2bs(val);
                }
            }
        }
    }
}

// ---------------------------------------------------------------------------
// Output projection: M=2048, N=1024, fp32 out. BM=64, BN=128, 256 blocks,
// XCD-contiguous logical order.
// ---------------------------------------------------------------------------
__global__ __launch_bounds__(256)
void gemm_out(const short* __restrict__ A, const short* __restrict__ Bt,
              float* __restrict__ out)
{
    __shared__ __align__(16) short As[64 * 64];    // 8 KB
    __shared__ __align__(16) short Bs[128 * 64];   // 16 KB
    const int lb = (blockIdx.x & 7) * 32 + (blockIdx.x >> 3);  // XCD-contig
    const int bn0 = (lb & 7) * 128, bm0 = (lb >> 3) * 64;
    const int tid = threadIdx.x;
    const int w = tid >> 6;                 // 0..3 = column-split wave index
    const int lane = tid & 63, lm = lane & 15, lq = lane >> 4;

    f32x4 acc[4][2];
    #pragma unroll
    for (int r = 0; r < 4; ++r)
        #pragma unroll
        for (int c = 0; c < 2; ++c) acc[r][c] = (f32x4){0.f, 0.f, 0.f, 0.f};

    for (int k0 = 0; k0 < 1024; k0 += 64) {
        const short* Ab = A  + (size_t)bm0 * 1024 + k0;
        const short* Bb = Bt + (size_t)bn0 * 1024 + k0;
        #pragma unroll
        for (int t = 0; t < 2; ++t) {       // A: 64 rows
            int s = t * 256 + tid;
            int r = s >> 3, c = s & 7;
            int cg = c ^ (r & 7);
            g2l16(Ab + r * 1024 + cg * 8, As + s * 8);
        }
        #pragma unroll
        for (int t = 0; t < 4; ++t) {       // B: 128 rows
            int s = t * 256 + tid;
            int r = s >> 3, c = s & 7;
            int cg = c ^ (r & 7);
            g2l16(Bb + r * 1024 + cg * 8, Bs + s * 8);
        }
        __syncthreads();
        #pragma unroll
        for (int kk = 0; kk < 2; ++kk) {
            bf16x8 af[4], bg[2];
            #pragma unroll
            for (int r4 = 0; r4 < 4; ++r4) {
                int ar = r4 * 16 + lm;
                int kc = kk * 4 + lq;
                af[r4] = *(const bf16x8*)(As + ((ar << 3) + (kc ^ (ar & 7))) * 8);
            }
            #pragma unroll
            for (int c4 = 0; c4 < 2; ++c4) {
                int br = w * 32 + c4 * 16 + lm;
                int kc = kk * 4 + lq;
                bg[c4] = *(const bf16x8*)(Bs + ((br << 3) + (kc ^ (br & 7))) * 8);
            }
            #pragma unroll
            for (int r4 = 0; r4 < 4; ++r4)
                #pragma unroll
                for (int c4 = 0; c4 < 2; ++c4)
                    acc[r4][c4] = __builtin_amdgcn_mfma_f32_16x16x32_bf16(
                        af[r4], bg[c4], acc[r4][c4], 0, 0, 0);
        }
        __syncthreads();
    }

    #pragma unroll
    for (int r4 = 0; r4 < 4; ++r4)
        #pragma unroll
        for (int c4 = 0; c4 < 2; ++c4) {
            const int n = bn0 + w * 32 + c4 * 16 + lm;
            #pragma unroll
            for (int reg = 0; reg < 4; ++reg) {
                const int m = bm0 + r4 * 16 + lq * 4 + reg;
                out[(size_t)m * 1024 + n] = acc[r4][c4][reg];
            }
        }
}

// ---------------------------------------------------------------------------
// MFMA attention. R21 = R20 (fused jh loop, combine deleted) with VGPR
// trimmed below the 2-blocks/CU threshold: R20's 124 VGPR gave 1 block/CU
// (occ 22%) at unchanged 121.6 us. The trim reverts the twice-proven-
// neutral prefetch fat (R11/R19): pos loops back to direct loads (-16
// VGPR), content K-prefetch depth 2 -> 1 (-8). Target <=112 VGPR so two
// 67 KB blocks co-reside (134 <= 160 KB LDS). This is the one unmeasured
// cell of the residency x work matrix: if any of the ~30 us per-block
// latency is fixed overhead (epilogue, barrier drains), 2-resident
// overlaps it; if throughput stays 121 us the structure's floor is real.
// ---------------------------------------------------------------------------
__device__ __forceinline__ int sidx(int m, int c) {   // m in [0,32), c in [0,1024)
    return (m << 10) + (c ^ (m << 3));
}

__global__ __launch_bounds__(512)
void attn_mfma(const short* __restrict__ qu_bf, const short* __restrict__ qv_bf,
               const short* __restrict__ k_bf,  const short* __restrict__ vt_bf,
               const short* __restrict__ r_bf,
               short* __restrict__ o_bf)
{
    __shared__ unsigned short sc[32 * 1024];   // 64 KB
    __shared__ float wsum[16][2][8];           // per-wave row partials
    __shared__ float rtot[32];                 // final row sums
    __half* sch = (__half*)sc;
    float*  scF = (float*)sc;                  // reused after PV reads

    // XCD-aware decode: L&7 = XCD; each XCD owns bh in [4*xcd, 4*xcd+4).
    const int L   = blockIdx.x;
    const int xcd = L & 7;
    const int pp  = L >> 3;                    // 0..127
    const int bh  = (xcd << 2) + (pp >> 5);    // 4 streams per XCD
    const int it  = pp & 31;

    const int i0  = it * 32;
    const int h   = bh & (H - 1);
    const int tid = threadIdx.x;
    const int w    = tid >> 6;       // 0..7
    const int lane = tid & 63;
    const int lm   = lane & 15;
    const int lq   = lane >> 4;
    const int dslice = w & 3, jq = w >> 2;

    const short* rbase = r_bf + (size_t)h * J * DH;
    const short* kbase = k_bf + (size_t)bh * J * DH;

    float sum0 = 0.f, sum1 = 0.f;
    f32x4 pa0 = {0.f,0.f,0.f,0.f}, pa1 = {0.f,0.f,0.f,0.f};
    f32x4 pa2 = {0.f,0.f,0.f,0.f}, pa3 = {0.f,0.f,0.f,0.f};
    f32x4 pb0 = {0.f,0.f,0.f,0.f}, pb1 = {0.f,0.f,0.f,0.f};
    f32x4 pb2 = {0.f,0.f,0.f,0.f}, pb3 = {0.f,0.f,0.f,0.f};

    #pragma unroll 1
    for (int jh = 0; jh < 2; ++jh) {
        const int cbeg = jh << 10, cend = cbeg + 1024;
        if (jh) __syncthreads();   // prev PV score reads done before overwrite

        // ---- Qv / Qw fragments (per iteration; short live ranges) ----
        const short* qvp0 = qv_bf + ((size_t)(bh * S + i0 + lm)) * DH + lq * 8;
        const short* qvp1 = qvp0 + 16 * DH;
        bf16x8 av00 = *(const bf16x8*)qvp0, av01 = *(const bf16x8*)(qvp0 + 32);
        bf16x8 av10 = *(const bf16x8*)qvp1, av11 = *(const bf16x8*)(qvp1 + 32);
        int r1a = i0 + 1 + lm;  if (r1a > S - 1) r1a = S - 1;   // clamped rows masked
        int r1b = i0 + 17 + lm; if (r1b > S - 1) r1b = S - 1;
        const short* qwp0 = qv_bf + ((size_t)(bh * S + r1a)) * DH + lq * 8;
        const short* qwp1 = qv_bf + ((size_t)(bh * S + r1b)) * DH + lq * 8;
        bf16x8 aw00 = *(const bf16x8*)qwp0, aw01 = *(const bf16x8*)(qwp0 + 32);
        bf16x8 aw10 = *(const bf16x8*)qwp1, aw11 = *(const bf16x8*)(qwp1 + 32);

        // ---- zero the pos hole column: row m, col i0+m+1025 (if in window) ----
        if (tid < 32) {
            int hole = i0 + tid + 1025;
            if (hole >= cbeg && hole < cend) sc[sidx(tid, hole - cbeg)] = 0;
        }

        // ---- pos main: col = i0 + 16t + lm + m - 1023; direct loads ----
        {
            int tmp = cbeg + 977 - i0;
            int tlo = tmp > 0 ? ((tmp + 15) >> 4) : 0;
            int thi = (cend + 1022 - i0) >> 4; if (thi > 127) thi = 127;
            for (int t = tlo + w; t <= thi; t += 8) {
                const short* rp = rbase + (size_t)(t * 16 + lm) * DH + lq * 8;
                bf16x8 b0 = *(const bf16x8*)rp, b1 = *(const bf16x8*)(rp + 32);
                f32x4 c0 = {0.f,0.f,0.f,0.f}, c1 = {0.f,0.f,0.f,0.f};
                __builtin_amdgcn_s_setprio(1);
                c0 = __builtin_amdgcn_mfma_f32_16x16x32_bf16(av00, b0, c0, 0, 0, 0);
                c1 = __builtin_amdgcn_mfma_f32_16x16x32_bf16(av10, b0, c1, 0, 0, 0);
                c0 = __builtin_amdgcn_mfma_f32_16x16x32_bf16(av01, b1, c0, 0, 0, 0);
                c1 = __builtin_amdgcn_mfma_f32_16x16x32_bf16(av11, b1, c1, 0, 0, 0);
                __builtin_amdgcn_s_setprio(0);
                int cb = i0 + t * 16 + lm - 1023 - cbeg;     // local col for m=0
                int base = i0 + 16 * t - 1023;               // scalar col_min
                if (base >= cbeg && base + 46 < cend) {
                    #pragma unroll
                    for (int r = 0; r < 4; ++r) {
                        int m0 = lq * 4 + r, m1 = m0 + 16;
                        sch[sidx(m0, cb + m0)] = __float2half(c0[r]);
                        sch[sidx(m1, cb + m1)] = __float2half(c1[r]);
                    }
                } else {
                    #pragma unroll
                    for (int r = 0; r < 4; ++r) {
                        int m0 = lq * 4 + r, m1 = m0 + 16;
                        int cA = cb + m0, cB = cb + m1;
                        if (cA >= 0 && cA < 1024) sch[sidx(m0, cA)] = __float2half(c0[r]);
                        if (cB >= 0 && cB < 1024) sch[sidx(m1, cB)] = __float2half(c1[r]);
                    }
                }
            }
        }

        // ---- pos wrap: col = i0 + 16t + lm + m + 1026, rows Qv[i+1] ----
        {
            int tmpw = cbeg - 1072 - i0;
            int tlw = tmpw > 0 ? ((tmpw + 15) >> 4) : 0;
            int thw = (cend - 1027 - i0) >> 4; if (thw > 127) thw = 127;
            for (int t = tlw + w; t <= thw; t += 8) {
                const short* rp = rbase + (size_t)(t * 16 + lm) * DH + lq * 8;
                bf16x8 b0 = *(const bf16x8*)rp, b1 = *(const bf16x8*)(rp + 32);
                f32x4 c0 = {0.f,0.f,0.f,0.f}, c1 = {0.f,0.f,0.f,0.f};
                __builtin_amdgcn_s_setprio(1);
                c0 = __builtin_amdgcn_mfma_f32_16x16x32_bf16(aw00, b0, c0, 0, 0, 0);
                c1 = __builtin_amdgcn_mfma_f32_16x16x32_bf16(aw10, b0, c1, 0, 0, 0);
                c0 = __builtin_amdgcn_mfma_f32_16x16x32_bf16(aw01, b1, c0, 0, 0, 0);
                c1 = __builtin_amdgcn_mfma_f32_16x16x32_bf16(aw11, b1, c1, 0, 0, 0);
                __builtin_amdgcn_s_setprio(0);
                int cb = i0 + t * 16 + lm + 1026 - cbeg;
                int base = i0 + 16 * t + 1026;
                if (base >= cbeg && base + 46 < cend) {
                    #pragma unroll
                    for (int r = 0; r < 4; ++r) {
                        int m0 = lq * 4 + r, m1 = m0 + 16;
                        sch[sidx(m0, cb + m0)] = __float2half(c0[r]);
                        sch[sidx(m1, cb + m1)] = __float2half(c1[r]);
                    }
                } else {
                    #pragma unroll
                    for (int r = 0; r < 4; ++r) {
                        int m0 = lq * 4 + r, m1 = m0 + 16;
                        int cA = cb + m0, cB = cb + m1;
                        if (cA >= 0 && cA < 1024) sch[sidx(m0, cA)] = __float2half(c0[r]);
                        if (cB >= 0 && cB < 1024) sch[sidx(m1, cB)] = __float2half(c1[r]);
                    }
                }
            }
        }

        // ---- prefetch first content K-tile before the barrier ----
        bf16x8 kb0, kb1;
        {
            int t0 = jh * 64 + w + 8 * (it & 7);
            const short* kp0 = kbase + (size_t)(t0 * 16 + lm) * DH + lq * 8;
            kb0 = *(const bf16x8*)kp0; kb1 = *(const bf16x8*)(kp0 + 32);
        }
        __syncthreads();

        // ---- Qu fragments ----
        const short* qup0 = qu_bf + ((size_t)(bh * S + i0 + lm)) * DH + lq * 8;
        const short* qup1 = qup0 + 16 * DH;
        bf16x8 au00 = *(const bf16x8*)qup0, au01 = *(const bf16x8*)(qup0 + 32);
        bf16x8 au10 = *(const bf16x8*)qup1, au11 = *(const bf16x8*)(qup1 + 32);

        // ---- content + softmax FUSED; depth-1 rolling K prefetch ----
        #pragma unroll 1
        for (int g = 0; g < 8; ++g) {
            bf16x8 nb0, nb1;
            if (g + 1 < 8) {
                int u = jh * 64 + w + 8 * ((g + 1 + it) & 7);
                const short* np = kbase + (size_t)(u * 16 + lm) * DH + lq * 8;
                nb0 = *(const bf16x8*)np; nb1 = *(const bf16x8*)(np + 32);
            }
            int t = jh * 64 + w + 8 * ((g + it) & 7);
            int lc = t * 16 - cbeg;                  // 16-aligned local col base
            int aA = sidx(lm,      lc + lq * 4);     // 4 consecutive u16, 8B-aligned
            int aB = sidx(lm + 16, lc + lq * 4);
            h16x4 hA = *(const h16x4*)(sc + aA);
            h16x4 hB = *(const h16x4*)(sc + aB);
            f32x4 c0, c1;
            #pragma unroll
            for (int r = 0; r < 4; ++r) { c0[r] = (float)hA[r]; c1[r] = (float)hB[r]; }
            __builtin_amdgcn_s_setprio(1);
            c0 = __builtin_amdgcn_mfma_f32_16x16x32_bf16(kb0, au00, c0, 0, 0, 0);
            c1 = __builtin_amdgcn_mfma_f32_16x16x32_bf16(kb0, au10, c1, 0, 0, 0);
            c0 = __builtin_amdgcn_mfma_f32_16x16x32_bf16(kb1, au01, c0, 0, 0, 0);
            c1 = __builtin_amdgcn_mfma_f32_16x16x32_bf16(kb1, au11, c1, 0, 0, 0);
            __builtin_amdgcn_s_setprio(0);
            us4 oA, oB;
            #pragma unroll
            for (int r = 0; r < 4; ++r) {
                float e0 = __builtin_amdgcn_exp2f(c0[r]);
                float e1 = __builtin_amdgcn_exp2f(c1[r]);
                sum0 += e0; sum1 += e1;
                oA[r] = f2bf_fast(e0);
                oB[r] = f2bf_fast(e1);
            }
            *(us4*)(sc + aA) = oA;
            *(us4*)(sc + aB) = oB;
            kb0 = nb0; kb1 = nb1;
        }

        // ---- prefetch first PV V-chunk before the barrier ----
        const short* vtb = vt_bf + ((size_t)bh * DH + dslice * 16 + lm) * J + cbeg + jq * 512;
        bf16x8 cv0, cv1, cv2, cv3;
        {
            int j0 = (it & 3) * 128;
            cv0 = *(const bf16x8*)(vtb + j0 +  0 + lq * 8);
            cv1 = *(const bf16x8*)(vtb + j0 + 32 + lq * 8);
            cv2 = *(const bf16x8*)(vtb + j0 + 64 + lq * 8);
            cv3 = *(const bf16x8*)(vtb + j0 + 96 + lq * 8);
        }
        __syncthreads();

        // ---- PV: wave -> d-slice (w&3), j-quarter (w>>2); accumulate ----
        #pragma unroll 1
        for (int jo0 = 0; jo0 < 4; ++jo0) {       // 128 local j per iteration
            bf16x8 nv0, nv1, nv2, nv3;
            if (jo0 < 3) {
                int jn = ((jo0 + 1 + it) & 3) * 128;
                nv0 = *(const bf16x8*)(vtb + jn +  0 + lq * 8);
                nv1 = *(const bf16x8*)(vtb + jn + 32 + lq * 8);
                nv2 = *(const bf16x8*)(vtb + jn + 64 + lq * 8);
                nv3 = *(const bf16x8*)(vtb + jn + 96 + lq * 8);
            }
            int j0 = ((jo0 + it) & 3) * 128;
            int lb = jq * 512 + j0;
            bf16x8 a0 = *(const bf16x8*)(sc + sidx(lm, lb +  0 + lq * 8));
            bf16x8 a1 = *(const bf16x8*)(sc + sidx(lm, lb + 32 + lq * 8));
            bf16x8 a2 = *(const bf16x8*)(sc + sidx(lm, lb + 64 + lq * 8));
            bf16x8 a3 = *(const bf16x8*)(sc + sidx(lm, lb + 96 + lq * 8));
            bf16x8 c0 = *(const bf16x8*)(sc + sidx(16 + lm, lb +  0 + lq * 8));
            bf16x8 c1 = *(const bf16x8*)(sc + sidx(16 + lm, lb + 32 + lq * 8));
            bf16x8 c2 = *(const bf16x8*)(sc + sidx(16 + lm, lb + 64 + lq * 8));
            bf16x8 c3 = *(const bf16x8*)(sc + sidx(16 + lm, lb + 96 + lq * 8));
            __builtin_amdgcn_s_setprio(1);
            pa0 = __builtin_amdgcn_mfma_f32_16x16x32_bf16(a0, cv0, pa0, 0, 0, 0);
            pb0 = __builtin_amdgcn_mfma_f32_16x16x32_bf16(c0, cv0, pb0, 0, 0, 0);
            pa1 = __builtin_amdgcn_mfma_f32_16x16x32_bf16(a1, cv1, pa1, 0, 0, 0);
            pb1 = __builtin_amdgcn_mfma_f32_16x16x32_bf16(c1, cv1, pb1, 0, 0, 0);
            pa2 = __builtin_amdgcn_mfma_f32_16x16x32_bf16(a2, cv2, pa2, 0, 0, 0);
            pb2 = __builtin_amdgcn_mfma_f32_16x16x32_bf16(c2, cv2, pb2, 0, 0, 0);
            pa3 = __builtin_amdgcn_mfma_f32_16x16x32_bf16(a3, cv3, pa3, 0, 0, 0);
            pb3 = __builtin_amdgcn_mfma_f32_16x16x32_bf16(c3, cv3, pb3, 0, 0, 0);
            __builtin_amdgcn_s_setprio(0);
            if (jo0 < 3) { cv0 = nv0; cv1 = nv1; cv2 = nv2; cv3 = nv3; }
        }
    }

    // ---- epilogue: row sums, O reduce, normalize, write o_bf ----
    sum0 += __shfl_xor(sum0, 16); sum0 += __shfl_xor(sum0, 32);
    sum1 += __shfl_xor(sum1, 16); sum1 += __shfl_xor(sum1, 32);
    if (lane < 16) { wsum[lane][0][w] = sum0; wsum[lane][1][w] = sum1; }
    __syncthreads();   // all PV score reads done; sc reusable; wsum visible

    #pragma unroll
    for (int r = 0; r < 4; ++r) {
        int m0 = lq * 4 + r, m1 = m0 + 16;
        scF[jq * 2048 + m0 * 64 + dslice * 16 + lm] = pa0[r] + pa1[r] + pa2[r] + pa3[r];
        scF[jq * 2048 + m1 * 64 + dslice * 16 + lm] = pb0[r] + pb1[r] + pb2[r] + pb3[r];
    }
    if (tid < 32) {
        float s = 0.f;
        #pragma unroll
        for (int ww = 0; ww < 8; ++ww) s += wsum[tid & 15][tid >> 4][ww];
        rtot[tid] = 1.0f / s;
    }
    __syncthreads();

    const int bb = bh >> 4;
    #pragma unroll
    for (int e = tid; e < 2048; e += 512) {
        int m = e >> 6, d = e & 63;
        float val = (scF[e] + scF[2048 + e]) * rtot[m];
        o_bf[((size_t)(i0 + m) * B + bb) * (H * DH) + h * DH + d] = f2bs(val);
    }
}

// ---------------------------------------------------------------------------
extern "C" void kernel_launch(void* const* d_in, const int* in_sizes, int n_in,
                              void* d_out, int out_size, void* d_ws, size_t ws_size,
                              hipStream_t stream)
{
    const float* x    = (const float*)d_in[0];   // [S, B, D]
    const float* pemb = (const float*)d_in[1];   // [S+M, D]
    const float* mem  = (const float*)d_in[2];   // [M, B, D]
    const float* u    = (const float*)d_in[3];   // [H, DH]
    const float* v    = (const float*)d_in[4];   // [H, DH]
    const float* Wkv  = (const float*)d_in[5];   // [D, 2*H*DH]
    const float* Wq   = (const float*)d_in[6];   // [D, H*DH]
    const float* Wpos = (const float*)d_in[7];   // [D, H*DH]
    const float* Wout = (const float*)d_in[8];   // [H*DH, D]
    float* out = (float*)d_out;                  // [S, B, D]

    char* p = (char*)d_ws;
    short* a_bf  = (short*)p; p += (size_t)4096 * 1024 * 2;    // mem||x  [0,8M)
    short* p_bf  = (short*)p; p += (size_t)2048 * 1024 * 2;    // [8M,12M)
    short* wkvt  = (short*)p; p += (size_t)2048 * 1024 * 2;    // [12M,16M)
    short* wqt   = (short*)p; p += (size_t)1024 * 1024 * 2;    // [16M,18M)
    short* wpt   = (short*)p; p += (size_t)1024 * 1024 * 2;    // [18M,20M)
    short* wot   = (short*)p; p += (size_t)1024 * 1024 * 2;    // [20M,22M)
    short* k_bf  = (short*)p; p += (size_t)B * H * J * DH * 2;
    short* vt_bf = (short*)p; p += (size_t)B * H * J * DH * 2;
    short* qu_bf = (short*)p; p += (size_t)B * H * S * DH * 2;
    short* qv_bf = (short*)p; p += (size_t)B * H * S * DH * 2;
    short* r_bf  = (short*)p; p += (size_t)H * J * DH * 2;
    short* o_bf  = (short*)p;

    prep<<<7424, 256, 0, stream>>>(mem, x, pemb, Wkv, Wq, Wpos, Wout,
                                   a_bf, p_bf, wkvt, wqt, wpt, wot);
    proj_fused<<<768, 256, 0, stream>>>(a_bf, p_bf, wkvt, wqt, wpt,
                                        k_bf, vt_bf, qu_bf, qv_bf, r_bf, u, v);
    attn_mfma<<<1024, 512, 0, stream>>>(
        qu_bf, qv_bf, k_bf, vt_bf, r_bf, o_bf);
    gemm_out<<<256, 256, 0, stream>>>(o_bf, wot, out);
}